// Round 1
// 1845.428 us; speedup vs baseline: 1.0707x; 1.0707x over previous
//
#include <hip/hip_runtime.h>

// ---------------------------------------------------------------------------
// Problem constants
// ---------------------------------------------------------------------------
#define NB    128
#define HD    100
#define NU    20000
#define NTG   10000
#define NTREE 30000
#define NG    30000
#define TT    20
#define EG    200000
#define ET    60000
#define VOC   50000

#define ESTR  304   // Etab row stride (u16): 608 B, 16B-aligned
#define WROWS 336   // GRU weight rows: 3 gates x 112 (gate stride 112)

typedef unsigned short u16;
typedef unsigned int   u32;
typedef __attribute__((ext_vector_type(8))) short short8;
typedef __attribute__((ext_vector_type(4))) float floatx4;

__device__ __forceinline__ float sigmoidf_(float x) {
    return __fdividef(1.f, 1.f + __expf(-x));
}
__device__ __forceinline__ float tanhf_(float x) {
    return 1.f - __fdividef(2.f, __expf(2.f * x) + 1.f);
}
__device__ __forceinline__ u16 f2bf(float f) {
    u32 u = __float_as_uint(f);
    u32 r = (u + 0x7fffu + ((u >> 16) & 1u)) >> 16;
    return (u16)r;
}
__device__ __forceinline__ float bf2f(u16 h) {
    return __uint_as_float(((u32)h) << 16);
}

// ---------------------------------------------------------------------------
// Fused 2-layer GRU v6: 512 threads / 32 rows / all TT steps.
//
// Key change vs v5: gate dimension padded to stride 112 in the weight matrix
// ([336][128] rows: r@0, z@112, n@224) so that wave w (7 compute waves) owns
// col-tiles {w, w+7, w+14} and each lane holds the (r,z,n) pre-activations of
// ITS output column in MFMA accumulator registers. The GRU combine runs
// entirely in-register -> the 300-wide gate LDS buffer (GA), its 8-way bank
// conflicts and the scalar u16 round-trip are all deleted.
//  - weights register-resident: 3 mats x 3 tiles x 4 kchunks = 144 regs
//    -> fits 256 with transients -> 2 waves/SIMD (vs 1 in v5).
//  - wave 7 = producer: stages next step's Etab x-gate rows into a
//    double-buffered LDS tile (coalesced 16B loads via reg staging).
//  - h mirrors double-buffered + XOR-swizzled (byte ^= ((row>>2)&3)<<5):
//    conflict-free, and the step needs only ONE barrier (vs 4).
// ---------------------------------------------------------------------------
struct GruProb {
    const u16*   Etab;     // [VOC][304] (includes bih0)
    const int*   nodes;    // [M][TT]
    const float* h0;       // [2][M][100] fp32
    const u16*   Whh0;     // [336][128] gate-padded (col100 = bhh0)
    const u16*   Wih1;     // (col100 = bih1)
    const u16*   Whh1;     // (col100 = bhh1)
    u16*         hout;     // [M][128]
    int          M;
};

__global__ __launch_bounds__(512, 2) void gru_fused6(GruProb Pg, GruProb Pt, int gblocks)
{
    const bool isg = (int)blockIdx.x < gblocks;
    const GruProb P = isg ? Pg : Pt;
    const int bx = isg ? blockIdx.x : blockIdx.x - gblocks;
    const int M  = P.M;
    const int m0 = bx * 32;

    // h mirrors: [32][128] u16, 256B rows, byte ^= ((row>>2)&3)<<5 swizzle
    __shared__ u16 H0[2][32 * 128];
    __shared__ u16 H1[2][32 * 128];
    // x-gate tile: [32][320] u16 (640B rows = 5x128B -> swizzle closed)
    __shared__ u16 XB[2][32 * 320];

    const int tid  = threadIdx.x;
    const int w    = tid >> 6, lane = tid & 63;
    const int fr   = lane & 15, quad = lane >> 4;
    const int c    = w * 16 + fr;                 // output column of this lane
    const bool cok = (w < 7) && (c < HD);

    // ---- register-resident weight fragments (tiles g*7 + w) ----
    short8 Bh0[3][4], Bx1[3][4], Bh1[3][4];
    if (w < 7) {
#pragma unroll
        for (int g = 0; g < 3; ++g) {
            const size_t rb = (size_t)((g * 7 + w) * 16 + fr) * 128 + quad * 8;
#pragma unroll
            for (int kk = 0; kk < 4; ++kk) {
                Bh0[g][kk] = *(const short8*)(P.Whh0 + rb + kk * 32);
                Bx1[g][kk] = *(const short8*)(P.Wih1 + rb + kk * 32);
                Bh1[g][kk] = *(const short8*)(P.Whh1 + rb + kk * 32);
            }
        }
    }

    // ---- zero h mirrors ----
    for (int i = tid; i < 32 * 128; i += 512) {
        H0[0][i] = 0; H0[1][i] = 0; H1[0][i] = 0; H1[1][i] = 0;
    }
    __syncthreads();
    // bias slot col 100 = 1.0 in all four buffers (swizzled position)
    if (tid < 32) {
        int o = (tid * 256 + (200 ^ (((tid >> 2) & 3) << 5))) >> 1;
        H0[0][o] = 0x3F80; H0[1][o] = 0x3F80;
        H1[0][o] = 0x3F80; H1[1][o] = 0x3F80;
    }

    // ---- init h carry + LDS mirrors ----
    float h0f[2][4] = {{0.f,0.f,0.f,0.f},{0.f,0.f,0.f,0.f}};
    float h1f[2][4] = {{0.f,0.f,0.f,0.f},{0.f,0.f,0.f,0.f}};
    if (cok) {
#pragma unroll
        for (int rt = 0; rt < 2; ++rt)
#pragma unroll
        for (int r = 0; r < 4; ++r) {
            int row = rt * 16 + quad * 4 + r;
            int gm  = m0 + row;
            float v0 = 0.f, v1 = 0.f;
            if (gm < M) {
                v0 = P.h0[(size_t)gm * HD + c];
                v1 = P.h0[(size_t)(M + gm) * HD + c];
            }
            h0f[rt][r] = v0; h1f[rt][r] = v1;
            int off = (2 * c) ^ (((row >> 2) & 3) << 5);
            *(u16*)((char*)&H0[0][0] + row * 256 + off) = f2bf(v0);
            *(u16*)((char*)&H1[0][0] + row * 256 + off) = f2bf(v1);
        }
    }

    // ---- producer-wave staging helper: copy 32 Etab rows -> XB buffer ----
    auto stage = [&](u16* xb, int ids) {
#pragma unroll
        for (int half = 0; half < 2; ++half) {
            uint4 v[10];
#pragma unroll
            for (int i2 = 0; i2 < 10; ++i2) {
                int i = half * 10 + i2;
                int L = i * 1024 + lane * 16;       // linear byte offset in XB
                int row = (int)((u32)L / 640u);
                int bp = L - row * 640;
                int b  = bp ^ (((row >> 2) & 3) << 5);   // inverse of read swizzle
                if (b >= 608) b = 0;                     // pad granule -> garbage, never read
                int nd = __shfl(ids, row);
                v[i2] = *(const uint4*)((const char*)P.Etab + (size_t)nd * 608 + b);
            }
#pragma unroll
            for (int i2 = 0; i2 < 10; ++i2) {
                int i = half * 10 + i2;
                *(uint4*)((char*)xb + i * 1024 + lane * 16) = v[i2];
            }
        }
    };

    int idv = 0;
    if (w == 7) {
        if (lane < 32 && (m0 + lane) < M)
            idv = P.nodes[(size_t)(m0 + lane) * TT];
        stage(&XB[0][0], idv);                  // x-gates for t=0
        idv = 0;
        if (lane < 32 && (m0 + lane) < M)
            idv = P.nodes[(size_t)(m0 + lane) * TT + 1];
    }
    __syncthreads();

    int cur = 0;
    for (int t = 0; t < TT; ++t) {
        // ================= phase A =================
        if (w < 7) {
            // GEMM0: Gh0 = h0 @ Whh0'^T  (3 gate tiles in-register) + combine0
#pragma unroll
            for (int rt = 0; rt < 2; ++rt) {
                short8 a[4];
#pragma unroll
                for (int kk = 0; kk < 4; ++kk) {
                    int row = rt * 16 + fr;
                    int off = (kk * 64 + quad * 16) ^ (((row >> 2) & 3) << 5);
                    a[kk] = *(const short8*)((const char*)&H0[cur][0] + row * 256 + off);
                }
                floatx4 ag[3];
#pragma unroll
                for (int g = 0; g < 3; ++g) ag[g] = (floatx4){0.f, 0.f, 0.f, 0.f};
#pragma unroll
                for (int g = 0; g < 3; ++g)
#pragma unroll
                    for (int kk = 0; kk < 4; ++kk)
                        ag[g] = __builtin_amdgcn_mfma_f32_16x16x32_bf16(a[kk], Bh0[g][kk], ag[g], 0, 0, 0);
                if (cok) {
#pragma unroll
                    for (int r = 0; r < 4; ++r) {
                        int row = rt * 16 + quad * 4 + r;
                        int q = ((row >> 2) & 3) << 5;
                        const char* xbase = (const char*)&XB[cur][0] + row * 640;
                        float xr = bf2f(*(const u16*)(xbase + ((2 * c)       ^ q)));
                        float xz = bf2f(*(const u16*)(xbase + ((200 + 2 * c) ^ q)));
                        float xn = bf2f(*(const u16*)(xbase + ((400 + 2 * c) ^ q)));
                        float rr = sigmoidf_(xr + ag[0][r]);
                        float zz = sigmoidf_(xz + ag[1][r]);
                        float nn = tanhf_(xn + rr * ag[2][r]);
                        float o  = (1.f - zz) * nn + zz * h0f[rt][r];
                        h0f[rt][r] = o;
                        *(u16*)((char*)&H0[cur ^ 1][0] + row * 256 + ((2 * c) ^ q)) = f2bf(o);
                    }
                }
            }
        } else {
            // wave 7: stage x-gates for step t+1, prefetch ids for t+2
            if (t + 1 < TT) stage(&XB[cur ^ 1][0], idv);
            int id2 = 0;
            if (t + 2 < TT && lane < 32 && (m0 + lane) < M)
                id2 = P.nodes[(size_t)(m0 + lane) * TT + t + 2];
            idv = id2;
        }
        __syncthreads();   // the ONE barrier per step

        // ================= phase B =================
        if (w < 7) {
#pragma unroll
            for (int rt = 0; rt < 2; ++rt) {
                short8 a0[4], a1[4];
#pragma unroll
                for (int kk = 0; kk < 4; ++kk) {
                    int row = rt * 16 + fr;
                    int off = (kk * 64 + quad * 16) ^ (((row >> 2) & 3) << 5);
                    a0[kk] = *(const short8*)((const char*)&H0[cur ^ 1][0] + row * 256 + off);
                    a1[kk] = *(const short8*)((const char*)&H1[cur][0]     + row * 256 + off);
                }
                floatx4 ax[3], ah[3];
#pragma unroll
                for (int g = 0; g < 3; ++g) {
                    ax[g] = (floatx4){0.f, 0.f, 0.f, 0.f};
                    ah[g] = (floatx4){0.f, 0.f, 0.f, 0.f};
                }
#pragma unroll
                for (int g = 0; g < 3; ++g)
#pragma unroll
                    for (int kk = 0; kk < 4; ++kk) {
                        ax[g] = __builtin_amdgcn_mfma_f32_16x16x32_bf16(a0[kk], Bx1[g][kk], ax[g], 0, 0, 0);
                        ah[g] = __builtin_amdgcn_mfma_f32_16x16x32_bf16(a1[kk], Bh1[g][kk], ah[g], 0, 0, 0);
                    }
                if (cok) {
#pragma unroll
                    for (int r = 0; r < 4; ++r) {
                        int row = rt * 16 + quad * 4 + r;
                        int q = ((row >> 2) & 3) << 5;
                        float rr = sigmoidf_(ax[0][r] + ah[0][r]);
                        float zz = sigmoidf_(ax[1][r] + ah[1][r]);
                        float nn = tanhf_(ax[2][r] + rr * ah[2][r]);
                        float o  = (1.f - zz) * nn + zz * h1f[rt][r];
                        h1f[rt][r] = o;
                        *(u16*)((char*)&H1[cur ^ 1][0] + row * 256 + ((2 * c) ^ q)) = f2bf(o);
                    }
                }
            }
        }
        cur ^= 1;
    }
    __syncthreads();

    // ---- write final top-layer hidden, bf16 [M][128] (de-swizzle) ----
    for (int i = tid; i < 32 * 128; i += 512) {
        int row = i >> 7, cc = i & 127;
        int gm = m0 + row;
        if (gm < M) {
            int o = (row * 256 + ((2 * cc) ^ (((row >> 2) & 3) << 5))) >> 1;
            P.hout[(size_t)gm * 128 + cc] = H1[cur][o];
        }
    }
}

// ---------------------------------------------------------------------------
// bf16 MFMA GEMM (Etab build + GAT feature GEMMs)
// ---------------------------------------------------------------------------
#define LDST 40
__global__ __launch_bounds__(256) void gemm_mfma(
    const u16* __restrict__ A, const u16* __restrict__ B,
    float* __restrict__ Cf, u16* __restrict__ Cb,
    int M, int N, int Kt, int lda, int ldw, int ldc)
{
    const int m0 = blockIdx.x * 64;
    if (m0 >= M) return;
    const int n0 = blockIdx.y * 64;

    __shared__ u16 Als[64 * LDST];
    __shared__ u16 Wls[64 * LDST];

    const int tid  = threadIdx.x;
    const int wave = tid >> 6, lane = tid & 63;
    const int row  = tid >> 2, part = (tid & 3) * 8;
    const int fr   = lane & 15, quad = lane >> 4;

    floatx4 acc[4];
#pragma unroll
    for (int t = 0; t < 4; ++t) acc[t] = (floatx4){0.f, 0.f, 0.f, 0.f};

    const int am = m0 + row;  const bool aok = am < M;
    const int wn = n0 + row;  const bool wok = wn < N;
    const uint4 z4 = {0u, 0u, 0u, 0u};

    for (int kk = 0; kk < Kt; ++kk) {
        uint4 av = aok ? *(const uint4*)(A + (size_t)am * lda + kk * 32 + part) : z4;
        uint4 wv = wok ? *(const uint4*)(B + (size_t)wn * ldw + kk * 32 + part) : z4;
        __syncthreads();
        *(uint4*)&Als[row * LDST + part] = av;
        *(uint4*)&Wls[row * LDST + part] = wv;
        __syncthreads();
        short8 af = *(const short8*)&Als[((wave << 4) + fr) * LDST + quad * 8];
#pragma unroll
        for (int t = 0; t < 4; ++t) {
            short8 bf = *(const short8*)&Wls[((t << 4) + fr) * LDST + quad * 8];
            acc[t] = __builtin_amdgcn_mfma_f32_16x16x32_bf16(af, bf, acc[t], 0, 0, 0);
        }
    }

    const int orow0 = m0 + (wave << 4) + quad * 4;
#pragma unroll
    for (int t = 0; t < 4; ++t) {
        int col = n0 + (t << 4) + fr;
        if (col >= N) continue;
#pragma unroll
        for (int r = 0; r < 4; ++r) {
            int mr = orow0 + r;
            if (mr >= M) continue;
            float v = acc[t][r];
            if (Cf) Cf[(size_t)mr * ldc + col] = v;
            if (Cb) Cb[(size_t)mr * ldc + col] = f2bf(v);
        }
    }
}

// ---------------------------------------------------------------------------
// fp32 tiled GEMM (user-embed MLP only)
// ---------------------------------------------------------------------------
__global__ __launch_bounds__(256) void gemm_nt(
    const float* __restrict__ A, const float* __restrict__ W,
    const float* __restrict__ bias, float* __restrict__ C,
    int M, int N, int K, int relu)
{
    const int m0 = blockIdx.x * 64;
    const int n0 = blockIdx.y * 64;
    __shared__ float As[20][68];
    __shared__ float Ws[20][68];
    const int tid = threadIdx.x;
    const int r0 = (tid >> 4) * 4;
    const int c0 = (tid & 15) * 4;
    int sr[5], sk[5];
#pragma unroll
    for (int it = 0; it < 5; ++it) {
        int idx = tid + it * 256;
        sr[it] = idx / 20; sk[it] = idx - sr[it] * 20;
    }
    float acc[4][4];
#pragma unroll
    for (int i = 0; i < 4; ++i)
#pragma unroll
        for (int j = 0; j < 4; ++j) acc[i][j] = 0.f;
    const int nch = (K + 19) / 20;
    for (int ch = 0; ch < nch; ++ch) {
        const int k0 = ch * 20;
#pragma unroll
        for (int it = 0; it < 5; ++it) {
            int m = m0 + sr[it], k = k0 + sk[it];
            float va = 0.f, vw = 0.f;
            if (k < K) {
                if (m < M) va = A[(size_t)m * K + k];
                int n = n0 + sr[it];
                if (n < N) vw = W[(size_t)n * K + k];
            }
            As[sk[it]][sr[it]] = va;
            Ws[sk[it]][sr[it]] = vw;
        }
        __syncthreads();
#pragma unroll
        for (int kkk = 0; kkk < 20; ++kkk) {
            float4 a = *(const float4*)&As[kkk][r0];
            float4 w = *(const float4*)&Ws[kkk][c0];
            float av[4] = {a.x, a.y, a.z, a.w};
            float wv[4] = {w.x, w.y, w.z, w.w};
#pragma unroll
            for (int i = 0; i < 4; ++i)
#pragma unroll
                for (int j = 0; j < 4; ++j)
                    acc[i][j] = fmaf(av[i], wv[j], acc[i][j]);
        }
        __syncthreads();
    }
#pragma unroll
    for (int i = 0; i < 4; ++i) {
        int m = m0 + r0 + i;
        if (m >= M) continue;
#pragma unroll
        for (int j = 0; j < 4; ++j) {
            int n = n0 + c0 + j;
            if (n >= N) continue;
            float v = acc[i][j] + (bias ? bias[n] : 0.f);
            if (relu) v = fmaxf(v, 0.f);
            C[(size_t)m * N + n] = v;
        }
    }
}

// fp32 [M][K] -> bf16 [Mp][ldk]; col K..ldk zero, except col 100 gets
// app[n] (if app) or 1.0 (if appone) — the K-slot bias fold.
__global__ void convert_pad2(const float* __restrict__ src, u16* __restrict__ dst,
                             int M, int Mp, int K, int ldk,
                             const float* __restrict__ app, int appone)
{
    int t = blockIdx.x * blockDim.x + threadIdx.x;
    if (t >= Mp * ldk) return;
    int n = t / ldk, c = t - n * ldk;
    u16 o = 0;
    if (n < M) {
        if (c < K) o = f2bf(src[(size_t)n * K + c]);
        else if (c == 100) {
            if (app) o = f2bf(app[n]);
            else if (appone) o = 0x3F80;
        }
    }
    dst[t] = o;
}

// GRU weight -> gate-padded bf16 [336][128]: gates r/z/n at row offsets
// 0/112/224; col100 = bias; everything else zero.
__global__ void convert_gru_w(const float* __restrict__ src, u16* __restrict__ dst,
                              const float* __restrict__ bias)
{
    int t = blockIdx.x * blockDim.x + threadIdx.x;
    if (t >= WROWS * 128) return;
    int rr = t >> 7, c = t & 127;
    int g = rr / 112, r2 = rr - g * 112;
    u16 o = 0;
    if (r2 < 100) {
        int sr = g * 100 + r2;
        if (c < 100) o = f2bf(src[(size_t)sr * 100 + c]);
        else if (c == 100) o = f2bf(bias[sr]);
    }
    dst[t] = o;
}

// xg (bf16 [NG][128]) = concat(hg[:128], ue, hg[128:])
__global__ void build_xg_bf(const u16* __restrict__ hgb, const float* __restrict__ ue,
                            u16* __restrict__ xgb)
{
    int t = blockIdx.x * blockDim.x + threadIdx.x;
    if (t >= NG * 128) return;
    int n = t >> 7, c = t & 127;
    u16 o = 0;
    if (n < NB)           o = hgb[n * 128 + c];
    else if (n < NB + NU) { if (c < HD) o = f2bf(ue[(size_t)(n - NB) * HD + c]); }
    else                  o = hgb[(size_t)(n - NU) * 128 + c];
    xgb[t] = o;
}

// tree roots: hb rows[0:128) <- xg_final fp32
__global__ void set_roots(const float* __restrict__ src, u16* __restrict__ hb)
{
    int t = blockIdx.x * blockDim.x + threadIdx.x;
    if (t >= NB * HD) return;
    int n = t / HD, c = t - n * HD;
    hb[(size_t)n * 128 + c] = f2bf(src[t]);
}

// ---------------------------------------------------------------------------
// CSR build
// ---------------------------------------------------------------------------
__global__ void csr_count(const int* __restrict__ ei, int E, int N, int* __restrict__ cnt)
{
    int e = blockIdx.x * blockDim.x + threadIdx.x;
    if (e >= E + N) return;
    int dst = (e < E) ? ei[E + e] : e - E;
    atomicAdd(&cnt[dst], 1);
}

__global__ void csr_scan(const int* __restrict__ cnt, int* __restrict__ off,
                         int* __restrict__ cur, int N)
{
    __shared__ int part[256];
    const int tid = threadIdx.x;
    const int per = (N + 255) / 256;
    const int i0 = tid * per;
    const int i1 = min(i0 + per, N);
    int s = 0;
    for (int i = i0; i < i1; ++i) s += cnt[i];
    part[tid] = s;
    __syncthreads();
    for (int o = 1; o < 256; o <<= 1) {
        int u = (tid >= o) ? part[tid - o] : 0;
        __syncthreads();
        part[tid] += u;
        __syncthreads();
    }
    int base = part[tid] - s;
    for (int i = i0; i < i1; ++i) {
        off[i] = base; cur[i] = base;
        base += cnt[i];
    }
    if (tid == 255) off[N] = part[255];
}

__global__ void csr_scatter(const int* __restrict__ ei, int E, int N,
                            int* __restrict__ cur, int* __restrict__ eidx)
{
    int e = blockIdx.x * blockDim.x + threadIdx.x;
    if (e >= E + N) return;
    int dst = (e < E) ? ei[E + e] : e - E;
    int pos = atomicAdd(&cur[dst], 1);
    eidx[pos] = e;
}

// ---------------------------------------------------------------------------
// GAT pieces (feat is bf16)
// ---------------------------------------------------------------------------
__global__ void gat_es_ed(const u16* __restrict__ feat, const float* __restrict__ asrc,
                          const float* __restrict__ adst, float* __restrict__ es,
                          float* __restrict__ ed, int N, int heads, int C)
{
    int gid = blockIdx.x * blockDim.x + threadIdx.x;
    if (gid >= N * heads) return;
    int n = gid / heads, hd = gid - n * heads;
    const u16* hp = feat + ((size_t)n * heads + hd) * C;
    const float* as = asrc + (size_t)hd * C;
    const float* ad = adst + (size_t)hd * C;
    float s1 = 0.f, s2 = 0.f;
    for (int c = 0; c < C; c += 4) {
        uint2 pk = *(const uint2*)(hp + c);
        float v0 = bf2f((u16)(pk.x & 0xffff)), v1 = bf2f((u16)(pk.x >> 16));
        float v2 = bf2f((u16)(pk.y & 0xffff)), v3 = bf2f((u16)(pk.y >> 16));
        s1 += v0 * as[c] + v1 * as[c + 1] + v2 * as[c + 2] + v3 * as[c + 3];
        s2 += v0 * ad[c] + v1 * ad[c + 1] + v2 * ad[c + 2] + v3 * ad[c + 3];
    }
    es[gid] = s1; ed[gid] = s2;
}

__device__ __forceinline__ void atomic_max_f(float* addr, float v)
{
    if (v >= 0.f) atomicMax((int*)addr, __float_as_int(v));
    else          atomicMin((unsigned int*)addr, __float_as_uint(v));
}

__global__ void gat_edge_logit(const int* __restrict__ ei, int E, int N, int heads,
                               const float* __restrict__ es, const float* __restrict__ ed,
                               float* __restrict__ eb, float* __restrict__ m)
{
    int gid = blockIdx.x * blockDim.x + threadIdx.x;
    int EE = E + N;
    if (gid >= EE * heads) return;
    int idx = gid / heads, hd = gid - idx * heads;
    int src, dst;
    if (idx < E) { src = ei[idx]; dst = ei[E + idx]; } else { src = dst = idx - E; }
    float e = es[src * heads + hd] + ed[dst * heads + hd];
    e = e > 0.f ? e : 0.2f * e;
    eb[gid] = e;
    atomic_max_f(&m[dst * heads + hd], e);
}

__global__ void gat_edge_expsum(const int* __restrict__ ei, int E, int N, int heads,
                                float* __restrict__ eb, const float* __restrict__ m,
                                float* __restrict__ s)
{
    int gid = blockIdx.x * blockDim.x + threadIdx.x;
    int EE = E + N;
    if (gid >= EE * heads) return;
    int idx = gid / heads, hd = gid - idx * heads;
    int dst = (idx < E) ? ei[E + idx] : idx - E;
    float e = __expf(eb[gid] - m[dst * heads + hd]);
    eb[gid] = e;
    atomicAdd(&s[dst * heads + hd], e);
}

template<int C, int VEC>
__global__ __launch_bounds__(256) void gat_accum_csr(
    const int* __restrict__ off, const int* __restrict__ eidx,
    const int* __restrict__ ei, int E,
    const float* __restrict__ eb, const float* __restrict__ s,
    const u16* __restrict__ feat, const float* __restrict__ bias,
    float* __restrict__ outf, u16* __restrict__ outb,
    int N, int heads, int HC, int nchunk)
{
    int gt = blockIdx.x * blockDim.x + threadIdx.x;
    int w = gt >> 6, lane = gt & 63;
    int dst = w / nchunk, chunk = w - dst * nchunk;
    if (dst >= N) return;
    int c0 = chunk * 64 * VEC + lane * VEC;
    if (c0 >= HC) return;
    int hh[VEC]; float sinv[VEC], acc[VEC];
#pragma unroll
    for (int v = 0; v < VEC; ++v) {
        int c = c0 + v;
        hh[v] = c / C;
        sinv[v] = __fdividef(1.f, s[dst * heads + hh[v]]);
        acc[v] = 0.f;
    }
    int e0 = off[dst], e1 = off[dst + 1];
    for (int p = e0; p < e1; ++p) {
        int j = eidx[p];
        int src = (j < E) ? ei[j] : (j - E);
        const u16* frp = feat + (size_t)src * HC + c0;
        float fv[VEC];
        if (VEC == 4) {
            uint2 pk = *(const uint2*)frp;
            fv[0] = bf2f((u16)(pk.x & 0xffff)); fv[1] = bf2f((u16)(pk.x >> 16));
            fv[2] = bf2f((u16)(pk.y & 0xffff)); fv[3] = bf2f((u16)(pk.y >> 16));
        } else {
            u32 pk = *(const u32*)frp;
            fv[0] = bf2f((u16)(pk & 0xffff)); fv[1] = bf2f((u16)(pk >> 16));
        }
#pragma unroll
        for (int v = 0; v < VEC; ++v)
            acc[v] += fv[v] * eb[(size_t)j * heads + hh[v]] * sinv[v];
    }
#pragma unroll
    for (int v = 0; v < VEC; ++v) {
        int c = c0 + v;
        float o = fmaxf(acc[v] + bias[c], 0.f);
        if (outf) outf[(size_t)dst * HC + c] = o;
        if (outb) outb[(size_t)dst * HC + c] = f2bf(o);
    }
}

__global__ void scatter_mean_accum(const float* __restrict__ x, const int* __restrict__ idx,
                                   float* __restrict__ ssum, float* __restrict__ cnt)
{
    int t = blockIdx.x * blockDim.x + threadIdx.x;
    if (t >= NTREE * HD) return;
    int n = t / HD, c = t - n * HD;
    int b = idx[n];
    atomicAdd(&ssum[b * HD + c], x[t]);
    if (c == 0) atomicAdd(&cnt[b], 1.f);
}

__global__ void fc_out(const float* __restrict__ ssum, const float* __restrict__ cnt,
                       const float* __restrict__ W, const float* __restrict__ b,
                       float* __restrict__ out)
{
    int t = threadIdx.x;                 // 512 threads
    int bb = t >> 2, j = t & 3;
    float inv = __fdividef(1.f, fmaxf(cnt[bb], 1.f));
    float acc = b[j];
    for (int k = 0; k < HD; ++k) acc += ssum[bb * HD + k] * inv * W[j * HD + k];
    out[t] = acc;
}

// ---------------------------------------------------------------------------
// Host launcher
// ---------------------------------------------------------------------------
extern "C" void kernel_launch(void* const* d_in, const int* in_sizes, int n_in,
                              void* d_out, int out_size, void* d_ws, size_t ws_size,
                              hipStream_t stream)
{
    const float* user_feats = (const float*)d_in[1];
    const int*   gnf        = (const int*)d_in[2];
    const int*   gei        = (const int*)d_in[3];
    const int*   tnf        = (const int*)d_in[4];
    const int*   tei        = (const int*)d_in[5];
    const int*   indices    = (const int*)d_in[6];
    const float* h0g        = (const float*)d_in[7];
    const float* h0t        = (const float*)d_in[8];
    const float* temb       = (const float*)d_in[9];
    const float* gW[2][4] = {{(const float*)d_in[10], (const float*)d_in[11], (const float*)d_in[12], (const float*)d_in[13]},
                             {(const float*)d_in[14], (const float*)d_in[15], (const float*)d_in[16], (const float*)d_in[17]}};
    const float* tW[2][4] = {{(const float*)d_in[18], (const float*)d_in[19], (const float*)d_in[20], (const float*)d_in[21]},
                             {(const float*)d_in[22], (const float*)d_in[23], (const float*)d_in[24], (const float*)d_in[25]}};
    const float* uW1 = (const float*)d_in[26]; const float* ub1 = (const float*)d_in[27];
    const float* uW2 = (const float*)d_in[28]; const float* ub2 = (const float*)d_in[29];
    const float* gc1W = (const float*)d_in[30]; const float* gc1as = (const float*)d_in[31];
    const float* gc1ad = (const float*)d_in[32]; const float* gc1b = (const float*)d_in[33];
    const float* gc2W = (const float*)d_in[34]; const float* gc2as = (const float*)d_in[35];
    const float* gc2ad = (const float*)d_in[36]; const float* gc2b = (const float*)d_in[37];
    const float* tc1W = (const float*)d_in[38]; const float* tc1as = (const float*)d_in[39];
    const float* tc1ad = (const float*)d_in[40]; const float* tc1b = (const float*)d_in[41];
    const float* tc2W = (const float*)d_in[42]; const float* tc2as = (const float*)d_in[43];
    const float* tc2ad = (const float*)d_in[44]; const float* tc2b = (const float*)d_in[45];
    const float* fcW = (const float*)d_in[46]; const float* fcb = (const float*)d_in[47];
    float* out = (float*)d_out;

    char* ws = (char*)d_ws;
    const size_t NEED = 226500000;
    if (ws_size < NEED) return;

    // ---- workspace layout (decimal byte offsets) ----
    float* XGF    = (float*)(ws + 0);            // 12 MB xg_final fp32 [NG][100]
    u16*   TEMB_B = (u16*)(ws + 12000000);       // 12.8 MB [VOC][128]
    u16*   ETAB_G = (u16*)(ws + 25000000);       // 30.4 MB [VOC][304]
    u16*   ETAB_T = (u16*)(ws + 60400000);       // 30.4 MB
    u16*   GH1B   = (u16*)(ws + 96000000);       // 2.56 MB [NTG][128]
    u16*   TH1B   = (u16*)(ws + 98600000);       // 7.68 MB [NTREE][128]
    float* UE     = (float*)(ws + 106400000);    // 8 MB
    float* HID    = (float*)(ws + 114400000);    // 8 MB
    u16*   WARENA = (u16*)(ws + 122400000);      // ~0.97 MB (1.2 MB region)
    int*   GOFF   = (int*)(ws + 123600000);
    int*   GCUR   = (int*)(ws + 123800000);
    int*   GCNT   = (int*)(ws + 124000000);
    int*   GEIDX  = (int*)(ws + 124200000);      // 0.92 MB
    int*   TOFF   = (int*)(ws + 125200000);
    int*   TCUR   = (int*)(ws + 125400000);
    int*   TCNT   = (int*)(ws + 125600000);
    int*   TEIDX  = (int*)(ws + 125800000);      // 0.36 MB
    float* ESB    = (float*)(ws + 126200000);
    float* EDB    = (float*)(ws + 127200000);
    float* MB     = (float*)(ws + 128200000);
    float* SB     = (float*)(ws + 129200000);
    float* EBB    = (float*)(ws + 130200000);    // 7.36 MB
    float* SSUM   = (float*)(ws + 137600000);
    float* SCNT   = (float*)(ws + 137700000);
    u16*   XG_B   = (u16*)(ws + 138000000);      // 7.68 MB [NG][128]
    u16*   GFEAT1 = (u16*)(ws + 146000000);      // 30.72 MB [NG][512]
    u16*   GOUT1B = (u16*)(ws + 177000000);      // 30.72 MB
    u16*   GFEAT2 = (u16*)(ws + 208000000);      // 6 MB [NG][100]
    u16*   TFEAT1 = (u16*)(ws + 25000000);       // 48 MB [NTREE][800] (overlays Etabs, dead)
    u16*   TOUT1B = (u16*)(ws + 146000000);      // 48 MB (overlays GFEAT1/GOUT1B, dead)
    u16*   TFEAT2 = (u16*)(ws + 208000000);      // 6 MB (overlay GFEAT2, dead)
    float* XOUT2  = (float*)(ws + 214400000);    // 12 MB -> 226.4 MB

    // weight arena slots (u16 element offsets); each GRU W = [336][128]
    u16* gWHH0 = WARENA + 0;
    u16* gWIH1 = WARENA + 43008;
    u16* gWHH1 = WARENA + 86016;
    u16* tWHH0 = WARENA + 129024;
    u16* tWIH1 = WARENA + 172032;
    u16* tWHH1 = WARENA + 215040;
    u16* W_IH0 = WARENA + 258048;    // [320][128] scratch for Etab builds
    u16* W_G1  = WARENA + 299008;    // up to [800][128]
    u16* W_G2  = WARENA + 401408;    // up to [100][800]  -> end 481408 u16

    auto cvt = [&](const float* src, u16* dst, int M, int Mp, int K, int ldk,
                   const float* app = nullptr, int appone = 0) {
        convert_pad2<<<((size_t)Mp * ldk + 255) / 256, 256, 0, stream>>>(
            src, dst, M, Mp, K, ldk, app, appone);
    };
    auto cvtg = [&](const float* src, u16* dst, const float* bias) {
        convert_gru_w<<<(WROWS * 128 + 255) / 256, 256, 0, stream>>>(src, dst, bias);
    };
    auto mfma = [&](const u16* A, int lda, const u16* W, int ldw,
                    float* Cf, u16* Cb, int ldc, int M, int N, int Kt) {
        dim3 grid((M + 63) / 64, (N + 63) / 64, 1);
        gemm_mfma<<<grid, 256, 0, stream>>>(A, W, Cf, Cb, M, N, Kt, lda, ldw, ldc);
    };
    auto csr_build = [&](const int* ei, int E, int N, int* cnt, int* off, int* cur, int* eidx) {
        hipMemsetAsync(cnt, 0, (size_t)N * 4, stream);
        csr_count<<<(E + N + 255) / 256, 256, 0, stream>>>(ei, E, N, cnt);
        csr_scan<<<1, 256, 0, stream>>>(cnt, off, cur, N);
        csr_scatter<<<(E + N + 255) / 256, 256, 0, stream>>>(ei, E, N, cur, eidx);
    };
    auto gat_pre = [&](const u16* feat, int N, int heads, int C,
                       const float* asrc, const float* adst, const int* ei, int E) {
        gat_es_ed<<<(N * heads + 255) / 256, 256, 0, stream>>>(feat, asrc, adst, ESB, EDB, N, heads, C);
        hipMemsetAsync(MB, 0xFF, (size_t)N * heads * 4, stream);
        hipMemsetAsync(SB, 0, (size_t)N * heads * 4, stream);
        int EE = E + N;
        gat_edge_logit<<<(EE * heads + 255) / 256, 256, 0, stream>>>(ei, E, N, heads, ESB, EDB, EBB, MB);
        gat_edge_expsum<<<(EE * heads + 255) / 256, 256, 0, stream>>>(ei, E, N, heads, EBB, MB, SB);
    };

    // ---- 1. user embed (fp32) ----
    {
        dim3 g1((NU + 63) / 64, (HD + 63) / 64, 1);
        gemm_nt<<<g1, 256, 0, stream>>>(user_feats, uW1, ub1, HID, NU, HD, 9, 1);
        gemm_nt<<<g1, 256, 0, stream>>>(HID, uW2, ub2, UE, NU, HD, HD, 0);
    }

    // ---- 2. converts (+bias fold into col 100) + Etab builds ----
    cvt(temb, TEMB_B, VOC, VOC, HD, 128, nullptr, 1);           // col100 = 1
    cvtg(gW[0][1], gWHH0, gW[0][3]);                            // + bhh0 (gate-padded)
    cvtg(gW[1][0], gWIH1, gW[1][2]);                            // + bih1
    cvtg(gW[1][1], gWHH1, gW[1][3]);                            // + bhh1
    cvtg(tW[0][1], tWHH0, tW[0][3]);
    cvtg(tW[1][0], tWIH1, tW[1][2]);
    cvtg(tW[1][1], tWHH1, tW[1][3]);
    cvt(gW[0][0], W_IH0, 300, 320, HD, 128, gW[0][2]);          // + bih0 (old layout for Etab)
    mfma(TEMB_B, 128, W_IH0, 128, nullptr, ETAB_G, ESTR, VOC, 300, 4);
    cvt(tW[0][0], W_IH0, 300, 320, HD, 128, tW[0][2]);
    mfma(TEMB_B, 128, W_IH0, 128, nullptr, ETAB_T, ESTR, VOC, 300, 4);

    // CSR for both graphs
    csr_build(gei, EG, NG, GCNT, GOFF, GCUR, GEIDX);
    csr_build(tei, ET, NTREE, TCNT, TOFF, TCUR, TEIDX);

    // ---- 3. combined GRU (both branches, one launch) ----
    {
        GruProb Pg = { ETAB_G, gnf, h0g, gWHH0, gWIH1, gWHH1, GH1B, NTG };
        GruProb Pt = { ETAB_T, tnf, h0t, tWHH0, tWIH1, tWHH1, TH1B, NTREE };
        int gblk = (NTG + 31) / 32;      // 313
        int tblk = (NTREE + 31) / 32;    // 938
        gru_fused6<<<gblk + tblk, 512, 0, stream>>>(Pg, Pt, gblk);
    }

    // ---- 4. graph GAT chain ----
    build_xg_bf<<<(NG * 128 + 255) / 256, 256, 0, stream>>>(GH1B, UE, XG_B);
    cvt(gc1W, W_G1, 512, 512, HD, 128);
    cvt(gc2W, W_G2, 100, 100, 512, 512);
    {   // graph GAT1: 8 heads x 64
        mfma(XG_B, 128, W_G1, 128, nullptr, GFEAT1, 512, NG, 512, 4);
        gat_pre(GFEAT1, NG, 8, 64, gc1as, gc1ad, gei, EG);
        int waves = NG * 2;
        gat_accum_csr<64, 4><<<(waves + 3) / 4, 256, 0, stream>>>(
            GOFF, GEIDX, gei, EG, EBB, SB, GFEAT1, gc1b, nullptr, GOUT1B, NG, 8, 512, 2);
    }
    {   // graph GAT2: 1 head x 100
        mfma(GOUT1B, 512, W_G2, 512, nullptr, GFEAT2, 100, NG, 100, 16);
        gat_pre(GFEAT2, NG, 1, 100, gc2as, gc2ad, gei, EG);
        int waves = NG;
        gat_accum_csr<100, 2><<<(waves + 3) / 4, 256, 0, stream>>>(
            GOFF, GEIDX, gei, EG, EBB, SB, GFEAT2, gc2b, XGF, nullptr, NG, 1, 100, 1);
    }

    // ---- 5. tree GAT chain ----
    set_roots<<<(NB * HD + 255) / 256, 256, 0, stream>>>(XGF, TH1B);
    cvt(tc1W, W_G1, 800, 800, HD, 128);
    cvt(tc2W, W_G2, 100, 100, 800, 800);
    {   // tree GAT1: 8 heads x 100
        mfma(TH1B, 128, W_G1, 128, nullptr, TFEAT1, 800, NTREE, 800, 4);
        gat_pre(TFEAT1, NTREE, 8, 100, tc1as, tc1ad, tei, ET);
        int waves = NTREE * 4;
        gat_accum_csr<100, 4><<<(waves + 3) / 4, 256, 0, stream>>>(
            TOFF, TEIDX, tei, ET, EBB, SB, TFEAT1, tc1b, nullptr, TOUT1B, NTREE, 8, 800, 4);
    }
    {   // tree GAT2: 1 head x 100
        mfma(TOUT1B, 800, W_G2, 800, nullptr, TFEAT2, 100, NTREE, 100, 25);
        gat_pre(TFEAT2, NTREE, 1, 100, tc2as, tc2ad, tei, ET);
        int waves = NTREE;
        gat_accum_csr<100, 2><<<(waves + 3) / 4, 256, 0, stream>>>(
            TOFF, TEIDX, tei, ET, EBB, SB, TFEAT2, tc2b, XOUT2, nullptr, NTREE, 1, 100, 1);
    }

    // ---- 6. scatter_mean + classifier ----
    hipMemsetAsync(SSUM, 0, (size_t)NB * HD * 4, stream);
    hipMemsetAsync(SCNT, 0, (size_t)NB * 4, stream);
    scatter_mean_accum<<<(NTREE * HD + 255) / 256, 256, 0, stream>>>(XOUT2, indices, SSUM, SCNT);
    fc_out<<<1, 512, 0, stream>>>(SSUM, SCNT, fcW, fcb, out);
}

// Round 2
// 1785.463 us; speedup vs baseline: 1.1067x; 1.0336x over previous
//
#include <hip/hip_runtime.h>

// ---------------------------------------------------------------------------
// Problem constants
// ---------------------------------------------------------------------------
#define NB    128
#define HD    100
#define NU    20000
#define NTG   10000
#define NTREE 30000
#define NG    30000
#define TT    20
#define EG    200000
#define ET    60000
#define VOC   50000

#define ESTR  304   // Etab row stride (u16): 608 B, 16B-aligned
#define WROWS 336   // GRU weight rows: 3 gates x 112 (gate stride 112)

typedef unsigned short u16;
typedef unsigned int   u32;
typedef __attribute__((ext_vector_type(8))) short short8;
typedef __attribute__((ext_vector_type(4))) float floatx4;

__device__ __forceinline__ float sigmoidf_(float x) {
    return __fdividef(1.f, 1.f + __expf(-x));
}
__device__ __forceinline__ float tanhf_(float x) {
    return 1.f - __fdividef(2.f, __expf(2.f * x) + 1.f);
}
__device__ __forceinline__ u16 f2bf(float f) {
    u32 u = __float_as_uint(f);
    u32 r = (u + 0x7fffu + ((u >> 16) & 1u)) >> 16;
    return (u16)r;
}
__device__ __forceinline__ float bf2f(u16 h) {
    return __uint_as_float(((u32)h) << 16);
}

// ---------------------------------------------------------------------------
// Fused 2-layer GRU v7: 448 threads (7 compute waves) / 32 rows / TT steps.
//
// vs v6:
//  - H swizzle fixed to byte ^= ((row&7)<<4): v6's ((row>>2)&3)<<5 left the
//    low 2 row bits unswizzled -> 4-way bank conflict on every ds_read_b128
//    (SQ_LDS_BANK_CONFLICT stuck at 5e7). New mapping: slot = quad ^ (fr&7),
//    conflict-free for b128 A-frag reads; combine u16 writes stay <=2-way.
//  - XB producer wave DELETED. x-gates are consumed once per lane at a known
//    column -> prefetch 24 scalar u16 (3 gates x 8 rows) directly into
//    registers one step ahead (issued end of phase A, consumed next phase A).
//    Node ids staged once into a 2.5KB LDS table. Removes 168 scalar LDS
//    reads + 20 b128 LDS writes per step per block and the producer barrier
//    imbalance. LDS: 72KB -> 35KB.
// ---------------------------------------------------------------------------
struct GruProb {
    const u16*   Etab;     // [VOC][304] (includes bih0)
    const int*   nodes;    // [M][TT]
    const float* h0;       // [2][M][100] fp32
    const u16*   Whh0;     // [336][128] gate-padded (col100 = bhh0)
    const u16*   Wih1;     // (col100 = bih1)
    const u16*   Whh1;     // (col100 = bhh1)
    u16*         hout;     // [M][128]
    int          M;
};

__global__ __launch_bounds__(448, 2) void gru_fused7(GruProb Pg, GruProb Pt, int gblocks)
{
    const bool isg = (int)blockIdx.x < gblocks;
    const GruProb P = isg ? Pg : Pt;
    const int bx = isg ? blockIdx.x : blockIdx.x - gblocks;
    const int M  = P.M;
    const int m0 = bx * 32;

    // h mirrors: [32][128] u16, 256B rows, byte ^= ((row&7)<<4) swizzle
    __shared__ u16 H0[2][32 * 128];
    __shared__ u16 H1[2][32 * 128];
    __shared__ int NID[TT * 32];     // node ids, [t][row]

    const int tid  = threadIdx.x;
    const int w    = tid >> 6, lane = tid & 63;
    const int fr   = lane & 15, quad = lane >> 4;
    const int c    = w * 16 + fr;                 // output column of this lane
    const bool cok = (c < HD);

    // ---- register-resident weight fragments (tiles g*7 + w) ----
    short8 Bh0[3][4], Bx1[3][4], Bh1[3][4];
#pragma unroll
    for (int g = 0; g < 3; ++g) {
        const size_t rb = (size_t)((g * 7 + w) * 16 + fr) * 128 + quad * 8;
#pragma unroll
        for (int kk = 0; kk < 4; ++kk) {
            Bh0[g][kk] = *(const short8*)(P.Whh0 + rb + kk * 32);
            Bx1[g][kk] = *(const short8*)(P.Wih1 + rb + kk * 32);
            Bh1[g][kk] = *(const short8*)(P.Whh1 + rb + kk * 32);
        }
    }

    // ---- zero h mirrors + stage node-id table ----
    for (int i = tid; i < 32 * 128; i += 448) {
        H0[0][i] = 0; H0[1][i] = 0; H1[0][i] = 0; H1[1][i] = 0;
    }
    for (int i = tid; i < 32 * TT; i += 448) {
        int row = i / TT, t = i - row * TT;
        int gm = m0 + row;
        NID[t * 32 + row] = (gm < M) ? P.nodes[(size_t)gm * TT + t] : 0;
    }
    __syncthreads();
    // bias slot col 100 = 1.0 in all four buffers (swizzled position)
    if (tid < 32) {
        int off = 200 ^ ((tid & 7) << 4);        // byte offset within row
        u16* p0a = (u16*)((char*)&H0[0][0] + tid * 256 + off);
        u16* p0b = (u16*)((char*)&H0[1][0] + tid * 256 + off);
        u16* p1a = (u16*)((char*)&H1[0][0] + tid * 256 + off);
        u16* p1b = (u16*)((char*)&H1[1][0] + tid * 256 + off);
        *p0a = 0x3F80; *p0b = 0x3F80; *p1a = 0x3F80; *p1b = 0x3F80;
    }

    // ---- init h carry + LDS mirrors ----
    float h0f[2][4] = {{0.f,0.f,0.f,0.f},{0.f,0.f,0.f,0.f}};
    float h1f[2][4] = {{0.f,0.f,0.f,0.f},{0.f,0.f,0.f,0.f}};
    if (cok) {
#pragma unroll
        for (int rt = 0; rt < 2; ++rt)
#pragma unroll
        for (int r = 0; r < 4; ++r) {
            int row = rt * 16 + quad * 4 + r;
            int gm  = m0 + row;
            float v0 = 0.f, v1 = 0.f;
            if (gm < M) {
                v0 = P.h0[(size_t)gm * HD + c];
                v1 = P.h0[(size_t)(M + gm) * HD + c];
            }
            h0f[rt][r] = v0; h1f[rt][r] = v1;
            int off = (2 * c) ^ ((row & 7) << 4);
            *(u16*)((char*)&H0[0][0] + row * 256 + off) = f2bf(v0);
            *(u16*)((char*)&H1[0][0] + row * 256 + off) = f2bf(v1);
        }
    }

    // ---- x-gate register prefetch: 3 gates x 8 rows at this lane's column ----
    u16 xr[2][4], xz[2][4], xn[2][4];
    auto xpref = [&](int tn) {
        if (cok) {
#pragma unroll
            for (int rt = 0; rt < 2; ++rt)
#pragma unroll
            for (int r = 0; r < 4; ++r) {
                int row = rt * 16 + quad * 4 + r;
                int nd  = NID[tn * 32 + row];
                const u16* ex = P.Etab + (size_t)nd * ESTR + c;
                xr[rt][r] = ex[0];
                xz[rt][r] = ex[100];
                xn[rt][r] = ex[200];
            }
        }
    };
    xpref(0);
    __syncthreads();

    int cur = 0;
    for (int t = 0; t < TT; ++t) {
        // ================= phase A: GEMM0 + combine0 =================
#pragma unroll
        for (int rt = 0; rt < 2; ++rt) {
            short8 a[4];
#pragma unroll
            for (int kk = 0; kk < 4; ++kk) {
                int row = rt * 16 + fr;
                int off = (kk * 64 + quad * 16) ^ ((row & 7) << 4);
                a[kk] = *(const short8*)((const char*)&H0[cur][0] + row * 256 + off);
            }
            floatx4 ag[3];
#pragma unroll
            for (int g = 0; g < 3; ++g) ag[g] = (floatx4){0.f, 0.f, 0.f, 0.f};
#pragma unroll
            for (int g = 0; g < 3; ++g)
#pragma unroll
                for (int kk = 0; kk < 4; ++kk)
                    ag[g] = __builtin_amdgcn_mfma_f32_16x16x32_bf16(a[kk], Bh0[g][kk], ag[g], 0, 0, 0);
            if (cok) {
#pragma unroll
                for (int r = 0; r < 4; ++r) {
                    int row = rt * 16 + quad * 4 + r;
                    float rr = sigmoidf_(bf2f(xr[rt][r]) + ag[0][r]);
                    float zz = sigmoidf_(bf2f(xz[rt][r]) + ag[1][r]);
                    float nn = tanhf_(bf2f(xn[rt][r]) + rr * ag[2][r]);
                    float o  = (1.f - zz) * nn + zz * h0f[rt][r];
                    h0f[rt][r] = o;
                    *(u16*)((char*)&H0[cur ^ 1][0] + row * 256 + ((2 * c) ^ ((row & 7) << 4))) = f2bf(o);
                }
            }
        }
        // prefetch x-gates for t+1 (latency covered by phase B + next GEMM0)
        if (t + 1 < TT) xpref(t + 1);
        __syncthreads();   // the ONE barrier per step

        // ================= phase B: GEMM1 + combine1 =================
#pragma unroll
        for (int rt = 0; rt < 2; ++rt) {
            short8 a0[4], a1[4];
#pragma unroll
            for (int kk = 0; kk < 4; ++kk) {
                int row = rt * 16 + fr;
                int off = (kk * 64 + quad * 16) ^ ((row & 7) << 4);
                a0[kk] = *(const short8*)((const char*)&H0[cur ^ 1][0] + row * 256 + off);
                a1[kk] = *(const short8*)((const char*)&H1[cur][0]     + row * 256 + off);
            }
            floatx4 ax[3], ah[3];
#pragma unroll
            for (int g = 0; g < 3; ++g) {
                ax[g] = (floatx4){0.f, 0.f, 0.f, 0.f};
                ah[g] = (floatx4){0.f, 0.f, 0.f, 0.f};
            }
#pragma unroll
            for (int g = 0; g < 3; ++g)
#pragma unroll
                for (int kk = 0; kk < 4; ++kk) {
                    ax[g] = __builtin_amdgcn_mfma_f32_16x16x32_bf16(a0[kk], Bx1[g][kk], ax[g], 0, 0, 0);
                    ah[g] = __builtin_amdgcn_mfma_f32_16x16x32_bf16(a1[kk], Bh1[g][kk], ah[g], 0, 0, 0);
                }
            if (cok) {
#pragma unroll
                for (int r = 0; r < 4; ++r) {
                    int row = rt * 16 + quad * 4 + r;
                    float rr = sigmoidf_(ax[0][r] + ah[0][r]);
                    float zz = sigmoidf_(ax[1][r] + ah[1][r]);
                    float nn = tanhf_(ax[2][r] + rr * ah[2][r]);
                    float o  = (1.f - zz) * nn + zz * h1f[rt][r];
                    h1f[rt][r] = o;
                    *(u16*)((char*)&H1[cur ^ 1][0] + row * 256 + ((2 * c) ^ ((row & 7) << 4))) = f2bf(o);
                }
            }
        }
        cur ^= 1;
    }
    __syncthreads();

    // ---- write final top-layer hidden, bf16 [M][128] (de-swizzle) ----
    for (int i = tid; i < 32 * 128; i += 448) {
        int row = i >> 7, cc = i & 127;
        int gm = m0 + row;
        if (gm < M) {
            int off = (2 * cc) ^ ((row & 7) << 4);
            P.hout[(size_t)gm * 128 + cc] = *(const u16*)((const char*)&H1[cur][0] + row * 256 + off);
        }
    }
}

// ---------------------------------------------------------------------------
// bf16 MFMA GEMM (Etab build + GAT feature GEMMs)
// ---------------------------------------------------------------------------
#define LDST 40
__global__ __launch_bounds__(256) void gemm_mfma(
    const u16* __restrict__ A, const u16* __restrict__ B,
    float* __restrict__ Cf, u16* __restrict__ Cb,
    int M, int N, int Kt, int lda, int ldw, int ldc)
{
    const int m0 = blockIdx.x * 64;
    if (m0 >= M) return;
    const int n0 = blockIdx.y * 64;

    __shared__ u16 Als[64 * LDST];
    __shared__ u16 Wls[64 * LDST];

    const int tid  = threadIdx.x;
    const int wave = tid >> 6, lane = tid & 63;
    const int row  = tid >> 2, part = (tid & 3) * 8;
    const int fr   = lane & 15, quad = lane >> 4;

    floatx4 acc[4];
#pragma unroll
    for (int t = 0; t < 4; ++t) acc[t] = (floatx4){0.f, 0.f, 0.f, 0.f};

    const int am = m0 + row;  const bool aok = am < M;
    const int wn = n0 + row;  const bool wok = wn < N;
    const uint4 z4 = {0u, 0u, 0u, 0u};

    for (int kk = 0; kk < Kt; ++kk) {
        uint4 av = aok ? *(const uint4*)(A + (size_t)am * lda + kk * 32 + part) : z4;
        uint4 wv = wok ? *(const uint4*)(B + (size_t)wn * ldw + kk * 32 + part) : z4;
        __syncthreads();
        *(uint4*)&Als[row * LDST + part] = av;
        *(uint4*)&Wls[row * LDST + part] = wv;
        __syncthreads();
        short8 af = *(const short8*)&Als[((wave << 4) + fr) * LDST + quad * 8];
#pragma unroll
        for (int t = 0; t < 4; ++t) {
            short8 bf = *(const short8*)&Wls[((t << 4) + fr) * LDST + quad * 8];
            acc[t] = __builtin_amdgcn_mfma_f32_16x16x32_bf16(af, bf, acc[t], 0, 0, 0);
        }
    }

    const int orow0 = m0 + (wave << 4) + quad * 4;
#pragma unroll
    for (int t = 0; t < 4; ++t) {
        int col = n0 + (t << 4) + fr;
        if (col >= N) continue;
#pragma unroll
        for (int r = 0; r < 4; ++r) {
            int mr = orow0 + r;
            if (mr >= M) continue;
            float v = acc[t][r];
            if (Cf) Cf[(size_t)mr * ldc + col] = v;
            if (Cb) Cb[(size_t)mr * ldc + col] = f2bf(v);
        }
    }
}

// ---------------------------------------------------------------------------
// fp32 tiled GEMM (user-embed MLP only)
// ---------------------------------------------------------------------------
__global__ __launch_bounds__(256) void gemm_nt(
    const float* __restrict__ A, const float* __restrict__ W,
    const float* __restrict__ bias, float* __restrict__ C,
    int M, int N, int K, int relu)
{
    const int m0 = blockIdx.x * 64;
    const int n0 = blockIdx.y * 64;
    __shared__ float As[20][68];
    __shared__ float Ws[20][68];
    const int tid = threadIdx.x;
    const int r0 = (tid >> 4) * 4;
    const int c0 = (tid & 15) * 4;
    int sr[5], sk[5];
#pragma unroll
    for (int it = 0; it < 5; ++it) {
        int idx = tid + it * 256;
        sr[it] = idx / 20; sk[it] = idx - sr[it] * 20;
    }
    float acc[4][4];
#pragma unroll
    for (int i = 0; i < 4; ++i)
#pragma unroll
        for (int j = 0; j < 4; ++j) acc[i][j] = 0.f;
    const int nch = (K + 19) / 20;
    for (int ch = 0; ch < nch; ++ch) {
        const int k0 = ch * 20;
#pragma unroll
        for (int it = 0; it < 5; ++it) {
            int m = m0 + sr[it], k = k0 + sk[it];
            float va = 0.f, vw = 0.f;
            if (k < K) {
                if (m < M) va = A[(size_t)m * K + k];
                int n = n0 + sr[it];
                if (n < N) vw = W[(size_t)n * K + k];
            }
            As[sk[it]][sr[it]] = va;
            Ws[sk[it]][sr[it]] = vw;
        }
        __syncthreads();
#pragma unroll
        for (int kkk = 0; kkk < 20; ++kkk) {
            float4 a = *(const float4*)&As[kkk][r0];
            float4 w = *(const float4*)&Ws[kkk][c0];
            float av[4] = {a.x, a.y, a.z, a.w};
            float wv[4] = {w.x, w.y, w.z, w.w};
#pragma unroll
            for (int i = 0; i < 4; ++i)
#pragma unroll
                for (int j = 0; j < 4; ++j)
                    acc[i][j] = fmaf(av[i], wv[j], acc[i][j]);
        }
        __syncthreads();
    }
#pragma unroll
    for (int i = 0; i < 4; ++i) {
        int m = m0 + r0 + i;
        if (m >= M) continue;
#pragma unroll
        for (int j = 0; j < 4; ++j) {
            int n = n0 + c0 + j;
            if (n >= N) continue;
            float v = acc[i][j] + (bias ? bias[n] : 0.f);
            if (relu) v = fmaxf(v, 0.f);
            C[(size_t)m * N + n] = v;
        }
    }
}

// fp32 [M][K] -> bf16 [Mp][ldk]; col K..ldk zero, except col 100 gets
// app[n] (if app) or 1.0 (if appone) — the K-slot bias fold.
__global__ void convert_pad2(const float* __restrict__ src, u16* __restrict__ dst,
                             int M, int Mp, int K, int ldk,
                             const float* __restrict__ app, int appone)
{
    int t = blockIdx.x * blockDim.x + threadIdx.x;
    if (t >= Mp * ldk) return;
    int n = t / ldk, c = t - n * ldk;
    u16 o = 0;
    if (n < M) {
        if (c < K) o = f2bf(src[(size_t)n * K + c]);
        else if (c == 100) {
            if (app) o = f2bf(app[n]);
            else if (appone) o = 0x3F80;
        }
    }
    dst[t] = o;
}

// GRU weight -> gate-padded bf16 [336][128]: gates r/z/n at row offsets
// 0/112/224; col100 = bias; everything else zero.
__global__ void convert_gru_w(const float* __restrict__ src, u16* __restrict__ dst,
                              const float* __restrict__ bias)
{
    int t = blockIdx.x * blockDim.x + threadIdx.x;
    if (t >= WROWS * 128) return;
    int rr = t >> 7, c = t & 127;
    int g = rr / 112, r2 = rr - g * 112;
    u16 o = 0;
    if (r2 < 100) {
        int sr = g * 100 + r2;
        if (c < 100) o = f2bf(src[(size_t)sr * 100 + c]);
        else if (c == 100) o = f2bf(bias[sr]);
    }
    dst[t] = o;
}

// xg (bf16 [NG][128]) = concat(hg[:128], ue, hg[128:])
__global__ void build_xg_bf(const u16* __restrict__ hgb, const float* __restrict__ ue,
                            u16* __restrict__ xgb)
{
    int t = blockIdx.x * blockDim.x + threadIdx.x;
    if (t >= NG * 128) return;
    int n = t >> 7, c = t & 127;
    u16 o = 0;
    if (n < NB)           o = hgb[n * 128 + c];
    else if (n < NB + NU) { if (c < HD) o = f2bf(ue[(size_t)(n - NB) * HD + c]); }
    else                  o = hgb[(size_t)(n - NU) * 128 + c];
    xgb[t] = o;
}

// tree roots: hb rows[0:128) <- xg_final fp32
__global__ void set_roots(const float* __restrict__ src, u16* __restrict__ hb)
{
    int t = blockIdx.x * blockDim.x + threadIdx.x;
    if (t >= NB * HD) return;
    int n = t / HD, c = t - n * HD;
    hb[(size_t)n * 128 + c] = f2bf(src[t]);
}

// ---------------------------------------------------------------------------
// CSR build
// ---------------------------------------------------------------------------
__global__ void csr_count(const int* __restrict__ ei, int E, int N, int* __restrict__ cnt)
{
    int e = blockIdx.x * blockDim.x + threadIdx.x;
    if (e >= E + N) return;
    int dst = (e < E) ? ei[E + e] : e - E;
    atomicAdd(&cnt[dst], 1);
}

__global__ void csr_scan(const int* __restrict__ cnt, int* __restrict__ off,
                         int* __restrict__ cur, int N)
{
    __shared__ int part[256];
    const int tid = threadIdx.x;
    const int per = (N + 255) / 256;
    const int i0 = tid * per;
    const int i1 = min(i0 + per, N);
    int s = 0;
    for (int i = i0; i < i1; ++i) s += cnt[i];
    part[tid] = s;
    __syncthreads();
    for (int o = 1; o < 256; o <<= 1) {
        int u = (tid >= o) ? part[tid - o] : 0;
        __syncthreads();
        part[tid] += u;
        __syncthreads();
    }
    int base = part[tid] - s;
    for (int i = i0; i < i1; ++i) {
        off[i] = base; cur[i] = base;
        base += cnt[i];
    }
    if (tid == 255) off[N] = part[255];
}

__global__ void csr_scatter(const int* __restrict__ ei, int E, int N,
                            int* __restrict__ cur, int* __restrict__ eidx)
{
    int e = blockIdx.x * blockDim.x + threadIdx.x;
    if (e >= E + N) return;
    int dst = (e < E) ? ei[E + e] : e - E;
    int pos = atomicAdd(&cur[dst], 1);
    eidx[pos] = e;
}

// ---------------------------------------------------------------------------
// GAT pieces (feat is bf16)
// ---------------------------------------------------------------------------
__global__ void gat_es_ed(const u16* __restrict__ feat, const float* __restrict__ asrc,
                          const float* __restrict__ adst, float* __restrict__ es,
                          float* __restrict__ ed, int N, int heads, int C)
{
    int gid = blockIdx.x * blockDim.x + threadIdx.x;
    if (gid >= N * heads) return;
    int n = gid / heads, hd = gid - n * heads;
    const u16* hp = feat + ((size_t)n * heads + hd) * C;
    const float* as = asrc + (size_t)hd * C;
    const float* ad = adst + (size_t)hd * C;
    float s1 = 0.f, s2 = 0.f;
    for (int c = 0; c < C; c += 4) {
        uint2 pk = *(const uint2*)(hp + c);
        float v0 = bf2f((u16)(pk.x & 0xffff)), v1 = bf2f((u16)(pk.x >> 16));
        float v2 = bf2f((u16)(pk.y & 0xffff)), v3 = bf2f((u16)(pk.y >> 16));
        s1 += v0 * as[c] + v1 * as[c + 1] + v2 * as[c + 2] + v3 * as[c + 3];
        s2 += v0 * ad[c] + v1 * ad[c + 1] + v2 * ad[c + 2] + v3 * ad[c + 3];
    }
    es[gid] = s1; ed[gid] = s2;
}

__device__ __forceinline__ void atomic_max_f(float* addr, float v)
{
    if (v >= 0.f) atomicMax((int*)addr, __float_as_int(v));
    else          atomicMin((unsigned int*)addr, __float_as_uint(v));
}

__global__ void gat_edge_logit(const int* __restrict__ ei, int E, int N, int heads,
                               const float* __restrict__ es, const float* __restrict__ ed,
                               float* __restrict__ eb, float* __restrict__ m)
{
    int gid = blockIdx.x * blockDim.x + threadIdx.x;
    int EE = E + N;
    if (gid >= EE * heads) return;
    int idx = gid / heads, hd = gid - idx * heads;
    int src, dst;
    if (idx < E) { src = ei[idx]; dst = ei[E + idx]; } else { src = dst = idx - E; }
    float e = es[src * heads + hd] + ed[dst * heads + hd];
    e = e > 0.f ? e : 0.2f * e;
    eb[gid] = e;
    atomic_max_f(&m[dst * heads + hd], e);
}

__global__ void gat_edge_expsum(const int* __restrict__ ei, int E, int N, int heads,
                                float* __restrict__ eb, const float* __restrict__ m,
                                float* __restrict__ s)
{
    int gid = blockIdx.x * blockDim.x + threadIdx.x;
    int EE = E + N;
    if (gid >= EE * heads) return;
    int idx = gid / heads, hd = gid - idx * heads;
    int dst = (idx < E) ? ei[E + idx] : idx - E;
    float e = __expf(eb[gid] - m[dst * heads + hd]);
    eb[gid] = e;
    atomicAdd(&s[dst * heads + hd], e);
}

template<int C, int VEC>
__global__ __launch_bounds__(256) void gat_accum_csr(
    const int* __restrict__ off, const int* __restrict__ eidx,
    const int* __restrict__ ei, int E,
    const float* __restrict__ eb, const float* __restrict__ s,
    const u16* __restrict__ feat, const float* __restrict__ bias,
    float* __restrict__ outf, u16* __restrict__ outb,
    int N, int heads, int HC, int nchunk)
{
    int gt = blockIdx.x * blockDim.x + threadIdx.x;
    int w = gt >> 6, lane = gt & 63;
    int dst = w / nchunk, chunk = w - dst * nchunk;
    if (dst >= N) return;
    int c0 = chunk * 64 * VEC + lane * VEC;
    if (c0 >= HC) return;
    int hh[VEC]; float sinv[VEC], acc[VEC];
#pragma unroll
    for (int v = 0; v < VEC; ++v) {
        int c = c0 + v;
        hh[v] = c / C;
        sinv[v] = __fdividef(1.f, s[dst * heads + hh[v]]);
        acc[v] = 0.f;
    }
    int e0 = off[dst], e1 = off[dst + 1];
    for (int p = e0; p < e1; ++p) {
        int j = eidx[p];
        int src = (j < E) ? ei[j] : (j - E);
        const u16* frp = feat + (size_t)src * HC + c0;
        float fv[VEC];
        if (VEC == 4) {
            uint2 pk = *(const uint2*)frp;
            fv[0] = bf2f((u16)(pk.x & 0xffff)); fv[1] = bf2f((u16)(pk.x >> 16));
            fv[2] = bf2f((u16)(pk.y & 0xffff)); fv[3] = bf2f((u16)(pk.y >> 16));
        } else {
            u32 pk = *(const u32*)frp;
            fv[0] = bf2f((u16)(pk & 0xffff)); fv[1] = bf2f((u16)(pk >> 16));
        }
#pragma unroll
        for (int v = 0; v < VEC; ++v)
            acc[v] += fv[v] * eb[(size_t)j * heads + hh[v]] * sinv[v];
    }
#pragma unroll
    for (int v = 0; v < VEC; ++v) {
        int c = c0 + v;
        float o = fmaxf(acc[v] + bias[c], 0.f);
        if (outf) outf[(size_t)dst * HC + c] = o;
        if (outb) outb[(size_t)dst * HC + c] = f2bf(o);
    }
}

__global__ void scatter_mean_accum(const float* __restrict__ x, const int* __restrict__ idx,
                                   float* __restrict__ ssum, float* __restrict__ cnt)
{
    int t = blockIdx.x * blockDim.x + threadIdx.x;
    if (t >= NTREE * HD) return;
    int n = t / HD, c = t - n * HD;
    int b = idx[n];
    atomicAdd(&ssum[b * HD + c], x[t]);
    if (c == 0) atomicAdd(&cnt[b], 1.f);
}

__global__ void fc_out(const float* __restrict__ ssum, const float* __restrict__ cnt,
                       const float* __restrict__ W, const float* __restrict__ b,
                       float* __restrict__ out)
{
    int t = threadIdx.x;                 // 512 threads
    int bb = t >> 2, j = t & 3;
    float inv = __fdividef(1.f, fmaxf(cnt[bb], 1.f));
    float acc = b[j];
    for (int k = 0; k < HD; ++k) acc += ssum[bb * HD + k] * inv * W[j * HD + k];
    out[t] = acc;
}

// ---------------------------------------------------------------------------
// Host launcher
// ---------------------------------------------------------------------------
extern "C" void kernel_launch(void* const* d_in, const int* in_sizes, int n_in,
                              void* d_out, int out_size, void* d_ws, size_t ws_size,
                              hipStream_t stream)
{
    const float* user_feats = (const float*)d_in[1];
    const int*   gnf        = (const int*)d_in[2];
    const int*   gei        = (const int*)d_in[3];
    const int*   tnf        = (const int*)d_in[4];
    const int*   tei        = (const int*)d_in[5];
    const int*   indices    = (const int*)d_in[6];
    const float* h0g        = (const float*)d_in[7];
    const float* h0t        = (const float*)d_in[8];
    const float* temb       = (const float*)d_in[9];
    const float* gW[2][4] = {{(const float*)d_in[10], (const float*)d_in[11], (const float*)d_in[12], (const float*)d_in[13]},
                             {(const float*)d_in[14], (const float*)d_in[15], (const float*)d_in[16], (const float*)d_in[17]}};
    const float* tW[2][4] = {{(const float*)d_in[18], (const float*)d_in[19], (const float*)d_in[20], (const float*)d_in[21]},
                             {(const float*)d_in[22], (const float*)d_in[23], (const float*)d_in[24], (const float*)d_in[25]}};
    const float* uW1 = (const float*)d_in[26]; const float* ub1 = (const float*)d_in[27];
    const float* uW2 = (const float*)d_in[28]; const float* ub2 = (const float*)d_in[29];
    const float* gc1W = (const float*)d_in[30]; const float* gc1as = (const float*)d_in[31];
    const float* gc1ad = (const float*)d_in[32]; const float* gc1b = (const float*)d_in[33];
    const float* gc2W = (const float*)d_in[34]; const float* gc2as = (const float*)d_in[35];
    const float* gc2ad = (const float*)d_in[36]; const float* gc2b = (const float*)d_in[37];
    const float* tc1W = (const float*)d_in[38]; const float* tc1as = (const float*)d_in[39];
    const float* tc1ad = (const float*)d_in[40]; const float* tc1b = (const float*)d_in[41];
    const float* tc2W = (const float*)d_in[42]; const float* tc2as = (const float*)d_in[43];
    const float* tc2ad = (const float*)d_in[44]; const float* tc2b = (const float*)d_in[45];
    const float* fcW = (const float*)d_in[46]; const float* fcb = (const float*)d_in[47];
    float* out = (float*)d_out;

    char* ws = (char*)d_ws;
    const size_t NEED = 226500000;
    if (ws_size < NEED) return;

    // ---- workspace layout (decimal byte offsets) ----
    float* XGF    = (float*)(ws + 0);            // 12 MB xg_final fp32 [NG][100]
    u16*   TEMB_B = (u16*)(ws + 12000000);       // 12.8 MB [VOC][128]
    u16*   ETAB_G = (u16*)(ws + 25000000);       // 30.4 MB [VOC][304]
    u16*   ETAB_T = (u16*)(ws + 60400000);       // 30.4 MB
    u16*   GH1B   = (u16*)(ws + 96000000);       // 2.56 MB [NTG][128]
    u16*   TH1B   = (u16*)(ws + 98600000);       // 7.68 MB [NTREE][128]
    float* UE     = (float*)(ws + 106400000);    // 8 MB
    float* HID    = (float*)(ws + 114400000);    // 8 MB
    u16*   WARENA = (u16*)(ws + 122400000);      // ~0.97 MB (1.2 MB region)
    int*   GOFF   = (int*)(ws + 123600000);
    int*   GCUR   = (int*)(ws + 123800000);
    int*   GCNT   = (int*)(ws + 124000000);
    int*   GEIDX  = (int*)(ws + 124200000);      // 0.92 MB
    int*   TOFF   = (int*)(ws + 125200000);
    int*   TCUR   = (int*)(ws + 125400000);
    int*   TCNT   = (int*)(ws + 125600000);
    int*   TEIDX  = (int*)(ws + 125800000);      // 0.36 MB
    float* ESB    = (float*)(ws + 126200000);
    float* EDB    = (float*)(ws + 127200000);
    float* MB     = (float*)(ws + 128200000);
    float* SB     = (float*)(ws + 129200000);
    float* EBB    = (float*)(ws + 130200000);    // 7.36 MB
    float* SSUM   = (float*)(ws + 137600000);
    float* SCNT   = (float*)(ws + 137700000);
    u16*   XG_B   = (u16*)(ws + 138000000);      // 7.68 MB [NG][128]
    u16*   GFEAT1 = (u16*)(ws + 146000000);      // 30.72 MB [NG][512]
    u16*   GOUT1B = (u16*)(ws + 177000000);      // 30.72 MB
    u16*   GFEAT2 = (u16*)(ws + 208000000);      // 6 MB [NG][100]
    u16*   TFEAT1 = (u16*)(ws + 25000000);       // 48 MB [NTREE][800] (overlays Etabs, dead)
    u16*   TOUT1B = (u16*)(ws + 146000000);      // 48 MB (overlays GFEAT1/GOUT1B, dead)
    u16*   TFEAT2 = (u16*)(ws + 208000000);      // 6 MB (overlay GFEAT2, dead)
    float* XOUT2  = (float*)(ws + 214400000);    // 12 MB -> 226.4 MB

    // weight arena slots (u16 element offsets); each GRU W = [336][128]
    u16* gWHH0 = WARENA + 0;
    u16* gWIH1 = WARENA + 43008;
    u16* gWHH1 = WARENA + 86016;
    u16* tWHH0 = WARENA + 129024;
    u16* tWIH1 = WARENA + 172032;
    u16* tWHH1 = WARENA + 215040;
    u16* W_IH0 = WARENA + 258048;    // [320][128] scratch for Etab builds
    u16* W_G1  = WARENA + 299008;    // up to [800][128]
    u16* W_G2  = WARENA + 401408;    // up to [100][800]  -> end 481408 u16

    auto cvt = [&](const float* src, u16* dst, int M, int Mp, int K, int ldk,
                   const float* app = nullptr, int appone = 0) {
        convert_pad2<<<((size_t)Mp * ldk + 255) / 256, 256, 0, stream>>>(
            src, dst, M, Mp, K, ldk, app, appone);
    };
    auto cvtg = [&](const float* src, u16* dst, const float* bias) {
        convert_gru_w<<<(WROWS * 128 + 255) / 256, 256, 0, stream>>>(src, dst, bias);
    };
    auto mfma = [&](const u16* A, int lda, const u16* W, int ldw,
                    float* Cf, u16* Cb, int ldc, int M, int N, int Kt) {
        dim3 grid((M + 63) / 64, (N + 63) / 64, 1);
        gemm_mfma<<<grid, 256, 0, stream>>>(A, W, Cf, Cb, M, N, Kt, lda, ldw, ldc);
    };
    auto csr_build = [&](const int* ei, int E, int N, int* cnt, int* off, int* cur, int* eidx) {
        hipMemsetAsync(cnt, 0, (size_t)N * 4, stream);
        csr_count<<<(E + N + 255) / 256, 256, 0, stream>>>(ei, E, N, cnt);
        csr_scan<<<1, 256, 0, stream>>>(cnt, off, cur, N);
        csr_scatter<<<(E + N + 255) / 256, 256, 0, stream>>>(ei, E, N, cur, eidx);
    };
    auto gat_pre = [&](const u16* feat, int N, int heads, int C,
                       const float* asrc, const float* adst, const int* ei, int E) {
        gat_es_ed<<<(N * heads + 255) / 256, 256, 0, stream>>>(feat, asrc, adst, ESB, EDB, N, heads, C);
        hipMemsetAsync(MB, 0xFF, (size_t)N * heads * 4, stream);
        hipMemsetAsync(SB, 0, (size_t)N * heads * 4, stream);
        int EE = E + N;
        gat_edge_logit<<<(EE * heads + 255) / 256, 256, 0, stream>>>(ei, E, N, heads, ESB, EDB, EBB, MB);
        gat_edge_expsum<<<(EE * heads + 255) / 256, 256, 0, stream>>>(ei, E, N, heads, EBB, MB, SB);
    };

    // ---- 1. user embed (fp32) ----
    {
        dim3 g1((NU + 63) / 64, (HD + 63) / 64, 1);
        gemm_nt<<<g1, 256, 0, stream>>>(user_feats, uW1, ub1, HID, NU, HD, 9, 1);
        gemm_nt<<<g1, 256, 0, stream>>>(HID, uW2, ub2, UE, NU, HD, HD, 0);
    }

    // ---- 2. converts (+bias fold into col 100) + Etab builds ----
    cvt(temb, TEMB_B, VOC, VOC, HD, 128, nullptr, 1);           // col100 = 1
    cvtg(gW[0][1], gWHH0, gW[0][3]);                            // + bhh0 (gate-padded)
    cvtg(gW[1][0], gWIH1, gW[1][2]);                            // + bih1
    cvtg(gW[1][1], gWHH1, gW[1][3]);                            // + bhh1
    cvtg(tW[0][1], tWHH0, tW[0][3]);
    cvtg(tW[1][0], tWIH1, tW[1][2]);
    cvtg(tW[1][1], tWHH1, tW[1][3]);
    cvt(gW[0][0], W_IH0, 300, 320, HD, 128, gW[0][2]);          // + bih0 (old layout for Etab)
    mfma(TEMB_B, 128, W_IH0, 128, nullptr, ETAB_G, ESTR, VOC, 300, 4);
    cvt(tW[0][0], W_IH0, 300, 320, HD, 128, tW[0][2]);
    mfma(TEMB_B, 128, W_IH0, 128, nullptr, ETAB_T, ESTR, VOC, 300, 4);

    // CSR for both graphs
    csr_build(gei, EG, NG, GCNT, GOFF, GCUR, GEIDX);
    csr_build(tei, ET, NTREE, TCNT, TOFF, TCUR, TEIDX);

    // ---- 3. combined GRU (both branches, one launch) ----
    {
        GruProb Pg = { ETAB_G, gnf, h0g, gWHH0, gWIH1, gWHH1, GH1B, NTG };
        GruProb Pt = { ETAB_T, tnf, h0t, tWHH0, tWIH1, tWHH1, TH1B, NTREE };
        int gblk = (NTG + 31) / 32;      // 313
        int tblk = (NTREE + 31) / 32;    // 938
        gru_fused7<<<gblk + tblk, 448, 0, stream>>>(Pg, Pt, gblk);
    }

    // ---- 4. graph GAT chain ----
    build_xg_bf<<<(NG * 128 + 255) / 256, 256, 0, stream>>>(GH1B, UE, XG_B);
    cvt(gc1W, W_G1, 512, 512, HD, 128);
    cvt(gc2W, W_G2, 100, 100, 512, 512);
    {   // graph GAT1: 8 heads x 64
        mfma(XG_B, 128, W_G1, 128, nullptr, GFEAT1, 512, NG, 512, 4);
        gat_pre(GFEAT1, NG, 8, 64, gc1as, gc1ad, gei, EG);
        int waves = NG * 2;
        gat_accum_csr<64, 4><<<(waves + 3) / 4, 256, 0, stream>>>(
            GOFF, GEIDX, gei, EG, EBB, SB, GFEAT1, gc1b, nullptr, GOUT1B, NG, 8, 512, 2);
    }
    {   // graph GAT2: 1 head x 100
        mfma(GOUT1B, 512, W_G2, 512, nullptr, GFEAT2, 100, NG, 100, 16);
        gat_pre(GFEAT2, NG, 1, 100, gc2as, gc2ad, gei, EG);
        int waves = NG;
        gat_accum_csr<100, 2><<<(waves + 3) / 4, 256, 0, stream>>>(
            GOFF, GEIDX, gei, EG, EBB, SB, GFEAT2, gc2b, XGF, nullptr, NG, 1, 100, 1);
    }

    // ---- 5. tree GAT chain ----
    set_roots<<<(NB * HD + 255) / 256, 256, 0, stream>>>(XGF, TH1B);
    cvt(tc1W, W_G1, 800, 800, HD, 128);
    cvt(tc2W, W_G2, 100, 100, 800, 800);
    {   // tree GAT1: 8 heads x 100
        mfma(TH1B, 128, W_G1, 128, nullptr, TFEAT1, 800, NTREE, 800, 4);
        gat_pre(TFEAT1, NTREE, 8, 100, tc1as, tc1ad, tei, ET);
        int waves = NTREE * 4;
        gat_accum_csr<100, 4><<<(waves + 3) / 4, 256, 0, stream>>>(
            TOFF, TEIDX, tei, ET, EBB, SB, TFEAT1, tc1b, nullptr, TOUT1B, NTREE, 8, 800, 4);
    }
    {   // tree GAT2: 1 head x 100
        mfma(TOUT1B, 800, W_G2, 800, nullptr, TFEAT2, 100, NTREE, 100, 25);
        gat_pre(TFEAT2, NTREE, 1, 100, tc2as, tc2ad, tei, ET);
        int waves = NTREE;
        gat_accum_csr<100, 2><<<(waves + 3) / 4, 256, 0, stream>>>(
            TOFF, TEIDX, tei, ET, EBB, SB, TFEAT2, tc2b, XOUT2, nullptr, NTREE, 1, 100, 1);
    }

    // ---- 6. scatter_mean + classifier ----
    hipMemsetAsync(SSUM, 0, (size_t)NB * HD * 4, stream);
    hipMemsetAsync(SCNT, 0, (size_t)NB * 4, stream);
    scatter_mean_accum<<<(NTREE * HD + 255) / 256, 256, 0, stream>>>(XOUT2, indices, SSUM, SCNT);
    fc_out<<<1, 512, 0, stream>>>(SSUM, SCNT, fcW, fcb, out);
}

// Round 3
// 1777.256 us; speedup vs baseline: 1.1118x; 1.0046x over previous
//
#include <hip/hip_runtime.h>

// ---------------------------------------------------------------------------
// Problem constants
// ---------------------------------------------------------------------------
#define NB    128
#define HD    100
#define NU    20000
#define NTG   10000
#define NTREE 30000
#define NG    30000
#define TT    20
#define EG    200000
#define ET    60000
#define VOC   50000

#define ESTR  304   // Etab row stride (u16): 608 B, 16B-aligned
#define WROWS 336   // GRU weight rows: 3 gates x 112 (gate stride 112)

typedef unsigned short u16;
typedef unsigned int   u32;
typedef __attribute__((ext_vector_type(8))) short short8;
typedef __attribute__((ext_vector_type(4))) float floatx4;

__device__ __forceinline__ float sigmoidf_(float x) {
    return __fdividef(1.f, 1.f + __expf(-x));
}
__device__ __forceinline__ float tanhf_(float x) {
    return 1.f - __fdividef(2.f, __expf(2.f * x) + 1.f);
}
__device__ __forceinline__ u16 f2bf(float f) {
    u32 u = __float_as_uint(f);
    u32 r = (u + 0x7fffu + ((u >> 16) & 1u)) >> 16;
    return (u16)r;
}
__device__ __forceinline__ float bf2f(u16 h) {
    return __uint_as_float(((u32)h) << 16);
}

// ---------------------------------------------------------------------------
// Fused 2-layer GRU v8: 448 threads (7 waves) / 32 rows / TT steps.
//
// vs v7 (one region per step = B(t) + A(t+1), single barrier — same count,
// restructured for latency):
//  - xpref moved to the TOP of the region: the 24 scattered Etab u16 loads
//    retire under the 72 MFMAs, so the compiler's vmcnt(0) drain before
//    s_barrier costs ~0 (v7 issued them right before the barrier -> full
//    gather latency exposed EVERY step).
//  - a0 fragment reuse: GEMM1-x of step t and GEMM0 of step t+1 both
//    multiply h0(t) -> load its fragments ONCE (24 -> 16 ds_read_b128/step).
//  - r/z gates of layer 1 accumulate in ONE 8-deep MFMA chain each
//    (bias-slot trick makes ir+hr a single accumulation); only the n gate
//    stays split (r multiplies hn alone). Saves 8 acc VGPRs + 24 v_add.
//  - occupancy is structurally 1 block/CU (weights = 258KB of RF); this
//    round targets the per-step serial cost, not occupancy.
// ---------------------------------------------------------------------------
struct GruProb {
    const u16*   Etab;     // [VOC][304] (includes bih0)
    const int*   nodes;    // [M][TT]
    const float* h0;       // [2][M][100] fp32
    const u16*   Whh0;     // [336][128] gate-padded (col100 = bhh0)
    const u16*   Wih1;     // (col100 = bih1)
    const u16*   Whh1;     // (col100 = bhh1)
    u16*         hout;     // [M][128]
    int          M;
};

__global__ __launch_bounds__(448, 2) void gru_fused8(GruProb Pg, GruProb Pt, int gblocks)
{
    const bool isg = (int)blockIdx.x < gblocks;
    const GruProb P = isg ? Pg : Pt;
    const int bx = isg ? blockIdx.x : blockIdx.x - gblocks;
    const int M  = P.M;
    const int m0 = bx * 32;

    // h mirrors: [32][128] u16, 256B rows, byte ^= ((row&7)<<4) swizzle
    __shared__ u16 H0[2][32 * 128];
    __shared__ u16 H1[2][32 * 128];
    __shared__ int NID[TT * 32];     // node ids, [t][row]

    const int tid  = threadIdx.x;
    const int w    = tid >> 6, lane = tid & 63;
    const int fr   = lane & 15, quad = lane >> 4;
    const int c    = w * 16 + fr;                 // output column of this lane
    const bool cok = (c < HD);

    // ---- register-resident weight fragments (tiles g*7 + w) ----
    short8 Bh0[3][4], Bx1[3][4], Bh1[3][4];
#pragma unroll
    for (int g = 0; g < 3; ++g) {
        const size_t rb = (size_t)((g * 7 + w) * 16 + fr) * 128 + quad * 8;
#pragma unroll
        for (int kk = 0; kk < 4; ++kk) {
            Bh0[g][kk] = *(const short8*)(P.Whh0 + rb + kk * 32);
            Bx1[g][kk] = *(const short8*)(P.Wih1 + rb + kk * 32);
            Bh1[g][kk] = *(const short8*)(P.Whh1 + rb + kk * 32);
        }
    }

    // ---- zero h mirrors + stage node-id table ----
    for (int i = tid; i < 32 * 128; i += 448) {
        H0[0][i] = 0; H0[1][i] = 0; H1[0][i] = 0; H1[1][i] = 0;
    }
    for (int i = tid; i < 32 * TT; i += 448) {
        int row = i / TT, t = i - row * TT;
        int gm = m0 + row;
        NID[t * 32 + row] = (gm < M) ? P.nodes[(size_t)gm * TT + t] : 0;
    }
    __syncthreads();
    // bias slot col 100 = 1.0 in all four buffers (swizzled position)
    if (tid < 32) {
        int off = 200 ^ ((tid & 7) << 4);        // byte offset within row
        *(u16*)((char*)&H0[0][0] + tid * 256 + off) = 0x3F80;
        *(u16*)((char*)&H0[1][0] + tid * 256 + off) = 0x3F80;
        *(u16*)((char*)&H1[0][0] + tid * 256 + off) = 0x3F80;
        *(u16*)((char*)&H1[1][0] + tid * 256 + off) = 0x3F80;
    }

    // ---- init h carry + LDS mirrors ----
    float h0f[2][4] = {{0.f,0.f,0.f,0.f},{0.f,0.f,0.f,0.f}};
    float h1f[2][4] = {{0.f,0.f,0.f,0.f},{0.f,0.f,0.f,0.f}};
    if (cok) {
#pragma unroll
        for (int rt = 0; rt < 2; ++rt)
#pragma unroll
        for (int r = 0; r < 4; ++r) {
            int row = rt * 16 + quad * 4 + r;
            int gm  = m0 + row;
            float v0 = 0.f, v1 = 0.f;
            if (gm < M) {
                v0 = P.h0[(size_t)gm * HD + c];
                v1 = P.h0[(size_t)(M + gm) * HD + c];
            }
            h0f[rt][r] = v0; h1f[rt][r] = v1;
            int off = (2 * c) ^ ((row & 7) << 4);
            *(u16*)((char*)&H0[0][0] + row * 256 + off) = f2bf(v0);
            *(u16*)((char*)&H1[0][0] + row * 256 + off) = f2bf(v1);
        }
    }

    // ---- x-gate register prefetch: 3 gates x 8 rows at this lane's column ----
    u16 xr[2][4], xz[2][4], xn[2][4];
    auto xpref = [&](int tn) {
        if (cok) {
#pragma unroll
            for (int rt = 0; rt < 2; ++rt)
#pragma unroll
            for (int r = 0; r < 4; ++r) {
                int row = rt * 16 + quad * 4 + r;
                int nd  = NID[tn * 32 + row];
                const u16* ex = P.Etab + (size_t)nd * ESTR + c;
                xr[rt][r] = ex[0];
                xz[rt][r] = ex[100];
                xn[rt][r] = ex[200];
            }
        }
    };
    __syncthreads();      // NID + H mirrors visible
    xpref(0);             // x(0) for the prologue

    // ---- prologue: A(0) — GEMM0 on h0_init (H0[0]) -> h0(0) -> H0[1] ----
#pragma unroll
    for (int rt = 0; rt < 2; ++rt) {
        short8 a[4];
#pragma unroll
        for (int kk = 0; kk < 4; ++kk) {
            int row = rt * 16 + fr;
            int off = (kk * 64 + quad * 16) ^ ((row & 7) << 4);
            a[kk] = *(const short8*)((const char*)&H0[0][0] + row * 256 + off);
        }
        floatx4 ag[3];
#pragma unroll
        for (int g = 0; g < 3; ++g) ag[g] = (floatx4){0.f, 0.f, 0.f, 0.f};
#pragma unroll
        for (int g = 0; g < 3; ++g)
#pragma unroll
            for (int kk = 0; kk < 4; ++kk)
                ag[g] = __builtin_amdgcn_mfma_f32_16x16x32_bf16(a[kk], Bh0[g][kk], ag[g], 0, 0, 0);
        if (cok) {
#pragma unroll
            for (int r = 0; r < 4; ++r) {
                int row = rt * 16 + quad * 4 + r;
                float rr = sigmoidf_(bf2f(xr[rt][r]) + ag[0][r]);
                float zz = sigmoidf_(bf2f(xz[rt][r]) + ag[1][r]);
                float nn = tanhf_(bf2f(xn[rt][r]) + rr * ag[2][r]);
                float o  = (1.f - zz) * nn + zz * h0f[rt][r];
                h0f[rt][r] = o;
                *(u16*)((char*)&H0[1][0] + row * 256 + ((2 * c) ^ ((row & 7) << 4))) = f2bf(o);
            }
        }
    }
    __syncthreads();

    // ---- regions r = 0..TT-1: B(r) + A(r+1), one barrier each ----
    for (int r = 0; r < TT; ++r) {
        const bool doA = (r + 1 < TT);
        // issue next x-gates FIRST: retire under the MFMAs below, so the
        // barrier's vmcnt drain costs nothing.
        if (doA) xpref(r + 1);

        const char* rd0 = (const char*)&H0[(r + 1) & 1][0];   // h0(r)
        const char* rd1 = (const char*)&H1[r & 1][0];         // h1(r-1)
        char*       wr0 = (char*)&H0[r & 1][0];               // h0(r+1)
        char*       wr1 = (char*)&H1[(r + 1) & 1][0];         // h1(r)

#pragma unroll
        for (int rt = 0; rt < 2; ++rt) {
            short8 a0[4], a1[4];
#pragma unroll
            for (int kk = 0; kk < 4; ++kk) {
                int row = rt * 16 + fr;
                int off = (kk * 64 + quad * 16) ^ ((row & 7) << 4);
                a0[kk] = *(const short8*)(rd0 + row * 256 + off);
                a1[kk] = *(const short8*)(rd1 + row * 256 + off);
            }
            // --- layer 1: r/z merged 8-deep chains; n split ---
            floatx4 rz0 = {0.f,0.f,0.f,0.f}, rz1 = {0.f,0.f,0.f,0.f};
            floatx4 xnv = {0.f,0.f,0.f,0.f}, hnv = {0.f,0.f,0.f,0.f};
#pragma unroll
            for (int kk = 0; kk < 4; ++kk)
                rz0 = __builtin_amdgcn_mfma_f32_16x16x32_bf16(a0[kk], Bx1[0][kk], rz0, 0, 0, 0);
#pragma unroll
            for (int kk = 0; kk < 4; ++kk)
                rz0 = __builtin_amdgcn_mfma_f32_16x16x32_bf16(a1[kk], Bh1[0][kk], rz0, 0, 0, 0);
#pragma unroll
            for (int kk = 0; kk < 4; ++kk)
                rz1 = __builtin_amdgcn_mfma_f32_16x16x32_bf16(a0[kk], Bx1[1][kk], rz1, 0, 0, 0);
#pragma unroll
            for (int kk = 0; kk < 4; ++kk)
                rz1 = __builtin_amdgcn_mfma_f32_16x16x32_bf16(a1[kk], Bh1[1][kk], rz1, 0, 0, 0);
#pragma unroll
            for (int kk = 0; kk < 4; ++kk)
                xnv = __builtin_amdgcn_mfma_f32_16x16x32_bf16(a0[kk], Bx1[2][kk], xnv, 0, 0, 0);
#pragma unroll
            for (int kk = 0; kk < 4; ++kk)
                hnv = __builtin_amdgcn_mfma_f32_16x16x32_bf16(a1[kk], Bh1[2][kk], hnv, 0, 0, 0);
            // --- layer 0, step r+1 (reuses a0 = h0(r)) ---
            floatx4 ag[3];
#pragma unroll
            for (int g = 0; g < 3; ++g) ag[g] = (floatx4){0.f, 0.f, 0.f, 0.f};
            if (doA) {
#pragma unroll
                for (int g = 0; g < 3; ++g)
#pragma unroll
                    for (int kk = 0; kk < 4; ++kk)
                        ag[g] = __builtin_amdgcn_mfma_f32_16x16x32_bf16(a0[kk], Bh0[g][kk], ag[g], 0, 0, 0);
            }
            if (cok) {
                // combine layer 1 -> h1(r)
#pragma unroll
                for (int r4 = 0; r4 < 4; ++r4) {
                    int row = rt * 16 + quad * 4 + r4;
                    float rr = sigmoidf_(rz0[r4]);
                    float zz = sigmoidf_(rz1[r4]);
                    float nn = tanhf_(xnv[r4] + rr * hnv[r4]);
                    float o  = (1.f - zz) * nn + zz * h1f[rt][r4];
                    h1f[rt][r4] = o;
                    *(u16*)(wr1 + row * 256 + ((2 * c) ^ ((row & 7) << 4))) = f2bf(o);
                }
                // combine layer 0 -> h0(r+1)
                if (doA) {
#pragma unroll
                    for (int r4 = 0; r4 < 4; ++r4) {
                        int row = rt * 16 + quad * 4 + r4;
                        float rr = sigmoidf_(bf2f(xr[rt][r4]) + ag[0][r4]);
                        float zz = sigmoidf_(bf2f(xz[rt][r4]) + ag[1][r4]);
                        float nn = tanhf_(bf2f(xn[rt][r4]) + rr * ag[2][r4]);
                        float o  = (1.f - zz) * nn + zz * h0f[rt][r4];
                        h0f[rt][r4] = o;
                        *(u16*)(wr0 + row * 256 + ((2 * c) ^ ((row & 7) << 4))) = f2bf(o);
                    }
                }
            }
        }
        __syncthreads();
    }

    // ---- write final top-layer hidden, bf16 [M][128] (de-swizzle) ----
    // h1(TT-1) lives in H1[TT & 1] == H1[0]
    for (int i = tid; i < 32 * 128; i += 448) {
        int row = i >> 7, cc = i & 127;
        int gm = m0 + row;
        if (gm < M) {
            int off = (2 * cc) ^ ((row & 7) << 4);
            P.hout[(size_t)gm * 128 + cc] = *(const u16*)((const char*)&H1[0][0] + row * 256 + off);
        }
    }
}

// ---------------------------------------------------------------------------
// bf16 MFMA GEMM (Etab build + GAT feature GEMMs)
// ---------------------------------------------------------------------------
#define LDST 40
__global__ __launch_bounds__(256) void gemm_mfma(
    const u16* __restrict__ A, const u16* __restrict__ B,
    float* __restrict__ Cf, u16* __restrict__ Cb,
    int M, int N, int Kt, int lda, int ldw, int ldc)
{
    const int m0 = blockIdx.x * 64;
    if (m0 >= M) return;
    const int n0 = blockIdx.y * 64;

    __shared__ u16 Als[64 * LDST];
    __shared__ u16 Wls[64 * LDST];

    const int tid  = threadIdx.x;
    const int wave = tid >> 6, lane = tid & 63;
    const int row  = tid >> 2, part = (tid & 3) * 8;
    const int fr   = lane & 15, quad = lane >> 4;

    floatx4 acc[4];
#pragma unroll
    for (int t = 0; t < 4; ++t) acc[t] = (floatx4){0.f, 0.f, 0.f, 0.f};

    const int am = m0 + row;  const bool aok = am < M;
    const int wn = n0 + row;  const bool wok = wn < N;
    const uint4 z4 = {0u, 0u, 0u, 0u};

    for (int kk = 0; kk < Kt; ++kk) {
        uint4 av = aok ? *(const uint4*)(A + (size_t)am * lda + kk * 32 + part) : z4;
        uint4 wv = wok ? *(const uint4*)(B + (size_t)wn * ldw + kk * 32 + part) : z4;
        __syncthreads();
        *(uint4*)&Als[row * LDST + part] = av;
        *(uint4*)&Wls[row * LDST + part] = wv;
        __syncthreads();
        short8 af = *(const short8*)&Als[((wave << 4) + fr) * LDST + quad * 8];
#pragma unroll
        for (int t = 0; t < 4; ++t) {
            short8 bf = *(const short8*)&Wls[((t << 4) + fr) * LDST + quad * 8];
            acc[t] = __builtin_amdgcn_mfma_f32_16x16x32_bf16(af, bf, acc[t], 0, 0, 0);
        }
    }

    const int orow0 = m0 + (wave << 4) + quad * 4;
#pragma unroll
    for (int t = 0; t < 4; ++t) {
        int col = n0 + (t << 4) + fr;
        if (col >= N) continue;
#pragma unroll
        for (int r = 0; r < 4; ++r) {
            int mr = orow0 + r;
            if (mr >= M) continue;
            float v = acc[t][r];
            if (Cf) Cf[(size_t)mr * ldc + col] = v;
            if (Cb) Cb[(size_t)mr * ldc + col] = f2bf(v);
        }
    }
}

// ---------------------------------------------------------------------------
// fp32 tiled GEMM (user-embed MLP only)
// ---------------------------------------------------------------------------
__global__ __launch_bounds__(256) void gemm_nt(
    const float* __restrict__ A, const float* __restrict__ W,
    const float* __restrict__ bias, float* __restrict__ C,
    int M, int N, int K, int relu)
{
    const int m0 = blockIdx.x * 64;
    const int n0 = blockIdx.y * 64;
    __shared__ float As[20][68];
    __shared__ float Ws[20][68];
    const int tid = threadIdx.x;
    const int r0 = (tid >> 4) * 4;
    const int c0 = (tid & 15) * 4;
    int sr[5], sk[5];
#pragma unroll
    for (int it = 0; it < 5; ++it) {
        int idx = tid + it * 256;
        sr[it] = idx / 20; sk[it] = idx - sr[it] * 20;
    }
    float acc[4][4];
#pragma unroll
    for (int i = 0; i < 4; ++i)
#pragma unroll
        for (int j = 0; j < 4; ++j) acc[i][j] = 0.f;
    const int nch = (K + 19) / 20;
    for (int ch = 0; ch < nch; ++ch) {
        const int k0 = ch * 20;
#pragma unroll
        for (int it = 0; it < 5; ++it) {
            int m = m0 + sr[it], k = k0 + sk[it];
            float va = 0.f, vw = 0.f;
            if (k < K) {
                if (m < M) va = A[(size_t)m * K + k];
                int n = n0 + sr[it];
                if (n < N) vw = W[(size_t)n * K + k];
            }
            As[sk[it]][sr[it]] = va;
            Ws[sk[it]][sr[it]] = vw;
        }
        __syncthreads();
#pragma unroll
        for (int kkk = 0; kkk < 20; ++kkk) {
            float4 a = *(const float4*)&As[kkk][r0];
            float4 w = *(const float4*)&Ws[kkk][c0];
            float av[4] = {a.x, a.y, a.z, a.w};
            float wv[4] = {w.x, w.y, w.z, w.w};
#pragma unroll
            for (int i = 0; i < 4; ++i)
#pragma unroll
                for (int j = 0; j < 4; ++j)
                    acc[i][j] = fmaf(av[i], wv[j], acc[i][j]);
        }
        __syncthreads();
    }
#pragma unroll
    for (int i = 0; i < 4; ++i) {
        int m = m0 + r0 + i;
        if (m >= M) continue;
#pragma unroll
        for (int j = 0; j < 4; ++j) {
            int n = n0 + c0 + j;
            if (n >= N) continue;
            float v = acc[i][j] + (bias ? bias[n] : 0.f);
            if (relu) v = fmaxf(v, 0.f);
            C[(size_t)m * N + n] = v;
        }
    }
}

// fp32 [M][K] -> bf16 [Mp][ldk]; col K..ldk zero, except col 100 gets
// app[n] (if app) or 1.0 (if appone) — the K-slot bias fold.
__global__ void convert_pad2(const float* __restrict__ src, u16* __restrict__ dst,
                             int M, int Mp, int K, int ldk,
                             const float* __restrict__ app, int appone)
{
    int t = blockIdx.x * blockDim.x + threadIdx.x;
    if (t >= Mp * ldk) return;
    int n = t / ldk, c = t - n * ldk;
    u16 o = 0;
    if (n < M) {
        if (c < K) o = f2bf(src[(size_t)n * K + c]);
        else if (c == 100) {
            if (app) o = f2bf(app[n]);
            else if (appone) o = 0x3F80;
        }
    }
    dst[t] = o;
}

// GRU weight -> gate-padded bf16 [336][128]: gates r/z/n at row offsets
// 0/112/224; col100 = bias; everything else zero.
__global__ void convert_gru_w(const float* __restrict__ src, u16* __restrict__ dst,
                              const float* __restrict__ bias)
{
    int t = blockIdx.x * blockDim.x + threadIdx.x;
    if (t >= WROWS * 128) return;
    int rr = t >> 7, c = t & 127;
    int g = rr / 112, r2 = rr - g * 112;
    u16 o = 0;
    if (r2 < 100) {
        int sr = g * 100 + r2;
        if (c < 100) o = f2bf(src[(size_t)sr * 100 + c]);
        else if (c == 100) o = f2bf(bias[sr]);
    }
    dst[t] = o;
}

// xg (bf16 [NG][128]) = concat(hg[:128], ue, hg[128:])
__global__ void build_xg_bf(const u16* __restrict__ hgb, const float* __restrict__ ue,
                            u16* __restrict__ xgb)
{
    int t = blockIdx.x * blockDim.x + threadIdx.x;
    if (t >= NG * 128) return;
    int n = t >> 7, c = t & 127;
    u16 o = 0;
    if (n < NB)           o = hgb[n * 128 + c];
    else if (n < NB + NU) { if (c < HD) o = f2bf(ue[(size_t)(n - NB) * HD + c]); }
    else                  o = hgb[(size_t)(n - NU) * 128 + c];
    xgb[t] = o;
}

// tree roots: hb rows[0:128) <- xg_final fp32
__global__ void set_roots(const float* __restrict__ src, u16* __restrict__ hb)
{
    int t = blockIdx.x * blockDim.x + threadIdx.x;
    if (t >= NB * HD) return;
    int n = t / HD, c = t - n * HD;
    hb[(size_t)n * 128 + c] = f2bf(src[t]);
}

// ---------------------------------------------------------------------------
// CSR build
// ---------------------------------------------------------------------------
__global__ void csr_count(const int* __restrict__ ei, int E, int N, int* __restrict__ cnt)
{
    int e = blockIdx.x * blockDim.x + threadIdx.x;
    if (e >= E + N) return;
    int dst = (e < E) ? ei[E + e] : e - E;
    atomicAdd(&cnt[dst], 1);
}

__global__ void csr_scan(const int* __restrict__ cnt, int* __restrict__ off,
                         int* __restrict__ cur, int N)
{
    __shared__ int part[256];
    const int tid = threadIdx.x;
    const int per = (N + 255) / 256;
    const int i0 = tid * per;
    const int i1 = min(i0 + per, N);
    int s = 0;
    for (int i = i0; i < i1; ++i) s += cnt[i];
    part[tid] = s;
    __syncthreads();
    for (int o = 1; o < 256; o <<= 1) {
        int u = (tid >= o) ? part[tid - o] : 0;
        __syncthreads();
        part[tid] += u;
        __syncthreads();
    }
    int base = part[tid] - s;
    for (int i = i0; i < i1; ++i) {
        off[i] = base; cur[i] = base;
        base += cnt[i];
    }
    if (tid == 255) off[N] = part[255];
}

__global__ void csr_scatter(const int* __restrict__ ei, int E, int N,
                            int* __restrict__ cur, int* __restrict__ eidx)
{
    int e = blockIdx.x * blockDim.x + threadIdx.x;
    if (e >= E + N) return;
    int dst = (e < E) ? ei[E + e] : e - E;
    int pos = atomicAdd(&cur[dst], 1);
    eidx[pos] = e;
}

// ---------------------------------------------------------------------------
// GAT pieces (feat is bf16)
// ---------------------------------------------------------------------------
__global__ void gat_es_ed(const u16* __restrict__ feat, const float* __restrict__ asrc,
                          const float* __restrict__ adst, float* __restrict__ es,
                          float* __restrict__ ed, int N, int heads, int C)
{
    int gid = blockIdx.x * blockDim.x + threadIdx.x;
    if (gid >= N * heads) return;
    int n = gid / heads, hd = gid - n * heads;
    const u16* hp = feat + ((size_t)n * heads + hd) * C;
    const float* as = asrc + (size_t)hd * C;
    const float* ad = adst + (size_t)hd * C;
    float s1 = 0.f, s2 = 0.f;
    for (int c = 0; c < C; c += 4) {
        uint2 pk = *(const uint2*)(hp + c);
        float v0 = bf2f((u16)(pk.x & 0xffff)), v1 = bf2f((u16)(pk.x >> 16));
        float v2 = bf2f((u16)(pk.y & 0xffff)), v3 = bf2f((u16)(pk.y >> 16));
        s1 += v0 * as[c] + v1 * as[c + 1] + v2 * as[c + 2] + v3 * as[c + 3];
        s2 += v0 * ad[c] + v1 * ad[c + 1] + v2 * ad[c + 2] + v3 * ad[c + 3];
    }
    es[gid] = s1; ed[gid] = s2;
}

__device__ __forceinline__ void atomic_max_f(float* addr, float v)
{
    if (v >= 0.f) atomicMax((int*)addr, __float_as_int(v));
    else          atomicMin((unsigned int*)addr, __float_as_uint(v));
}

__global__ void gat_edge_logit(const int* __restrict__ ei, int E, int N, int heads,
                               const float* __restrict__ es, const float* __restrict__ ed,
                               float* __restrict__ eb, float* __restrict__ m)
{
    int gid = blockIdx.x * blockDim.x + threadIdx.x;
    int EE = E + N;
    if (gid >= EE * heads) return;
    int idx = gid / heads, hd = gid - idx * heads;
    int src, dst;
    if (idx < E) { src = ei[idx]; dst = ei[E + idx]; } else { src = dst = idx - E; }
    float e = es[src * heads + hd] + ed[dst * heads + hd];
    e = e > 0.f ? e : 0.2f * e;
    eb[gid] = e;
    atomic_max_f(&m[dst * heads + hd], e);
}

__global__ void gat_edge_expsum(const int* __restrict__ ei, int E, int N, int heads,
                                float* __restrict__ eb, const float* __restrict__ m,
                                float* __restrict__ s)
{
    int gid = blockIdx.x * blockDim.x + threadIdx.x;
    int EE = E + N;
    if (gid >= EE * heads) return;
    int idx = gid / heads, hd = gid - idx * heads;
    int dst = (idx < E) ? ei[E + idx] : idx - E;
    float e = __expf(eb[gid] - m[dst * heads + hd]);
    eb[gid] = e;
    atomicAdd(&s[dst * heads + hd], e);
}

template<int C, int VEC>
__global__ __launch_bounds__(256) void gat_accum_csr(
    const int* __restrict__ off, const int* __restrict__ eidx,
    const int* __restrict__ ei, int E,
    const float* __restrict__ eb, const float* __restrict__ s,
    const u16* __restrict__ feat, const float* __restrict__ bias,
    float* __restrict__ outf, u16* __restrict__ outb,
    int N, int heads, int HC, int nchunk)
{
    int gt = blockIdx.x * blockDim.x + threadIdx.x;
    int w = gt >> 6, lane = gt & 63;
    int dst = w / nchunk, chunk = w - dst * nchunk;
    if (dst >= N) return;
    int c0 = chunk * 64 * VEC + lane * VEC;
    if (c0 >= HC) return;
    int hh[VEC]; float sinv[VEC], acc[VEC];
#pragma unroll
    for (int v = 0; v < VEC; ++v) {
        int c = c0 + v;
        hh[v] = c / C;
        sinv[v] = __fdividef(1.f, s[dst * heads + hh[v]]);
        acc[v] = 0.f;
    }
    int e0 = off[dst], e1 = off[dst + 1];
    for (int p = e0; p < e1; ++p) {
        int j = eidx[p];
        int src = (j < E) ? ei[j] : (j - E);
        const u16* frp = feat + (size_t)src * HC + c0;
        float fv[VEC];
        if (VEC == 4) {
            uint2 pk = *(const uint2*)frp;
            fv[0] = bf2f((u16)(pk.x & 0xffff)); fv[1] = bf2f((u16)(pk.x >> 16));
            fv[2] = bf2f((u16)(pk.y & 0xffff)); fv[3] = bf2f((u16)(pk.y >> 16));
        } else {
            u32 pk = *(const u32*)frp;
            fv[0] = bf2f((u16)(pk & 0xffff)); fv[1] = bf2f((u16)(pk >> 16));
        }
#pragma unroll
        for (int v = 0; v < VEC; ++v)
            acc[v] += fv[v] * eb[(size_t)j * heads + hh[v]] * sinv[v];
    }
#pragma unroll
    for (int v = 0; v < VEC; ++v) {
        int c = c0 + v;
        float o = fmaxf(acc[v] + bias[c], 0.f);
        if (outf) outf[(size_t)dst * HC + c] = o;
        if (outb) outb[(size_t)dst * HC + c] = f2bf(o);
    }
}

__global__ void scatter_mean_accum(const float* __restrict__ x, const int* __restrict__ idx,
                                   float* __restrict__ ssum, float* __restrict__ cnt)
{
    int t = blockIdx.x * blockDim.x + threadIdx.x;
    if (t >= NTREE * HD) return;
    int n = t / HD, c = t - n * HD;
    int b = idx[n];
    atomicAdd(&ssum[b * HD + c], x[t]);
    if (c == 0) atomicAdd(&cnt[b], 1.f);
}

__global__ void fc_out(const float* __restrict__ ssum, const float* __restrict__ cnt,
                       const float* __restrict__ W, const float* __restrict__ b,
                       float* __restrict__ out)
{
    int t = threadIdx.x;                 // 512 threads
    int bb = t >> 2, j = t & 3;
    float inv = __fdividef(1.f, fmaxf(cnt[bb], 1.f));
    float acc = b[j];
    for (int k = 0; k < HD; ++k) acc += ssum[bb * HD + k] * inv * W[j * HD + k];
    out[t] = acc;
}

// ---------------------------------------------------------------------------
// Host launcher
// ---------------------------------------------------------------------------
extern "C" void kernel_launch(void* const* d_in, const int* in_sizes, int n_in,
                              void* d_out, int out_size, void* d_ws, size_t ws_size,
                              hipStream_t stream)
{
    const float* user_feats = (const float*)d_in[1];
    const int*   gnf        = (const int*)d_in[2];
    const int*   gei        = (const int*)d_in[3];
    const int*   tnf        = (const int*)d_in[4];
    const int*   tei        = (const int*)d_in[5];
    const int*   indices    = (const int*)d_in[6];
    const float* h0g        = (const float*)d_in[7];
    const float* h0t        = (const float*)d_in[8];
    const float* temb       = (const float*)d_in[9];
    const float* gW[2][4] = {{(const float*)d_in[10], (const float*)d_in[11], (const float*)d_in[12], (const float*)d_in[13]},
                             {(const float*)d_in[14], (const float*)d_in[15], (const float*)d_in[16], (const float*)d_in[17]}};
    const float* tW[2][4] = {{(const float*)d_in[18], (const float*)d_in[19], (const float*)d_in[20], (const float*)d_in[21]},
                             {(const float*)d_in[22], (const float*)d_in[23], (const float*)d_in[24], (const float*)d_in[25]}};
    const float* uW1 = (const float*)d_in[26]; const float* ub1 = (const float*)d_in[27];
    const float* uW2 = (const float*)d_in[28]; const float* ub2 = (const float*)d_in[29];
    const float* gc1W = (const float*)d_in[30]; const float* gc1as = (const float*)d_in[31];
    const float* gc1ad = (const float*)d_in[32]; const float* gc1b = (const float*)d_in[33];
    const float* gc2W = (const float*)d_in[34]; const float* gc2as = (const float*)d_in[35];
    const float* gc2ad = (const float*)d_in[36]; const float* gc2b = (const float*)d_in[37];
    const float* tc1W = (const float*)d_in[38]; const float* tc1as = (const float*)d_in[39];
    const float* tc1ad = (const float*)d_in[40]; const float* tc1b = (const float*)d_in[41];
    const float* tc2W = (const float*)d_in[42]; const float* tc2as = (const float*)d_in[43];
    const float* tc2ad = (const float*)d_in[44]; const float* tc2b = (const float*)d_in[45];
    const float* fcW = (const float*)d_in[46]; const float* fcb = (const float*)d_in[47];
    float* out = (float*)d_out;

    char* ws = (char*)d_ws;
    const size_t NEED = 226500000;
    if (ws_size < NEED) return;

    // ---- workspace layout (decimal byte offsets) ----
    float* XGF    = (float*)(ws + 0);            // 12 MB xg_final fp32 [NG][100]
    u16*   TEMB_B = (u16*)(ws + 12000000);       // 12.8 MB [VOC][128]
    u16*   ETAB_G = (u16*)(ws + 25000000);       // 30.4 MB [VOC][304]
    u16*   ETAB_T = (u16*)(ws + 60400000);       // 30.4 MB
    u16*   GH1B   = (u16*)(ws + 96000000);       // 2.56 MB [NTG][128]
    u16*   TH1B   = (u16*)(ws + 98600000);       // 7.68 MB [NTREE][128]
    float* UE     = (float*)(ws + 106400000);    // 8 MB
    float* HID    = (float*)(ws + 114400000);    // 8 MB
    u16*   WARENA = (u16*)(ws + 122400000);      // ~0.97 MB (1.2 MB region)
    int*   GOFF   = (int*)(ws + 123600000);
    int*   GCUR   = (int*)(ws + 123800000);
    int*   GCNT   = (int*)(ws + 124000000);
    int*   GEIDX  = (int*)(ws + 124200000);      // 0.92 MB
    int*   TOFF   = (int*)(ws + 125200000);
    int*   TCUR   = (int*)(ws + 125400000);
    int*   TCNT   = (int*)(ws + 125600000);
    int*   TEIDX  = (int*)(ws + 125800000);      // 0.36 MB
    float* ESB    = (float*)(ws + 126200000);
    float* EDB    = (float*)(ws + 127200000);
    float* MB     = (float*)(ws + 128200000);
    float* SB     = (float*)(ws + 129200000);
    float* EBB    = (float*)(ws + 130200000);    // 7.36 MB
    float* SSUM   = (float*)(ws + 137600000);
    float* SCNT   = (float*)(ws + 137700000);
    u16*   XG_B   = (u16*)(ws + 138000000);      // 7.68 MB [NG][128]
    u16*   GFEAT1 = (u16*)(ws + 146000000);      // 30.72 MB [NG][512]
    u16*   GOUT1B = (u16*)(ws + 177000000);      // 30.72 MB
    u16*   GFEAT2 = (u16*)(ws + 208000000);      // 6 MB [NG][100]
    u16*   TFEAT1 = (u16*)(ws + 25000000);       // 48 MB [NTREE][800] (overlays Etabs, dead)
    u16*   TOUT1B = (u16*)(ws + 146000000);      // 48 MB (overlays GFEAT1/GOUT1B, dead)
    u16*   TFEAT2 = (u16*)(ws + 208000000);      // 6 MB (overlay GFEAT2, dead)
    float* XOUT2  = (float*)(ws + 214400000);    // 12 MB -> 226.4 MB

    // weight arena slots (u16 element offsets); each GRU W = [336][128]
    u16* gWHH0 = WARENA + 0;
    u16* gWIH1 = WARENA + 43008;
    u16* gWHH1 = WARENA + 86016;
    u16* tWHH0 = WARENA + 129024;
    u16* tWIH1 = WARENA + 172032;
    u16* tWHH1 = WARENA + 215040;
    u16* W_IH0 = WARENA + 258048;    // [320][128] scratch for Etab builds
    u16* W_G1  = WARENA + 299008;    // up to [800][128]
    u16* W_G2  = WARENA + 401408;    // up to [100][800]  -> end 481408 u16

    auto cvt = [&](const float* src, u16* dst, int M, int Mp, int K, int ldk,
                   const float* app = nullptr, int appone = 0) {
        convert_pad2<<<((size_t)Mp * ldk + 255) / 256, 256, 0, stream>>>(
            src, dst, M, Mp, K, ldk, app, appone);
    };
    auto cvtg = [&](const float* src, u16* dst, const float* bias) {
        convert_gru_w<<<(WROWS * 128 + 255) / 256, 256, 0, stream>>>(src, dst, bias);
    };
    auto mfma = [&](const u16* A, int lda, const u16* W, int ldw,
                    float* Cf, u16* Cb, int ldc, int M, int N, int Kt) {
        dim3 grid((M + 63) / 64, (N + 63) / 64, 1);
        gemm_mfma<<<grid, 256, 0, stream>>>(A, W, Cf, Cb, M, N, Kt, lda, ldw, ldc);
    };
    auto csr_build = [&](const int* ei, int E, int N, int* cnt, int* off, int* cur, int* eidx) {
        hipMemsetAsync(cnt, 0, (size_t)N * 4, stream);
        csr_count<<<(E + N + 255) / 256, 256, 0, stream>>>(ei, E, N, cnt);
        csr_scan<<<1, 256, 0, stream>>>(cnt, off, cur, N);
        csr_scatter<<<(E + N + 255) / 256, 256, 0, stream>>>(ei, E, N, cur, eidx);
    };
    auto gat_pre = [&](const u16* feat, int N, int heads, int C,
                       const float* asrc, const float* adst, const int* ei, int E) {
        gat_es_ed<<<(N * heads + 255) / 256, 256, 0, stream>>>(feat, asrc, adst, ESB, EDB, N, heads, C);
        hipMemsetAsync(MB, 0xFF, (size_t)N * heads * 4, stream);
        hipMemsetAsync(SB, 0, (size_t)N * heads * 4, stream);
        int EE = E + N;
        gat_edge_logit<<<(EE * heads + 255) / 256, 256, 0, stream>>>(ei, E, N, heads, ESB, EDB, EBB, MB);
        gat_edge_expsum<<<(EE * heads + 255) / 256, 256, 0, stream>>>(ei, E, N, heads, EBB, MB, SB);
    };

    // ---- 1. user embed (fp32) ----
    {
        dim3 g1((NU + 63) / 64, (HD + 63) / 64, 1);
        gemm_nt<<<g1, 256, 0, stream>>>(user_feats, uW1, ub1, HID, NU, HD, 9, 1);
        gemm_nt<<<g1, 256, 0, stream>>>(HID, uW2, ub2, UE, NU, HD, HD, 0);
    }

    // ---- 2. converts (+bias fold into col 100) + Etab builds ----
    cvt(temb, TEMB_B, VOC, VOC, HD, 128, nullptr, 1);           // col100 = 1
    cvtg(gW[0][1], gWHH0, gW[0][3]);                            // + bhh0 (gate-padded)
    cvtg(gW[1][0], gWIH1, gW[1][2]);                            // + bih1
    cvtg(gW[1][1], gWHH1, gW[1][3]);                            // + bhh1
    cvtg(tW[0][1], tWHH0, tW[0][3]);
    cvtg(tW[1][0], tWIH1, tW[1][2]);
    cvtg(tW[1][1], tWHH1, tW[1][3]);
    cvt(gW[0][0], W_IH0, 300, 320, HD, 128, gW[0][2]);          // + bih0 (old layout for Etab)
    mfma(TEMB_B, 128, W_IH0, 128, nullptr, ETAB_G, ESTR, VOC, 300, 4);
    cvt(tW[0][0], W_IH0, 300, 320, HD, 128, tW[0][2]);
    mfma(TEMB_B, 128, W_IH0, 128, nullptr, ETAB_T, ESTR, VOC, 300, 4);

    // CSR for both graphs
    csr_build(gei, EG, NG, GCNT, GOFF, GCUR, GEIDX);
    csr_build(tei, ET, NTREE, TCNT, TOFF, TCUR, TEIDX);

    // ---- 3. combined GRU (both branches, one launch) ----
    {
        GruProb Pg = { ETAB_G, gnf, h0g, gWHH0, gWIH1, gWHH1, GH1B, NTG };
        GruProb Pt = { ETAB_T, tnf, h0t, tWHH0, tWIH1, tWHH1, TH1B, NTREE };
        int gblk = (NTG + 31) / 32;      // 313
        int tblk = (NTREE + 31) / 32;    // 938
        gru_fused8<<<gblk + tblk, 448, 0, stream>>>(Pg, Pt, gblk);
    }

    // ---- 4. graph GAT chain ----
    build_xg_bf<<<(NG * 128 + 255) / 256, 256, 0, stream>>>(GH1B, UE, XG_B);
    cvt(gc1W, W_G1, 512, 512, HD, 128);
    cvt(gc2W, W_G2, 100, 100, 512, 512);
    {   // graph GAT1: 8 heads x 64
        mfma(XG_B, 128, W_G1, 128, nullptr, GFEAT1, 512, NG, 512, 4);
        gat_pre(GFEAT1, NG, 8, 64, gc1as, gc1ad, gei, EG);
        int waves = NG * 2;
        gat_accum_csr<64, 4><<<(waves + 3) / 4, 256, 0, stream>>>(
            GOFF, GEIDX, gei, EG, EBB, SB, GFEAT1, gc1b, nullptr, GOUT1B, NG, 8, 512, 2);
    }
    {   // graph GAT2: 1 head x 100
        mfma(GOUT1B, 512, W_G2, 512, nullptr, GFEAT2, 100, NG, 100, 16);
        gat_pre(GFEAT2, NG, 1, 100, gc2as, gc2ad, gei, EG);
        int waves = NG;
        gat_accum_csr<100, 2><<<(waves + 3) / 4, 256, 0, stream>>>(
            GOFF, GEIDX, gei, EG, EBB, SB, GFEAT2, gc2b, XGF, nullptr, NG, 1, 100, 1);
    }

    // ---- 5. tree GAT chain ----
    set_roots<<<(NB * HD + 255) / 256, 256, 0, stream>>>(XGF, TH1B);
    cvt(tc1W, W_G1, 800, 800, HD, 128);
    cvt(tc2W, W_G2, 100, 100, 800, 800);
    {   // tree GAT1: 8 heads x 100
        mfma(TH1B, 128, W_G1, 128, nullptr, TFEAT1, 800, NTREE, 800, 4);
        gat_pre(TFEAT1, NTREE, 8, 100, tc1as, tc1ad, tei, ET);
        int waves = NTREE * 4;
        gat_accum_csr<100, 4><<<(waves + 3) / 4, 256, 0, stream>>>(
            TOFF, TEIDX, tei, ET, EBB, SB, TFEAT1, tc1b, nullptr, TOUT1B, NTREE, 8, 800, 4);
    }
    {   // tree GAT2: 1 head x 100
        mfma(TOUT1B, 800, W_G2, 800, nullptr, TFEAT2, 100, NTREE, 100, 25);
        gat_pre(TFEAT2, NTREE, 1, 100, tc2as, tc2ad, tei, ET);
        int waves = NTREE;
        gat_accum_csr<100, 2><<<(waves + 3) / 4, 256, 0, stream>>>(
            TOFF, TEIDX, tei, ET, EBB, SB, TFEAT2, tc2b, XOUT2, nullptr, NTREE, 1, 100, 1);
    }

    // ---- 6. scatter_mean + classifier ----
    hipMemsetAsync(SSUM, 0, (size_t)NB * HD * 4, stream);
    hipMemsetAsync(SCNT, 0, (size_t)NB * 4, stream);
    scatter_mean_accum<<<(NTREE * HD + 255) / 256, 256, 0, stream>>>(XOUT2, indices, SSUM, SCNT);
    fc_out<<<1, 512, 0, stream>>>(SSUM, SCNT, fcW, fcb, out);
}

// Round 4
// 1669.299 us; speedup vs baseline: 1.1837x; 1.0647x over previous
//
#include <hip/hip_runtime.h>

// ---------------------------------------------------------------------------
// Problem constants
// ---------------------------------------------------------------------------
#define NB    128
#define HD    100
#define NU    20000
#define NTG   10000
#define NTREE 30000
#define NG    30000
#define TT    20
#define EG    200000
#define ET    60000
#define VOC   50000

#define ESTR2 448   // interleaved Etab row stride in u16: [112 cols][4] (r,z,n,pad)
#define WROWS 336   // GRU weight rows: 3 gates x 112 (gate stride 112)

typedef unsigned short u16;
typedef unsigned int   u32;
typedef __attribute__((ext_vector_type(8))) short short8;
typedef __attribute__((ext_vector_type(4))) float floatx4;

__device__ __forceinline__ float sigmoidf_(float x) {
    return __fdividef(1.f, 1.f + __expf(-x));
}
__device__ __forceinline__ float tanhf_(float x) {
    return 1.f - __fdividef(2.f, __expf(2.f * x) + 1.f);
}
__device__ __forceinline__ u16 f2bf(float f) {
    u32 u = __float_as_uint(f);
    u32 r = (u + 0x7fffu + ((u >> 16) & 1u)) >> 16;
    return (u16)r;
}
// 1-inst RNE f32->bf16 (hot path only); v_cvt_pk_bf16_f32 low half
__device__ __forceinline__ u16 f2bf_c(float f) {
    u32 r;
    asm("v_cvt_pk_bf16_f32 %0, %1, %2" : "=v"(r) : "v"(f), "v"(f));
    return (u16)r;
}
__device__ __forceinline__ float bf2f(u16 h) {
    return __uint_as_float(((u32)h) << 16);
}

// ---------------------------------------------------------------------------
// Fused 2-layer GRU v9: 448 threads (7 waves) / 32 rows / TT steps.
// vs v8:
//  - Etab gate-interleaved [VOC][112][4]: per (row,col) ONE dwordx2 gather
//    (r,z,n,pad) replaces 3 scalar u16 gathers at 200B-apart offsets.
//    8 loads/lane/step (was 24), 1 cache line per 16-lane row window (was 3).
//  - f2bf_c (v_cvt_pk_bf16_f32, 1 inst) replaces 4-inst f2bf in hot stores.
// Structure/barriers identical to v8 (region r = B(r) + A(r+1), 1 barrier).
// ---------------------------------------------------------------------------
struct GruProb {
    const u16*   Etab;     // [VOC][112][4] interleaved (includes bih0)
    const int*   nodes;    // [M][TT]
    const float* h0;       // [2][M][100] fp32
    const u16*   Whh0;     // [336][128] gate-padded (col100 = bhh0)
    const u16*   Wih1;     // (col100 = bih1)
    const u16*   Whh1;     // (col100 = bhh1)
    u16*         hout;     // [M][128]
    int          M;
};

__global__ __launch_bounds__(448, 2) void gru_fused9(GruProb Pg, GruProb Pt, int gblocks)
{
    const bool isg = (int)blockIdx.x < gblocks;
    const GruProb P = isg ? Pg : Pt;
    const int bx = isg ? blockIdx.x : blockIdx.x - gblocks;
    const int M  = P.M;
    const int m0 = bx * 32;

    __shared__ u16 H0[2][32 * 128];
    __shared__ u16 H1[2][32 * 128];
    __shared__ int NID[TT * 32];

    const int tid  = threadIdx.x;
    const int w    = tid >> 6, lane = tid & 63;
    const int fr   = lane & 15, quad = lane >> 4;
    const int c    = w * 16 + fr;
    const bool cok = (c < HD);

    short8 Bh0[3][4], Bx1[3][4], Bh1[3][4];
#pragma unroll
    for (int g = 0; g < 3; ++g) {
        const size_t rb = (size_t)((g * 7 + w) * 16 + fr) * 128 + quad * 8;
#pragma unroll
        for (int kk = 0; kk < 4; ++kk) {
            Bh0[g][kk] = *(const short8*)(P.Whh0 + rb + kk * 32);
            Bx1[g][kk] = *(const short8*)(P.Wih1 + rb + kk * 32);
            Bh1[g][kk] = *(const short8*)(P.Whh1 + rb + kk * 32);
        }
    }

    for (int i = tid; i < 32 * 128; i += 448) {
        H0[0][i] = 0; H0[1][i] = 0; H1[0][i] = 0; H1[1][i] = 0;
    }
    for (int i = tid; i < 32 * TT; i += 448) {
        int row = i / TT, t = i - row * TT;
        int gm = m0 + row;
        NID[t * 32 + row] = (gm < M) ? P.nodes[(size_t)gm * TT + t] : 0;
    }
    __syncthreads();
    if (tid < 32) {
        int off = 200 ^ ((tid & 7) << 4);
        *(u16*)((char*)&H0[0][0] + tid * 256 + off) = 0x3F80;
        *(u16*)((char*)&H0[1][0] + tid * 256 + off) = 0x3F80;
        *(u16*)((char*)&H1[0][0] + tid * 256 + off) = 0x3F80;
        *(u16*)((char*)&H1[1][0] + tid * 256 + off) = 0x3F80;
    }

    float h0f[2][4] = {{0.f,0.f,0.f,0.f},{0.f,0.f,0.f,0.f}};
    float h1f[2][4] = {{0.f,0.f,0.f,0.f},{0.f,0.f,0.f,0.f}};
    if (cok) {
#pragma unroll
        for (int rt = 0; rt < 2; ++rt)
#pragma unroll
        for (int r = 0; r < 4; ++r) {
            int row = rt * 16 + quad * 4 + r;
            int gm  = m0 + row;
            float v0 = 0.f, v1 = 0.f;
            if (gm < M) {
                v0 = P.h0[(size_t)gm * HD + c];
                v1 = P.h0[(size_t)(M + gm) * HD + c];
            }
            h0f[rt][r] = v0; h1f[rt][r] = v1;
            int off = (2 * c) ^ ((row & 7) << 4);
            *(u16*)((char*)&H0[0][0] + row * 256 + off) = f2bf_c(v0);
            *(u16*)((char*)&H1[0][0] + row * 256 + off) = f2bf_c(v1);
        }
    }

    // x-gate prefetch: one dwordx2 per (rt,r) -> (r,z) in lo, (n,pad) in hi
    u32 xlo[2][4], xhi[2][4];
    auto xpref = [&](int tn) {
        if (cok) {
#pragma unroll
            for (int rt = 0; rt < 2; ++rt)
#pragma unroll
            for (int r = 0; r < 4; ++r) {
                int row = rt * 16 + quad * 4 + r;
                int nd  = NID[tn * 32 + row];
                uint2 v = *(const uint2*)(P.Etab + (size_t)nd * ESTR2 + c * 4);
                xlo[rt][r] = v.x; xhi[rt][r] = v.y;
            }
        }
    };
    __syncthreads();
    xpref(0);

    // ---- prologue: A(0) ----
#pragma unroll
    for (int rt = 0; rt < 2; ++rt) {
        short8 a[4];
#pragma unroll
        for (int kk = 0; kk < 4; ++kk) {
            int row = rt * 16 + fr;
            int off = (kk * 64 + quad * 16) ^ ((row & 7) << 4);
            a[kk] = *(const short8*)((const char*)&H0[0][0] + row * 256 + off);
        }
        floatx4 ag[3];
#pragma unroll
        for (int g = 0; g < 3; ++g) ag[g] = (floatx4){0.f, 0.f, 0.f, 0.f};
#pragma unroll
        for (int g = 0; g < 3; ++g)
#pragma unroll
            for (int kk = 0; kk < 4; ++kk)
                ag[g] = __builtin_amdgcn_mfma_f32_16x16x32_bf16(a[kk], Bh0[g][kk], ag[g], 0, 0, 0);
        if (cok) {
#pragma unroll
            for (int r = 0; r < 4; ++r) {
                int row = rt * 16 + quad * 4 + r;
                float rr = sigmoidf_(bf2f((u16)xlo[rt][r]) + ag[0][r]);
                float zz = sigmoidf_(bf2f((u16)(xlo[rt][r] >> 16)) + ag[1][r]);
                float nn = tanhf_(bf2f((u16)xhi[rt][r]) + rr * ag[2][r]);
                float o  = (1.f - zz) * nn + zz * h0f[rt][r];
                h0f[rt][r] = o;
                *(u16*)((char*)&H0[1][0] + row * 256 + ((2 * c) ^ ((row & 7) << 4))) = f2bf_c(o);
            }
        }
    }
    __syncthreads();

    // ---- regions r = 0..TT-1: B(r) + A(r+1) ----
    for (int r = 0; r < TT; ++r) {
        const bool doA = (r + 1 < TT);
        if (doA) xpref(r + 1);

        const char* rd0 = (const char*)&H0[(r + 1) & 1][0];
        const char* rd1 = (const char*)&H1[r & 1][0];
        char*       wr0 = (char*)&H0[r & 1][0];
        char*       wr1 = (char*)&H1[(r + 1) & 1][0];

#pragma unroll
        for (int rt = 0; rt < 2; ++rt) {
            short8 a0[4], a1[4];
#pragma unroll
            for (int kk = 0; kk < 4; ++kk) {
                int row = rt * 16 + fr;
                int off = (kk * 64 + quad * 16) ^ ((row & 7) << 4);
                a0[kk] = *(const short8*)(rd0 + row * 256 + off);
                a1[kk] = *(const short8*)(rd1 + row * 256 + off);
            }
            floatx4 rz0 = {0.f,0.f,0.f,0.f}, rz1 = {0.f,0.f,0.f,0.f};
            floatx4 xnv = {0.f,0.f,0.f,0.f}, hnv = {0.f,0.f,0.f,0.f};
#pragma unroll
            for (int kk = 0; kk < 4; ++kk)
                rz0 = __builtin_amdgcn_mfma_f32_16x16x32_bf16(a0[kk], Bx1[0][kk], rz0, 0, 0, 0);
#pragma unroll
            for (int kk = 0; kk < 4; ++kk)
                rz0 = __builtin_amdgcn_mfma_f32_16x16x32_bf16(a1[kk], Bh1[0][kk], rz0, 0, 0, 0);
#pragma unroll
            for (int kk = 0; kk < 4; ++kk)
                rz1 = __builtin_amdgcn_mfma_f32_16x16x32_bf16(a0[kk], Bx1[1][kk], rz1, 0, 0, 0);
#pragma unroll
            for (int kk = 0; kk < 4; ++kk)
                rz1 = __builtin_amdgcn_mfma_f32_16x16x32_bf16(a1[kk], Bh1[1][kk], rz1, 0, 0, 0);
#pragma unroll
            for (int kk = 0; kk < 4; ++kk)
                xnv = __builtin_amdgcn_mfma_f32_16x16x32_bf16(a0[kk], Bx1[2][kk], xnv, 0, 0, 0);
#pragma unroll
            for (int kk = 0; kk < 4; ++kk)
                hnv = __builtin_amdgcn_mfma_f32_16x16x32_bf16(a1[kk], Bh1[2][kk], hnv, 0, 0, 0);
            floatx4 ag[3];
#pragma unroll
            for (int g = 0; g < 3; ++g) ag[g] = (floatx4){0.f, 0.f, 0.f, 0.f};
            if (doA) {
#pragma unroll
                for (int g = 0; g < 3; ++g)
#pragma unroll
                    for (int kk = 0; kk < 4; ++kk)
                        ag[g] = __builtin_amdgcn_mfma_f32_16x16x32_bf16(a0[kk], Bh0[g][kk], ag[g], 0, 0, 0);
            }
            if (cok) {
#pragma unroll
                for (int r4 = 0; r4 < 4; ++r4) {
                    int row = rt * 16 + quad * 4 + r4;
                    float rr = sigmoidf_(rz0[r4]);
                    float zz = sigmoidf_(rz1[r4]);
                    float nn = tanhf_(xnv[r4] + rr * hnv[r4]);
                    float o  = (1.f - zz) * nn + zz * h1f[rt][r4];
                    h1f[rt][r4] = o;
                    *(u16*)(wr1 + row * 256 + ((2 * c) ^ ((row & 7) << 4))) = f2bf_c(o);
                }
                if (doA) {
#pragma unroll
                    for (int r4 = 0; r4 < 4; ++r4) {
                        int row = rt * 16 + quad * 4 + r4;
                        float rr = sigmoidf_(bf2f((u16)xlo[rt][r4]) + ag[0][r4]);
                        float zz = sigmoidf_(bf2f((u16)(xlo[rt][r4] >> 16)) + ag[1][r4]);
                        float nn = tanhf_(bf2f((u16)xhi[rt][r4]) + rr * ag[2][r4]);
                        float o  = (1.f - zz) * nn + zz * h0f[rt][r4];
                        h0f[rt][r4] = o;
                        *(u16*)(wr0 + row * 256 + ((2 * c) ^ ((row & 7) << 4))) = f2bf_c(o);
                    }
                }
            }
        }
        __syncthreads();
    }

    for (int i = tid; i < 32 * 128; i += 448) {
        int row = i >> 7, cc = i & 127;
        int gm = m0 + row;
        if (gm < M) {
            int off = (2 * cc) ^ ((row & 7) << 4);
            P.hout[(size_t)gm * 128 + cc] = *(const u16*)((const char*)&H1[0][0] + row * 256 + off);
        }
    }
}

// ---------------------------------------------------------------------------
// bf16 MFMA GEMM (Etab build + GAT feature GEMMs)
// ileave=1: store C bf16 gate-interleaved [M][112][4]: g=col/100, cc=col%100
// ---------------------------------------------------------------------------
#define LDST 40
__global__ __launch_bounds__(256) void gemm_mfma(
    const u16* __restrict__ A, const u16* __restrict__ B,
    float* __restrict__ Cf, u16* __restrict__ Cb,
    int M, int N, int Kt, int lda, int ldw, int ldc, int ileave)
{
    const int m0 = blockIdx.x * 64;
    if (m0 >= M) return;
    const int n0 = blockIdx.y * 64;

    __shared__ u16 Als[64 * LDST];
    __shared__ u16 Wls[64 * LDST];

    const int tid  = threadIdx.x;
    const int wave = tid >> 6, lane = tid & 63;
    const int row  = tid >> 2, part = (tid & 3) * 8;
    const int fr   = lane & 15, quad = lane >> 4;

    floatx4 acc[4];
#pragma unroll
    for (int t = 0; t < 4; ++t) acc[t] = (floatx4){0.f, 0.f, 0.f, 0.f};

    const int am = m0 + row;  const bool aok = am < M;
    const int wn = n0 + row;  const bool wok = wn < N;
    const uint4 z4 = {0u, 0u, 0u, 0u};

    for (int kk = 0; kk < Kt; ++kk) {
        uint4 av = aok ? *(const uint4*)(A + (size_t)am * lda + kk * 32 + part) : z4;
        uint4 wv = wok ? *(const uint4*)(B + (size_t)wn * ldw + kk * 32 + part) : z4;
        __syncthreads();
        *(uint4*)&Als[row * LDST + part] = av;
        *(uint4*)&Wls[row * LDST + part] = wv;
        __syncthreads();
        short8 af = *(const short8*)&Als[((wave << 4) + fr) * LDST + quad * 8];
#pragma unroll
        for (int t = 0; t < 4; ++t) {
            short8 bf = *(const short8*)&Wls[((t << 4) + fr) * LDST + quad * 8];
            acc[t] = __builtin_amdgcn_mfma_f32_16x16x32_bf16(af, bf, acc[t], 0, 0, 0);
        }
    }

    const int orow0 = m0 + (wave << 4) + quad * 4;
#pragma unroll
    for (int t = 0; t < 4; ++t) {
        int col = n0 + (t << 4) + fr;
        if (col >= N) continue;
#pragma unroll
        for (int r = 0; r < 4; ++r) {
            int mr = orow0 + r;
            if (mr >= M) continue;
            float v = acc[t][r];
            if (Cf) Cf[(size_t)mr * ldc + col] = v;
            if (Cb) {
                if (ileave) {
                    int g = col / 100, cc = col - g * 100;
                    Cb[(size_t)mr * ESTR2 + cc * 4 + g] = f2bf(v);
                } else {
                    Cb[(size_t)mr * ldc + col] = f2bf(v);
                }
            }
        }
    }
}

// ---------------------------------------------------------------------------
// fp32 tiled GEMM (user-embed MLP only)
// ---------------------------------------------------------------------------
__global__ __launch_bounds__(256) void gemm_nt(
    const float* __restrict__ A, const float* __restrict__ W,
    const float* __restrict__ bias, float* __restrict__ C,
    int M, int N, int K, int relu)
{
    const int m0 = blockIdx.x * 64;
    const int n0 = blockIdx.y * 64;
    __shared__ float As[20][68];
    __shared__ float Ws[20][68];
    const int tid = threadIdx.x;
    const int r0 = (tid >> 4) * 4;
    const int c0 = (tid & 15) * 4;
    int sr[5], sk[5];
#pragma unroll
    for (int it = 0; it < 5; ++it) {
        int idx = tid + it * 256;
        sr[it] = idx / 20; sk[it] = idx - sr[it] * 20;
    }
    float acc[4][4];
#pragma unroll
    for (int i = 0; i < 4; ++i)
#pragma unroll
        for (int j = 0; j < 4; ++j) acc[i][j] = 0.f;
    const int nch = (K + 19) / 20;
    for (int ch = 0; ch < nch; ++ch) {
        const int k0 = ch * 20;
#pragma unroll
        for (int it = 0; it < 5; ++it) {
            int m = m0 + sr[it], k = k0 + sk[it];
            float va = 0.f, vw = 0.f;
            if (k < K) {
                if (m < M) va = A[(size_t)m * K + k];
                int n = n0 + sr[it];
                if (n < N) vw = W[(size_t)n * K + k];
            }
            As[sk[it]][sr[it]] = va;
            Ws[sk[it]][sr[it]] = vw;
        }
        __syncthreads();
#pragma unroll
        for (int kkk = 0; kkk < 20; ++kkk) {
            float4 a = *(const float4*)&As[kkk][r0];
            float4 w = *(const float4*)&Ws[kkk][c0];
            float av[4] = {a.x, a.y, a.z, a.w};
            float wv[4] = {w.x, w.y, w.z, w.w};
#pragma unroll
            for (int i = 0; i < 4; ++i)
#pragma unroll
                for (int j = 0; j < 4; ++j)
                    acc[i][j] = fmaf(av[i], wv[j], acc[i][j]);
        }
        __syncthreads();
    }
#pragma unroll
    for (int i = 0; i < 4; ++i) {
        int m = m0 + r0 + i;
        if (m >= M) continue;
#pragma unroll
        for (int j = 0; j < 4; ++j) {
            int n = n0 + c0 + j;
            if (n >= N) continue;
            float v = acc[i][j] + (bias ? bias[n] : 0.f);
            if (relu) v = fmaxf(v, 0.f);
            C[(size_t)m * N + n] = v;
        }
    }
}

// fp32 [M][K] -> bf16 [Mp][ldk]; col K..ldk zero, except col 100 gets
// app[n] (if app) or 1.0 (if appone).
__global__ void convert_pad2(const float* __restrict__ src, u16* __restrict__ dst,
                             int M, int Mp, int K, int ldk,
                             const float* __restrict__ app, int appone)
{
    int t = blockIdx.x * blockDim.x + threadIdx.x;
    if (t >= Mp * ldk) return;
    int n = t / ldk, c = t - n * ldk;
    u16 o = 0;
    if (n < M) {
        if (c < K) o = f2bf(src[(size_t)n * K + c]);
        else if (c == 100) {
            if (app) o = f2bf(app[n]);
            else if (appone) o = 0x3F80;
        }
    }
    dst[t] = o;
}

// Batched GRU weight converts: 6 matrices -> gate-padded bf16 [336][128]
struct CvtgBatch {
    const float* src[6];
    const float* bias[6];
    u16*         dst[6];
};
#define CVTG_BLOCKS_PER_MAT 168   // 336*128/256
__global__ void convert_gru_w6(CvtgBatch B)
{
    int mat = blockIdx.x / CVTG_BLOCKS_PER_MAT;
    int t = (blockIdx.x - mat * CVTG_BLOCKS_PER_MAT) * blockDim.x + threadIdx.x;
    int rr = t >> 7, cc = t & 127;
    int g = rr / 112, r2 = rr - g * 112;
    u16 o = 0;
    if (r2 < 100) {
        int sr = g * 100 + r2;
        if (cc < 100) o = f2bf(B.src[mat][(size_t)sr * 100 + cc]);
        else if (cc == 100) o = f2bf(B.bias[mat][sr]);
    }
    B.dst[mat][t] = o;
}

// xg (bf16 [NG][128]) = concat(hg[:128], ue, hg[128:])
__global__ void build_xg_bf(const u16* __restrict__ hgb, const float* __restrict__ ue,
                            u16* __restrict__ xgb)
{
    int t = blockIdx.x * blockDim.x + threadIdx.x;
    if (t >= NG * 128) return;
    int n = t >> 7, c = t & 127;
    u16 o = 0;
    if (n < NB)           o = hgb[n * 128 + c];
    else if (n < NB + NU) { if (c < HD) o = f2bf(ue[(size_t)(n - NB) * HD + c]); }
    else                  o = hgb[(size_t)(n - NU) * 128 + c];
    xgb[t] = o;
}

__global__ void set_roots(const float* __restrict__ src, u16* __restrict__ hb)
{
    int t = blockIdx.x * blockDim.x + threadIdx.x;
    if (t >= NB * HD) return;
    int n = t / HD, c = t - n * HD;
    hb[(size_t)n * 128 + c] = f2bf(src[t]);
}

// ---------------------------------------------------------------------------
// CSR build
// ---------------------------------------------------------------------------
__global__ void csr_count(const int* __restrict__ ei, int E, int N, int* __restrict__ cnt)
{
    int e = blockIdx.x * blockDim.x + threadIdx.x;
    if (e >= E + N) return;
    int dst = (e < E) ? ei[E + e] : e - E;
    atomicAdd(&cnt[dst], 1);
}

__global__ void csr_scan(const int* __restrict__ cnt, int* __restrict__ off,
                         int* __restrict__ cur, int N)
{
    __shared__ int part[256];
    const int tid = threadIdx.x;
    const int per = (N + 255) / 256;
    const int i0 = tid * per;
    const int i1 = min(i0 + per, N);
    int s = 0;
    for (int i = i0; i < i1; ++i) s += cnt[i];
    part[tid] = s;
    __syncthreads();
    for (int o = 1; o < 256; o <<= 1) {
        int u = (tid >= o) ? part[tid - o] : 0;
        __syncthreads();
        part[tid] += u;
        __syncthreads();
    }
    int base = part[tid] - s;
    for (int i = i0; i < i1; ++i) {
        off[i] = base; cur[i] = base;
        base += cnt[i];
    }
    if (tid == 255) off[N] = part[255];
}

__global__ void csr_scatter(const int* __restrict__ ei, int E, int N,
                            int* __restrict__ cur, int* __restrict__ eidx)
{
    int e = blockIdx.x * blockDim.x + threadIdx.x;
    if (e >= E + N) return;
    int dst = (e < E) ? ei[E + e] : e - E;
    int pos = atomicAdd(&cur[dst], 1);
    eidx[pos] = e;
}

// ---------------------------------------------------------------------------
// GAT pieces (feat is bf16); es_ed also initializes m (=-inf bits) and s (=0)
// ---------------------------------------------------------------------------
__global__ void gat_es_ed(const u16* __restrict__ feat, const float* __restrict__ asrc,
                          const float* __restrict__ adst, float* __restrict__ es,
                          float* __restrict__ ed, float* __restrict__ m,
                          float* __restrict__ s, int N, int heads, int C)
{
    int gid = blockIdx.x * blockDim.x + threadIdx.x;
    if (gid >= N * heads) return;
    int n = gid / heads, hd = gid - n * heads;
    const u16* hp = feat + ((size_t)n * heads + hd) * C;
    const float* as = asrc + (size_t)hd * C;
    const float* ad = adst + (size_t)hd * C;
    float s1 = 0.f, s2 = 0.f;
    for (int c = 0; c < C; c += 4) {
        uint2 pk = *(const uint2*)(hp + c);
        float v0 = bf2f((u16)(pk.x & 0xffff)), v1 = bf2f((u16)(pk.x >> 16));
        float v2 = bf2f((u16)(pk.y & 0xffff)), v3 = bf2f((u16)(pk.y >> 16));
        s1 += v0 * as[c] + v1 * as[c + 1] + v2 * as[c + 2] + v3 * as[c + 3];
        s2 += v0 * ad[c] + v1 * ad[c + 1] + v2 * ad[c + 2] + v3 * ad[c + 3];
    }
    es[gid] = s1; ed[gid] = s2;
    m[gid] = __uint_as_float(0xFFFFFFFFu);   // init for atomic_max_f
    s[gid] = 0.f;
}

__device__ __forceinline__ void atomic_max_f(float* addr, float v)
{
    if (v >= 0.f) atomicMax((int*)addr, __float_as_int(v));
    else          atomicMin((unsigned int*)addr, __float_as_uint(v));
}

__global__ void gat_edge_logit(const int* __restrict__ ei, int E, int N, int heads,
                               const float* __restrict__ es, const float* __restrict__ ed,
                               float* __restrict__ eb, float* __restrict__ m)
{
    int gid = blockIdx.x * blockDim.x + threadIdx.x;
    int EE = E + N;
    if (gid >= EE * heads) return;
    int idx = gid / heads, hd = gid - idx * heads;
    int src, dst;
    if (idx < E) { src = ei[idx]; dst = ei[E + idx]; } else { src = dst = idx - E; }
    float e = es[src * heads + hd] + ed[dst * heads + hd];
    e = e > 0.f ? e : 0.2f * e;
    eb[gid] = e;
    atomic_max_f(&m[dst * heads + hd], e);
}

__global__ void gat_edge_expsum(const int* __restrict__ ei, int E, int N, int heads,
                                float* __restrict__ eb, const float* __restrict__ m,
                                float* __restrict__ s)
{
    int gid = blockIdx.x * blockDim.x + threadIdx.x;
    int EE = E + N;
    if (gid >= EE * heads) return;
    int idx = gid / heads, hd = gid - idx * heads;
    int dst = (idx < E) ? ei[E + idx] : idx - E;
    float e = __expf(eb[gid] - m[dst * heads + hd]);
    eb[gid] = e;
    atomicAdd(&s[dst * heads + hd], e);
}

template<int C, int VEC>
__global__ __launch_bounds__(256) void gat_accum_csr(
    const int* __restrict__ off, const int* __restrict__ eidx,
    const int* __restrict__ ei, int E,
    const float* __restrict__ eb, const float* __restrict__ s,
    const u16* __restrict__ feat, const float* __restrict__ bias,
    float* __restrict__ outf, u16* __restrict__ outb,
    int N, int heads, int HC, int nchunk)
{
    int gt = blockIdx.x * blockDim.x + threadIdx.x;
    int w = gt >> 6, lane = gt & 63;
    int dst = w / nchunk, chunk = w - dst * nchunk;
    if (dst >= N) return;
    int c0 = chunk * 64 * VEC + lane * VEC;
    if (c0 >= HC) return;
    int hh[VEC]; float sinv[VEC], acc[VEC];
#pragma unroll
    for (int v = 0; v < VEC; ++v) {
        int c = c0 + v;
        hh[v] = c / C;
        sinv[v] = __fdividef(1.f, s[dst * heads + hh[v]]);
        acc[v] = 0.f;
    }
    int e0 = off[dst], e1 = off[dst + 1];
    for (int p = e0; p < e1; ++p) {
        int j = eidx[p];
        int src = (j < E) ? ei[j] : (j - E);
        const u16* frp = feat + (size_t)src * HC + c0;
        float fv[VEC];
        if (VEC == 4) {
            uint2 pk = *(const uint2*)frp;
            fv[0] = bf2f((u16)(pk.x & 0xffff)); fv[1] = bf2f((u16)(pk.x >> 16));
            fv[2] = bf2f((u16)(pk.y & 0xffff)); fv[3] = bf2f((u16)(pk.y >> 16));
        } else {
            u32 pk = *(const u32*)frp;
            fv[0] = bf2f((u16)(pk & 0xffff)); fv[1] = bf2f((u16)(pk >> 16));
        }
#pragma unroll
        for (int v = 0; v < VEC; ++v)
            acc[v] += fv[v] * eb[(size_t)j * heads + hh[v]] * sinv[v];
    }
#pragma unroll
    for (int v = 0; v < VEC; ++v) {
        int c = c0 + v;
        float o = fmaxf(acc[v] + bias[c], 0.f);
        if (outf) outf[(size_t)dst * HC + c] = o;
        if (outb) outb[(size_t)dst * HC + c] = f2bf(o);
    }
}

__global__ void scatter_mean_accum(const float* __restrict__ x, const int* __restrict__ idx,
                                   float* __restrict__ ssum, float* __restrict__ cnt)
{
    int t = blockIdx.x * blockDim.x + threadIdx.x;
    if (t >= NTREE * HD) return;
    int n = t / HD, c = t - n * HD;
    int b = idx[n];
    atomicAdd(&ssum[b * HD + c], x[t]);
    if (c == 0) atomicAdd(&cnt[b], 1.f);
}

__global__ void fc_out(const float* __restrict__ ssum, const float* __restrict__ cnt,
                       const float* __restrict__ W, const float* __restrict__ b,
                       float* __restrict__ out)
{
    int t = threadIdx.x;                 // 512 threads
    int bb = t >> 2, j = t & 3;
    float inv = __fdividef(1.f, fmaxf(cnt[bb], 1.f));
    float acc = b[j];
    for (int k = 0; k < HD; ++k) acc += ssum[bb * HD + k] * inv * W[j * HD + k];
    out[t] = acc;
}

// ---------------------------------------------------------------------------
// Host launcher
// ---------------------------------------------------------------------------
extern "C" void kernel_launch(void* const* d_in, const int* in_sizes, int n_in,
                              void* d_out, int out_size, void* d_ws, size_t ws_size,
                              hipStream_t stream)
{
    const float* user_feats = (const float*)d_in[1];
    const int*   gnf        = (const int*)d_in[2];
    const int*   gei        = (const int*)d_in[3];
    const int*   tnf        = (const int*)d_in[4];
    const int*   tei        = (const int*)d_in[5];
    const int*   indices    = (const int*)d_in[6];
    const float* h0g        = (const float*)d_in[7];
    const float* h0t        = (const float*)d_in[8];
    const float* temb       = (const float*)d_in[9];
    const float* gW[2][4] = {{(const float*)d_in[10], (const float*)d_in[11], (const float*)d_in[12], (const float*)d_in[13]},
                             {(const float*)d_in[14], (const float*)d_in[15], (const float*)d_in[16], (const float*)d_in[17]}};
    const float* tW[2][4] = {{(const float*)d_in[18], (const float*)d_in[19], (const float*)d_in[20], (const float*)d_in[21]},
                             {(const float*)d_in[22], (const float*)d_in[23], (const float*)d_in[24], (const float*)d_in[25]}};
    const float* uW1 = (const float*)d_in[26]; const float* ub1 = (const float*)d_in[27];
    const float* uW2 = (const float*)d_in[28]; const float* ub2 = (const float*)d_in[29];
    const float* gc1W = (const float*)d_in[30]; const float* gc1as = (const float*)d_in[31];
    const float* gc1ad = (const float*)d_in[32]; const float* gc1b = (const float*)d_in[33];
    const float* gc2W = (const float*)d_in[34]; const float* gc2as = (const float*)d_in[35];
    const float* gc2ad = (const float*)d_in[36]; const float* gc2b = (const float*)d_in[37];
    const float* tc1W = (const float*)d_in[38]; const float* tc1as = (const float*)d_in[39];
    const float* tc1ad = (const float*)d_in[40]; const float* tc1b = (const float*)d_in[41];
    const float* tc2W = (const float*)d_in[42]; const float* tc2as = (const float*)d_in[43];
    const float* tc2ad = (const float*)d_in[44]; const float* tc2b = (const float*)d_in[45];
    const float* fcW = (const float*)d_in[46]; const float* fcb = (const float*)d_in[47];
    float* out = (float*)d_out;

    char* ws = (char*)d_ws;
    const size_t NEED = 226500000;
    if (ws_size < NEED) return;

    // ---- workspace layout (decimal byte offsets, overlays noted) ----
    float* XGF    = (float*)(ws + 0);            // 12 MB [NG][100] fp32
    u16*   TEMB_B = (u16*)(ws + 12000000);       // 12.8 MB [VOC][128]
    u16*   ETAB_G = (u16*)(ws + 25000000);       // 44.8 MB [VOC][448] interleaved
    u16*   ETAB_T = (u16*)(ws + 70000000);       // 44.8 MB -> 114.8
    u16*   GH1B   = (u16*)(ws + 115000000);      // 2.56 MB [NTG][128]
    u16*   TH1B   = (u16*)(ws + 117600000);      // 7.68 MB [NTREE][128]
    float* UE     = (float*)(ws + 125300000);    // 8 MB
    float* HID    = (float*)(ws + 133400000);    // 8 MB
    u16*   WARENA = (u16*)(ws + 141500000);      // 1.1 MB weight arena
    int*   GOFF   = (int*)(ws + 142700000);
    int*   GCUR   = (int*)(ws + 142900000);
    int*   GCNT   = (int*)(ws + 143100000);
    int*   GEIDX  = (int*)(ws + 143300000);      // 0.92 MB
    int*   TOFF   = (int*)(ws + 144300000);
    int*   TCUR   = (int*)(ws + 144500000);
    int*   TCNT   = (int*)(ws + 144700000);
    int*   TEIDX  = (int*)(ws + 144900000);      // 0.36 MB
    float* ESB    = (float*)(ws + 145300000);
    float* EDB    = (float*)(ws + 146300000);
    float* MB     = (float*)(ws + 147300000);
    float* SB     = (float*)(ws + 148300000);
    float* EBB    = (float*)(ws + 149300000);    // 7.36 MB
    float* SSUM   = (float*)(ws + 156700000);
    float* SCNT   = (float*)(ws + 156800000);
    u16*   XG_B   = (u16*)(ws + 157000000);      // 7.68 MB [NG][128]
    u16*   GFEAT1 = (u16*)(ws + 165000000);      // 30.72 MB [NG][512] -> 195.72
    // overlays (regions dead by the time they're written):
    u16*   GOUT1B = (u16*)(ws + 25000000);       // 30.72 MB (over ETAB_G, dead after GRU)
    u16*   GFEAT2 = (u16*)(ws + 56000000);       // 6 MB [NG][100]
    u16*   TFEAT1 = (u16*)(ws + 25000000);       // 48 MB [NTREE][800] (after graph GATs)
    u16*   TOUT1B = (u16*)(ws + 74000000);       // 48 MB (over ETAB_T/GH1B/TH1B-tail, dead)
    u16*   TFEAT2 = (u16*)(ws + 123000000);      // 6 MB (over TH1B-tail/UE, dead)
    float* XOUT2  = (float*)(ws + 157000000);    // 12 MB (over XG_B/GFEAT1-head, dead)

    // weight arena slots (u16 element offsets); each GRU W = [336][128]
    u16* gWHH0 = WARENA + 0;
    u16* gWIH1 = WARENA + 43008;
    u16* gWHH1 = WARENA + 86016;
    u16* tWHH0 = WARENA + 129024;
    u16* tWIH1 = WARENA + 172032;
    u16* tWHH1 = WARENA + 215040;
    u16* W_IH0A = WARENA + 258048;   // [320][128] scratch for Etab builds
    u16* W_IH0B = WARENA + 299008;
    u16* W_G1  = WARENA + 339968;    // up to [800][128]
    u16* W_G2  = WARENA + 442368;    // up to [100][800] -> end 522368 u16 (1.045 MB)

    auto cvt = [&](const float* src, u16* dst, int M, int Mp, int K, int ldk,
                   const float* app = nullptr, int appone = 0) {
        convert_pad2<<<((size_t)Mp * ldk + 255) / 256, 256, 0, stream>>>(
            src, dst, M, Mp, K, ldk, app, appone);
    };
    auto mfma = [&](const u16* A, int lda, const u16* W, int ldw,
                    float* Cf, u16* Cb, int ldc, int M, int N, int Kt, int ileave = 0) {
        dim3 grid((M + 63) / 64, (N + 63) / 64, 1);
        gemm_mfma<<<grid, 256, 0, stream>>>(A, W, Cf, Cb, M, N, Kt, lda, ldw, ldc, ileave);
    };
    auto csr_build = [&](const int* ei, int E, int N, int* cnt, int* off, int* cur, int* eidx) {
        hipMemsetAsync(cnt, 0, (size_t)N * 4, stream);
        csr_count<<<(E + N + 255) / 256, 256, 0, stream>>>(ei, E, N, cnt);
        csr_scan<<<1, 256, 0, stream>>>(cnt, off, cur, N);
        csr_scatter<<<(E + N + 255) / 256, 256, 0, stream>>>(ei, E, N, cur, eidx);
    };
    auto gat_pre = [&](const u16* feat, int N, int heads, int C,
                       const float* asrc, const float* adst, const int* ei, int E) {
        gat_es_ed<<<(N * heads + 255) / 256, 256, 0, stream>>>(
            feat, asrc, adst, ESB, EDB, MB, SB, N, heads, C);
        int EE = E + N;
        gat_edge_logit<<<(EE * heads + 255) / 256, 256, 0, stream>>>(ei, E, N, heads, ESB, EDB, EBB, MB);
        gat_edge_expsum<<<(EE * heads + 255) / 256, 256, 0, stream>>>(ei, E, N, heads, EBB, MB, SB);
    };

    // ---- 1. user embed (fp32) ----
    {
        dim3 g1((NU + 63) / 64, (HD + 63) / 64, 1);
        gemm_nt<<<g1, 256, 0, stream>>>(user_feats, uW1, ub1, HID, NU, HD, 9, 1);
        gemm_nt<<<g1, 256, 0, stream>>>(HID, uW2, ub2, UE, NU, HD, HD, 0);
    }

    // ---- 2. converts + Etab builds (gate-interleaved) ----
    cvt(temb, TEMB_B, VOC, VOC, HD, 128, nullptr, 1);           // col100 = 1
    {
        CvtgBatch B;
        B.src[0] = gW[0][1]; B.bias[0] = gW[0][3]; B.dst[0] = gWHH0;
        B.src[1] = gW[1][0]; B.bias[1] = gW[1][2]; B.dst[1] = gWIH1;
        B.src[2] = gW[1][1]; B.bias[2] = gW[1][3]; B.dst[2] = gWHH1;
        B.src[3] = tW[0][1]; B.bias[3] = tW[0][3]; B.dst[3] = tWHH0;
        B.src[4] = tW[1][0]; B.bias[4] = tW[1][2]; B.dst[4] = tWIH1;
        B.src[5] = tW[1][1]; B.bias[5] = tW[1][3]; B.dst[5] = tWHH1;
        convert_gru_w6<<<6 * CVTG_BLOCKS_PER_MAT, 256, 0, stream>>>(B);
    }
    cvt(gW[0][0], W_IH0A, 300, 320, HD, 128, gW[0][2]);         // + bih0
    cvt(tW[0][0], W_IH0B, 300, 320, HD, 128, tW[0][2]);
    mfma(TEMB_B, 128, W_IH0A, 128, nullptr, ETAB_G, ESTR2, VOC, 300, 4, 1);
    mfma(TEMB_B, 128, W_IH0B, 128, nullptr, ETAB_T, ESTR2, VOC, 300, 4, 1);

    // CSR for both graphs
    csr_build(gei, EG, NG, GCNT, GOFF, GCUR, GEIDX);
    csr_build(tei, ET, NTREE, TCNT, TOFF, TCUR, TEIDX);

    // ---- 3. combined GRU (both branches, one launch) ----
    {
        GruProb Pg = { ETAB_G, gnf, h0g, gWHH0, gWIH1, gWHH1, GH1B, NTG };
        GruProb Pt = { ETAB_T, tnf, h0t, tWHH0, tWIH1, tWHH1, TH1B, NTREE };
        int gblk = (NTG + 31) / 32;      // 313
        int tblk = (NTREE + 31) / 32;    // 938
        gru_fused9<<<gblk + tblk, 448, 0, stream>>>(Pg, Pt, gblk);
    }

    // ---- 4. graph GAT chain ----
    build_xg_bf<<<(NG * 128 + 255) / 256, 256, 0, stream>>>(GH1B, UE, XG_B);
    cvt(gc1W, W_G1, 512, 512, HD, 128);
    cvt(gc2W, W_G2, 100, 100, 512, 512);
    {   // graph GAT1: 8 heads x 64
        mfma(XG_B, 128, W_G1, 128, nullptr, GFEAT1, 512, NG, 512, 4);
        gat_pre(GFEAT1, NG, 8, 64, gc1as, gc1ad, gei, EG);
        int waves = NG * 2;
        gat_accum_csr<64, 4><<<(waves + 3) / 4, 256, 0, stream>>>(
            GOFF, GEIDX, gei, EG, EBB, SB, GFEAT1, gc1b, nullptr, GOUT1B, NG, 8, 512, 2);
    }
    {   // graph GAT2: 1 head x 100
        mfma(GOUT1B, 512, W_G2, 512, nullptr, GFEAT2, 100, NG, 100, 16);
        gat_pre(GFEAT2, NG, 1, 100, gc2as, gc2ad, gei, EG);
        int waves = NG;
        gat_accum_csr<100, 2><<<(waves + 3) / 4, 256, 0, stream>>>(
            GOFF, GEIDX, gei, EG, EBB, SB, GFEAT2, gc2b, XGF, nullptr, NG, 1, 100, 1);
    }

    // ---- 5. tree GAT chain ----
    set_roots<<<(NB * HD + 255) / 256, 256, 0, stream>>>(XGF, TH1B);
    cvt(tc1W, W_G1, 800, 800, HD, 128);
    cvt(tc2W, W_G2, 100, 100, 800, 800);
    {   // tree GAT1: 8 heads x 100
        mfma(TH1B, 128, W_G1, 128, nullptr, TFEAT1, 800, NTREE, 800, 4);
        gat_pre(TFEAT1, NTREE, 8, 100, tc1as, tc1ad, tei, ET);
        int waves = NTREE * 4;
        gat_accum_csr<100, 4><<<(waves + 3) / 4, 256, 0, stream>>>(
            TOFF, TEIDX, tei, ET, EBB, SB, TFEAT1, tc1b, nullptr, TOUT1B, NTREE, 8, 800, 4);
    }
    {   // tree GAT2: 1 head x 100
        mfma(TOUT1B, 800, W_G2, 800, nullptr, TFEAT2, 100, NTREE, 100, 25);
        gat_pre(TFEAT2, NTREE, 1, 100, tc2as, tc2ad, tei, ET);
        int waves = NTREE;
        gat_accum_csr<100, 2><<<(waves + 3) / 4, 256, 0, stream>>>(
            TOFF, TEIDX, tei, ET, EBB, SB, TFEAT2, tc2b, XOUT2, nullptr, NTREE, 1, 100, 1);
    }

    // ---- 6. scatter_mean + classifier ----
    hipMemsetAsync(SSUM, 0, (size_t)NB * HD * 4, stream);
    hipMemsetAsync(SCNT, 0, (size_t)NB * 4, stream);
    scatter_mean_accum<<<(NTREE * HD + 255) / 256, 256, 0, stream>>>(XOUT2, indices, SSUM, SCNT);
    fc_out<<<1, 512, 0, stream>>>(SSUM, SCNT, fcW, fcb, out);
}

// Round 5
// 1546.646 us; speedup vs baseline: 1.2776x; 1.0793x over previous
//
#include <hip/hip_runtime.h>

// ---------------------------------------------------------------------------
// Problem constants
// ---------------------------------------------------------------------------
#define NB    128
#define HD    100
#define NU    20000
#define NTG   10000
#define NTREE 30000
#define NG    30000
#define TT    20
#define EG    200000
#define ET    60000
#define VOC   50000

#define ESTR2 448   // interleaved Etab row stride in u16: [112 cols][4] (r,z,n,pad)
#define WROWS 336   // GRU weight rows: 3 gates x 112 (gate stride 112)
#define LOG2E  1.4426950408889634f
#define LOG2E2 2.8853900817779268f

typedef unsigned short u16;
typedef unsigned int   u32;
typedef __attribute__((ext_vector_type(8))) short short8;
typedef __attribute__((ext_vector_type(4))) float floatx4;

// gate pre-activations arrive PRE-SCALED by log2e (r,z) / 2log2e (n):
// sigmoid(x) = 1/(1+2^(-x*log2e)); tanh(u) = 1 - 2/(2^(2u*log2e)+1)
__device__ __forceinline__ float sigmoid2_(float y) {
    return __fdividef(1.f, 1.f + __builtin_amdgcn_exp2f(-y));
}
__device__ __forceinline__ float tanh2_(float y) {
    return 1.f - __fdividef(2.f, __builtin_amdgcn_exp2f(y) + 1.f);
}
__device__ __forceinline__ u16 f2bf(float f) {
    u32 u = __float_as_uint(f);
    u32 r = (u + 0x7fffu + ((u >> 16) & 1u)) >> 16;
    return (u16)r;
}
// 1-inst RNE f32->bf16 (hot path only)
__device__ __forceinline__ u16 f2bf_c(float f) {
    u32 r;
    asm("v_cvt_pk_bf16_f32 %0, %1, %2" : "=v"(r) : "v"(f), "v"(f));
    return (u16)r;
}
__device__ __forceinline__ float bf2f(u16 h) {
    return __uint_as_float(((u32)h) << 16);
}

// ---------------------------------------------------------------------------
// Fused 2-layer GRU v10: 448 threads (7 waves) / 32 rows / TT steps.
// vs v9: gate-scale folded into weights (exp2 path, no scale-muls in the
// trans-heavy combine); h update as n + z*(h-n). Structure identical.
// ---------------------------------------------------------------------------
struct GruProb {
    const u16*   Etab;     // [VOC][112][4] interleaved, pre-scaled
    const int*   nodes;    // [M][TT]
    const float* h0;       // [2][M][100] fp32
    const u16*   Whh0;     // [336][128] gate-padded, scaled (col100 = bhh0)
    const u16*   Wih1;
    const u16*   Whh1;
    u16*         hout;     // [M][128]
    int          M;
};

__global__ __launch_bounds__(448, 2) void gru_fused10(GruProb Pg, GruProb Pt, int gblocks)
{
    const bool isg = (int)blockIdx.x < gblocks;
    const GruProb P = isg ? Pg : Pt;
    const int bx = isg ? blockIdx.x : blockIdx.x - gblocks;
    const int M  = P.M;
    const int m0 = bx * 32;

    __shared__ u16 H0[2][32 * 128];
    __shared__ u16 H1[2][32 * 128];
    __shared__ int NID[TT * 32];

    const int tid  = threadIdx.x;
    const int w    = tid >> 6, lane = tid & 63;
    const int fr   = lane & 15, quad = lane >> 4;
    const int c    = w * 16 + fr;
    const bool cok = (c < HD);

    short8 Bh0[3][4], Bx1[3][4], Bh1[3][4];
#pragma unroll
    for (int g = 0; g < 3; ++g) {
        const size_t rb = (size_t)((g * 7 + w) * 16 + fr) * 128 + quad * 8;
#pragma unroll
        for (int kk = 0; kk < 4; ++kk) {
            Bh0[g][kk] = *(const short8*)(P.Whh0 + rb + kk * 32);
            Bx1[g][kk] = *(const short8*)(P.Wih1 + rb + kk * 32);
            Bh1[g][kk] = *(const short8*)(P.Whh1 + rb + kk * 32);
        }
    }

    for (int i = tid; i < 32 * 128; i += 448) {
        H0[0][i] = 0; H0[1][i] = 0; H1[0][i] = 0; H1[1][i] = 0;
    }
    for (int i = tid; i < 32 * TT; i += 448) {
        int row = i / TT, t = i - row * TT;
        int gm = m0 + row;
        NID[t * 32 + row] = (gm < M) ? P.nodes[(size_t)gm * TT + t] : 0;
    }
    __syncthreads();
    if (tid < 32) {
        int off = 200 ^ ((tid & 7) << 4);
        *(u16*)((char*)&H0[0][0] + tid * 256 + off) = 0x3F80;
        *(u16*)((char*)&H0[1][0] + tid * 256 + off) = 0x3F80;
        *(u16*)((char*)&H1[0][0] + tid * 256 + off) = 0x3F80;
        *(u16*)((char*)&H1[1][0] + tid * 256 + off) = 0x3F80;
    }

    float h0f[2][4] = {{0.f,0.f,0.f,0.f},{0.f,0.f,0.f,0.f}};
    float h1f[2][4] = {{0.f,0.f,0.f,0.f},{0.f,0.f,0.f,0.f}};
    if (cok) {
#pragma unroll
        for (int rt = 0; rt < 2; ++rt)
#pragma unroll
        for (int r = 0; r < 4; ++r) {
            int row = rt * 16 + quad * 4 + r;
            int gm  = m0 + row;
            float v0 = 0.f, v1 = 0.f;
            if (gm < M) {
                v0 = P.h0[(size_t)gm * HD + c];
                v1 = P.h0[(size_t)(M + gm) * HD + c];
            }
            h0f[rt][r] = v0; h1f[rt][r] = v1;
            int off = (2 * c) ^ ((row & 7) << 4);
            *(u16*)((char*)&H0[0][0] + row * 256 + off) = f2bf_c(v0);
            *(u16*)((char*)&H1[0][0] + row * 256 + off) = f2bf_c(v1);
        }
    }

    // x-gate prefetch: one dwordx2 per (rt,r) -> (r,z) in lo, (n,pad) in hi
    u32 xlo[2][4], xhi[2][4];
    auto xpref = [&](int tn) {
        if (cok) {
#pragma unroll
            for (int rt = 0; rt < 2; ++rt)
#pragma unroll
            for (int r = 0; r < 4; ++r) {
                int row = rt * 16 + quad * 4 + r;
                int nd  = NID[tn * 32 + row];
                uint2 v = *(const uint2*)(P.Etab + (size_t)nd * ESTR2 + c * 4);
                xlo[rt][r] = v.x; xhi[rt][r] = v.y;
            }
        }
    };
    __syncthreads();
    xpref(0);

    // ---- prologue: A(0) ----
#pragma unroll
    for (int rt = 0; rt < 2; ++rt) {
        short8 a[4];
#pragma unroll
        for (int kk = 0; kk < 4; ++kk) {
            int row = rt * 16 + fr;
            int off = (kk * 64 + quad * 16) ^ ((row & 7) << 4);
            a[kk] = *(const short8*)((const char*)&H0[0][0] + row * 256 + off);
        }
        floatx4 ag[3];
#pragma unroll
        for (int g = 0; g < 3; ++g) ag[g] = (floatx4){0.f, 0.f, 0.f, 0.f};
#pragma unroll
        for (int g = 0; g < 3; ++g)
#pragma unroll
            for (int kk = 0; kk < 4; ++kk)
                ag[g] = __builtin_amdgcn_mfma_f32_16x16x32_bf16(a[kk], Bh0[g][kk], ag[g], 0, 0, 0);
        if (cok) {
#pragma unroll
            for (int r = 0; r < 4; ++r) {
                int row = rt * 16 + quad * 4 + r;
                float rr = sigmoid2_(bf2f((u16)xlo[rt][r]) + ag[0][r]);
                float zz = sigmoid2_(bf2f((u16)(xlo[rt][r] >> 16)) + ag[1][r]);
                float nn = tanh2_(bf2f((u16)xhi[rt][r]) + rr * ag[2][r]);
                float o  = nn + zz * (h0f[rt][r] - nn);
                h0f[rt][r] = o;
                *(u16*)((char*)&H0[1][0] + row * 256 + ((2 * c) ^ ((row & 7) << 4))) = f2bf_c(o);
            }
        }
    }
    __syncthreads();

    // ---- regions r = 0..TT-1: B(r) + A(r+1) ----
    for (int r = 0; r < TT; ++r) {
        const bool doA = (r + 1 < TT);
        if (doA) xpref(r + 1);

        const char* rd0 = (const char*)&H0[(r + 1) & 1][0];
        const char* rd1 = (const char*)&H1[r & 1][0];
        char*       wr0 = (char*)&H0[r & 1][0];
        char*       wr1 = (char*)&H1[(r + 1) & 1][0];

#pragma unroll
        for (int rt = 0; rt < 2; ++rt) {
            short8 a0[4], a1[4];
#pragma unroll
            for (int kk = 0; kk < 4; ++kk) {
                int row = rt * 16 + fr;
                int off = (kk * 64 + quad * 16) ^ ((row & 7) << 4);
                a0[kk] = *(const short8*)(rd0 + row * 256 + off);
                a1[kk] = *(const short8*)(rd1 + row * 256 + off);
            }
            floatx4 rz0 = {0.f,0.f,0.f,0.f}, rz1 = {0.f,0.f,0.f,0.f};
            floatx4 xnv = {0.f,0.f,0.f,0.f}, hnv = {0.f,0.f,0.f,0.f};
#pragma unroll
            for (int kk = 0; kk < 4; ++kk)
                rz0 = __builtin_amdgcn_mfma_f32_16x16x32_bf16(a0[kk], Bx1[0][kk], rz0, 0, 0, 0);
#pragma unroll
            for (int kk = 0; kk < 4; ++kk)
                rz0 = __builtin_amdgcn_mfma_f32_16x16x32_bf16(a1[kk], Bh1[0][kk], rz0, 0, 0, 0);
#pragma unroll
            for (int kk = 0; kk < 4; ++kk)
                rz1 = __builtin_amdgcn_mfma_f32_16x16x32_bf16(a0[kk], Bx1[1][kk], rz1, 0, 0, 0);
#pragma unroll
            for (int kk = 0; kk < 4; ++kk)
                rz1 = __builtin_amdgcn_mfma_f32_16x16x32_bf16(a1[kk], Bh1[1][kk], rz1, 0, 0, 0);
#pragma unroll
            for (int kk = 0; kk < 4; ++kk)
                xnv = __builtin_amdgcn_mfma_f32_16x16x32_bf16(a0[kk], Bx1[2][kk], xnv, 0, 0, 0);
#pragma unroll
            for (int kk = 0; kk < 4; ++kk)
                hnv = __builtin_amdgcn_mfma_f32_16x16x32_bf16(a1[kk], Bh1[2][kk], hnv, 0, 0, 0);
            floatx4 ag[3];
#pragma unroll
            for (int g = 0; g < 3; ++g) ag[g] = (floatx4){0.f, 0.f, 0.f, 0.f};
            if (doA) {
#pragma unroll
                for (int g = 0; g < 3; ++g)
#pragma unroll
                    for (int kk = 0; kk < 4; ++kk)
                        ag[g] = __builtin_amdgcn_mfma_f32_16x16x32_bf16(a0[kk], Bh0[g][kk], ag[g], 0, 0, 0);
            }
            if (cok) {
#pragma unroll
                for (int r4 = 0; r4 < 4; ++r4) {
                    int row = rt * 16 + quad * 4 + r4;
                    float rr = sigmoid2_(rz0[r4]);
                    float zz = sigmoid2_(rz1[r4]);
                    float nn = tanh2_(xnv[r4] + rr * hnv[r4]);
                    float o  = nn + zz * (h1f[rt][r4] - nn);
                    h1f[rt][r4] = o;
                    *(u16*)(wr1 + row * 256 + ((2 * c) ^ ((row & 7) << 4))) = f2bf_c(o);
                }
                if (doA) {
#pragma unroll
                    for (int r4 = 0; r4 < 4; ++r4) {
                        int row = rt * 16 + quad * 4 + r4;
                        float rr = sigmoid2_(bf2f((u16)xlo[rt][r4]) + ag[0][r4]);
                        float zz = sigmoid2_(bf2f((u16)(xlo[rt][r4] >> 16)) + ag[1][r4]);
                        float nn = tanh2_(bf2f((u16)xhi[rt][r4]) + rr * ag[2][r4]);
                        float o  = nn + zz * (h0f[rt][r4] - nn);
                        h0f[rt][r4] = o;
                        *(u16*)(wr0 + row * 256 + ((2 * c) ^ ((row & 7) << 4))) = f2bf_c(o);
                    }
                }
            }
        }
        __syncthreads();
    }

    for (int i = tid; i < 32 * 128; i += 448) {
        int row = i >> 7, cc = i & 127;
        int gm = m0 + row;
        if (gm < M) {
            int off = (2 * cc) ^ ((row & 7) << 4);
            P.hout[(size_t)gm * 128 + cc] = *(const u16*)((const char*)&H1[0][0] + row * 256 + off);
        }
    }
}

// ---------------------------------------------------------------------------
// bf16 MFMA GEMM (GAT feature GEMMs)
// ---------------------------------------------------------------------------
#define LDST 40
__global__ __launch_bounds__(256) void gemm_mfma(
    const u16* __restrict__ A, const u16* __restrict__ B,
    float* __restrict__ Cf, u16* __restrict__ Cb,
    int M, int N, int Kt, int lda, int ldw, int ldc)
{
    const int m0 = blockIdx.x * 64;
    if (m0 >= M) return;
    const int n0 = blockIdx.y * 64;

    __shared__ u16 Als[64 * LDST];
    __shared__ u16 Wls[64 * LDST];

    const int tid  = threadIdx.x;
    const int wave = tid >> 6, lane = tid & 63;
    const int row  = tid >> 2, part = (tid & 3) * 8;
    const int fr   = lane & 15, quad = lane >> 4;

    floatx4 acc[4];
#pragma unroll
    for (int t = 0; t < 4; ++t) acc[t] = (floatx4){0.f, 0.f, 0.f, 0.f};

    const int am = m0 + row;  const bool aok = am < M;
    const int wn = n0 + row;  const bool wok = wn < N;
    const uint4 z4 = {0u, 0u, 0u, 0u};

    for (int kk = 0; kk < Kt; ++kk) {
        uint4 av = aok ? *(const uint4*)(A + (size_t)am * lda + kk * 32 + part) : z4;
        uint4 wv = wok ? *(const uint4*)(B + (size_t)wn * ldw + kk * 32 + part) : z4;
        __syncthreads();
        *(uint4*)&Als[row * LDST + part] = av;
        *(uint4*)&Wls[row * LDST + part] = wv;
        __syncthreads();
        short8 af = *(const short8*)&Als[((wave << 4) + fr) * LDST + quad * 8];
#pragma unroll
        for (int t = 0; t < 4; ++t) {
            short8 bf = *(const short8*)&Wls[((t << 4) + fr) * LDST + quad * 8];
            acc[t] = __builtin_amdgcn_mfma_f32_16x16x32_bf16(af, bf, acc[t], 0, 0, 0);
        }
    }

    const int orow0 = m0 + (wave << 4) + quad * 4;
#pragma unroll
    for (int t = 0; t < 4; ++t) {
        int col = n0 + (t << 4) + fr;
        if (col >= N) continue;
#pragma unroll
        for (int r = 0; r < 4; ++r) {
            int mr = orow0 + r;
            if (mr >= M) continue;
            float v = acc[t][r];
            if (Cf) Cf[(size_t)mr * ldc + col] = v;
            if (Cb) Cb[(size_t)mr * ldc + col] = f2bf(v);
        }
    }
}

// Dual Etab build: z=0 -> (W0, C0), z=1 -> (W1, C1). A shared [VOC][128].
// W rows pre-ordered (r,z,n,pad)-interleaved so the row-major output IS the
// interleaved Etab layout -> contiguous u16 stores (no scatter).
__global__ __launch_bounds__(256) void gemm_etab(
    const u16* __restrict__ A, const u16* __restrict__ W0, const u16* __restrict__ W1,
    u16* __restrict__ C0, u16* __restrict__ C1)
{
    const int m0 = blockIdx.x * 64;
    const int n0 = blockIdx.y * 64;
    const u16* B = blockIdx.z ? W1 : W0;
    u16* Cb = blockIdx.z ? C1 : C0;
    const int N = 400;

    __shared__ u16 Als[64 * LDST];
    __shared__ u16 Wls[64 * LDST];

    const int tid  = threadIdx.x;
    const int wave = tid >> 6, lane = tid & 63;
    const int row  = tid >> 2, part = (tid & 3) * 8;
    const int fr   = lane & 15, quad = lane >> 4;

    floatx4 acc[4];
#pragma unroll
    for (int t = 0; t < 4; ++t) acc[t] = (floatx4){0.f, 0.f, 0.f, 0.f};

    const int am = m0 + row;
    const int wn = n0 + row;  const bool wok = wn < N;
    const uint4 z4 = {0u, 0u, 0u, 0u};

    for (int kk = 0; kk < 4; ++kk) {
        uint4 av = *(const uint4*)(A + (size_t)am * 128 + kk * 32 + part);
        uint4 wv = wok ? *(const uint4*)(B + (size_t)wn * 128 + kk * 32 + part) : z4;
        __syncthreads();
        *(uint4*)&Als[row * LDST + part] = av;
        *(uint4*)&Wls[row * LDST + part] = wv;
        __syncthreads();
        short8 af = *(const short8*)&Als[((wave << 4) + fr) * LDST + quad * 8];
#pragma unroll
        for (int t = 0; t < 4; ++t) {
            short8 bf = *(const short8*)&Wls[((t << 4) + fr) * LDST + quad * 8];
            acc[t] = __builtin_amdgcn_mfma_f32_16x16x32_bf16(af, bf, acc[t], 0, 0, 0);
        }
    }

    const int orow0 = m0 + (wave << 4) + quad * 4;
#pragma unroll
    for (int t = 0; t < 4; ++t) {
        int col = n0 + (t << 4) + fr;
        if (col >= N) continue;
#pragma unroll
        for (int r = 0; r < 4; ++r)
            Cb[(size_t)(orow0 + r) * ESTR2 + col] = f2bf(acc[t][r]);
    }
}

// ---------------------------------------------------------------------------
// fp32 tiled GEMM (user-embed MLP only)
// ---------------------------------------------------------------------------
__global__ __launch_bounds__(256) void gemm_nt(
    const float* __restrict__ A, const float* __restrict__ W,
    const float* __restrict__ bias, float* __restrict__ C,
    int M, int N, int K, int relu)
{
    const int m0 = blockIdx.x * 64;
    const int n0 = blockIdx.y * 64;
    __shared__ float As[20][68];
    __shared__ float Ws[20][68];
    const int tid = threadIdx.x;
    const int r0 = (tid >> 4) * 4;
    const int c0 = (tid & 15) * 4;
    int sr[5], sk[5];
#pragma unroll
    for (int it = 0; it < 5; ++it) {
        int idx = tid + it * 256;
        sr[it] = idx / 20; sk[it] = idx - sr[it] * 20;
    }
    float acc[4][4];
#pragma unroll
    for (int i = 0; i < 4; ++i)
#pragma unroll
        for (int j = 0; j < 4; ++j) acc[i][j] = 0.f;
    const int nch = (K + 19) / 20;
    for (int ch = 0; ch < nch; ++ch) {
        const int k0 = ch * 20;
#pragma unroll
        for (int it = 0; it < 5; ++it) {
            int m = m0 + sr[it], k = k0 + sk[it];
            float va = 0.f, vw = 0.f;
            if (k < K) {
                if (m < M) va = A[(size_t)m * K + k];
                int n = n0 + sr[it];
                if (n < N) vw = W[(size_t)n * K + k];
            }
            As[sk[it]][sr[it]] = va;
            Ws[sk[it]][sr[it]] = vw;
        }
        __syncthreads();
#pragma unroll
        for (int kkk = 0; kkk < 20; ++kkk) {
            float4 a = *(const float4*)&As[kkk][r0];
            float4 w = *(const float4*)&Ws[kkk][c0];
            float av[4] = {a.x, a.y, a.z, a.w};
            float wv[4] = {w.x, w.y, w.z, w.w};
#pragma unroll
            for (int i = 0; i < 4; ++i)
#pragma unroll
                for (int j = 0; j < 4; ++j)
                    acc[i][j] = fmaf(av[i], wv[j], acc[i][j]);
        }
        __syncthreads();
    }
#pragma unroll
    for (int i = 0; i < 4; ++i) {
        int m = m0 + r0 + i;
        if (m >= M) continue;
#pragma unroll
        for (int j = 0; j < 4; ++j) {
            int n = n0 + c0 + j;
            if (n >= N) continue;
            float v = acc[i][j] + (bias ? bias[n] : 0.f);
            if (relu) v = fmaxf(v, 0.f);
            C[(size_t)m * N + n] = v;
        }
    }
}

// fp32 [M][K] -> bf16 [Mp][ldk]; col K..ldk zero, except col 100 gets
// app[n] (if app) or 1.0 (if appone).
__global__ void convert_pad2(const float* __restrict__ src, u16* __restrict__ dst,
                             int M, int Mp, int K, int ldk,
                             const float* __restrict__ app, int appone)
{
    int t = blockIdx.x * blockDim.x + threadIdx.x;
    if (t >= Mp * ldk) return;
    int n = t / ldk, c = t - n * ldk;
    u16 o = 0;
    if (n < M) {
        if (c < K) o = f2bf(src[(size_t)n * K + c]);
        else if (c == 100) {
            if (app) o = f2bf(app[n]);
            else if (appone) o = 0x3F80;
        }
    }
    dst[t] = o;
}

// Batched GRU weight converts: 6 matrices -> gate-padded bf16 [336][128],
// pre-scaled by log2e (r,z) / 2log2e (n) for the exp2 combine path.
struct CvtgBatch {
    const float* src[6];
    const float* bias[6];
    u16*         dst[6];
};
#define CVTG_BLOCKS_PER_MAT 168   // 336*128/256
__global__ void convert_gru_w6(CvtgBatch B)
{
    int mat = blockIdx.x / CVTG_BLOCKS_PER_MAT;
    int t = (blockIdx.x - mat * CVTG_BLOCKS_PER_MAT) * blockDim.x + threadIdx.x;
    int rr = t >> 7, cc = t & 127;
    int g = rr / 112, r2 = rr - g * 112;
    u16 o = 0;
    if (r2 < 100) {
        float sc = (g == 2) ? LOG2E2 : LOG2E;
        int sr = g * 100 + r2;
        if (cc < 100) o = f2bf(B.src[mat][(size_t)sr * 100 + cc] * sc);
        else if (cc == 100) o = f2bf(B.bias[mat][sr] * sc);
    }
    B.dst[mat][t] = o;
}

// Wih0 -> [448][128] with row order (r,z,n,pad) per column, scaled; both
// branches in one launch. Row j: cc=j>>2, g=j&3.
__global__ void convert_ih0(const float* __restrict__ s0, const float* __restrict__ b0,
                            u16* __restrict__ d0,
                            const float* __restrict__ s1, const float* __restrict__ b1,
                            u16* __restrict__ d1)
{
    int t = blockIdx.x * blockDim.x + threadIdx.x;
    if (t >= 2 * 448 * 128) return;
    int which = t / (448 * 128);
    int tt = t - which * (448 * 128);
    const float* s = which ? s1 : s0;
    const float* b = which ? b1 : b0;
    u16* d = which ? d1 : d0;
    int j = tt >> 7, kc = tt & 127;
    int cc = j >> 2, g = j & 3;
    u16 o = 0;
    if (g < 3 && cc < 100) {
        float sc = (g == 2) ? LOG2E2 : LOG2E;
        int sr = g * 100 + cc;
        if (kc < 100) o = f2bf(s[(size_t)sr * 100 + kc] * sc);
        else if (kc == 100) o = f2bf(b[sr] * sc);
    }
    d[tt] = o;
}

// xg (bf16 [NG][128]) = concat(hg[:128], ue, hg[128:])
__global__ void build_xg_bf(const u16* __restrict__ hgb, const float* __restrict__ ue,
                            u16* __restrict__ xgb)
{
    int t = blockIdx.x * blockDim.x + threadIdx.x;
    if (t >= NG * 128) return;
    int n = t >> 7, c = t & 127;
    u16 o = 0;
    if (n < NB)           o = hgb[n * 128 + c];
    else if (n < NB + NU) { if (c < HD) o = f2bf(ue[(size_t)(n - NB) * HD + c]); }
    else                  o = hgb[(size_t)(n - NU) * 128 + c];
    xgb[t] = o;
}

__global__ void set_roots(const float* __restrict__ src, u16* __restrict__ hb)
{
    int t = blockIdx.x * blockDim.x + threadIdx.x;
    if (t >= NB * HD) return;
    int n = t / HD, c = t - n * HD;
    hb[(size_t)n * 128 + c] = f2bf(src[t]);
}

// ---------------------------------------------------------------------------
// CSR build — both graphs fused per phase
// ---------------------------------------------------------------------------
__global__ void csr_count2(const int* __restrict__ gei, const int* __restrict__ tei,
                           int* __restrict__ gcnt, int* __restrict__ tcnt)
{
    int e = blockIdx.x * blockDim.x + threadIdx.x;
    const int GE = EG + NG;
    if (e < GE) {
        int dst = (e < EG) ? gei[EG + e] : e - EG;
        atomicAdd(&gcnt[dst], 1);
    } else {
        int e2 = e - GE;
        if (e2 >= ET + NTREE) return;
        int dst = (e2 < ET) ? tei[ET + e2] : e2 - ET;
        atomicAdd(&tcnt[dst], 1);
    }
}

__global__ void csr_scan2(int* __restrict__ gcnt, int* __restrict__ goff, int* __restrict__ gcur,
                          int* __restrict__ tcnt, int* __restrict__ toff, int* __restrict__ tcur)
{
    const int* cnt = blockIdx.x ? tcnt : gcnt;
    int* off = blockIdx.x ? toff : goff;
    int* cur = blockIdx.x ? tcur : gcur;
    const int N = blockIdx.x ? NTREE : NG;
    __shared__ int part[256];
    const int tid = threadIdx.x;
    const int per = (N + 255) / 256;
    const int i0 = tid * per;
    const int i1 = min(i0 + per, N);
    int s = 0;
    for (int i = i0; i < i1; ++i) s += cnt[i];
    part[tid] = s;
    __syncthreads();
    for (int o = 1; o < 256; o <<= 1) {
        int u = (tid >= o) ? part[tid - o] : 0;
        __syncthreads();
        part[tid] += u;
        __syncthreads();
    }
    int base = part[tid] - s;
    for (int i = i0; i < i1; ++i) {
        off[i] = base; cur[i] = base;
        base += cnt[i];
    }
    if (tid == 255) off[N] = part[255];
}

__global__ void csr_scatter2(const int* __restrict__ gei, const int* __restrict__ tei,
                             int* __restrict__ gcur, int* __restrict__ tcur,
                             int* __restrict__ geidx, int* __restrict__ teidx)
{
    int e = blockIdx.x * blockDim.x + threadIdx.x;
    const int GE = EG + NG;
    if (e < GE) {
        int dst = (e < EG) ? gei[EG + e] : e - EG;
        int pos = atomicAdd(&gcur[dst], 1);
        geidx[pos] = e;
    } else {
        int e2 = e - GE;
        if (e2 >= ET + NTREE) return;
        int dst = (e2 < ET) ? tei[ET + e2] : e2 - ET;
        int pos = atomicAdd(&tcur[dst], 1);
        teidx[pos] = e2;
    }
}

// ---------------------------------------------------------------------------
// GAT pieces (feat is bf16); es_ed also initializes m (=-inf bits) and s (=0)
// ---------------------------------------------------------------------------
__global__ void gat_es_ed(const u16* __restrict__ feat, const float* __restrict__ asrc,
                          const float* __restrict__ adst, float* __restrict__ es,
                          float* __restrict__ ed, float* __restrict__ m,
                          float* __restrict__ s, int N, int heads, int C)
{
    int gid = blockIdx.x * blockDim.x + threadIdx.x;
    if (gid >= N * heads) return;
    int n = gid / heads, hd = gid - n * heads;
    const u16* hp = feat + ((size_t)n * heads + hd) * C;
    const float* as = asrc + (size_t)hd * C;
    const float* ad = adst + (size_t)hd * C;
    float s1 = 0.f, s2 = 0.f;
    for (int c = 0; c < C; c += 4) {
        uint2 pk = *(const uint2*)(hp + c);
        float v0 = bf2f((u16)(pk.x & 0xffff)), v1 = bf2f((u16)(pk.x >> 16));
        float v2 = bf2f((u16)(pk.y & 0xffff)), v3 = bf2f((u16)(pk.y >> 16));
        s1 += v0 * as[c] + v1 * as[c + 1] + v2 * as[c + 2] + v3 * as[c + 3];
        s2 += v0 * ad[c] + v1 * ad[c + 1] + v2 * ad[c + 2] + v3 * ad[c + 3];
    }
    es[gid] = s1; ed[gid] = s2;
    m[gid] = __uint_as_float(0xFFFFFFFFu);   // init for atomic_max_f
    s[gid] = 0.f;
}

__device__ __forceinline__ void atomic_max_f(float* addr, float v)
{
    if (v >= 0.f) atomicMax((int*)addr, __float_as_int(v));
    else          atomicMin((unsigned int*)addr, __float_as_uint(v));
}

__global__ void gat_edge_logit(const int* __restrict__ ei, int E, int N, int heads,
                               const float* __restrict__ es, const float* __restrict__ ed,
                               float* __restrict__ eb, float* __restrict__ m)
{
    int gid = blockIdx.x * blockDim.x + threadIdx.x;
    int EE = E + N;
    if (gid >= EE * heads) return;
    int idx = gid / heads, hd = gid - idx * heads;
    int src, dst;
    if (idx < E) { src = ei[idx]; dst = ei[E + idx]; } else { src = dst = idx - E; }
    float e = es[src * heads + hd] + ed[dst * heads + hd];
    e = e > 0.f ? e : 0.2f * e;
    eb[gid] = e;
    atomic_max_f(&m[dst * heads + hd], e);
}

__global__ void gat_edge_expsum(const int* __restrict__ ei, int E, int N, int heads,
                                float* __restrict__ eb, const float* __restrict__ m,
                                float* __restrict__ s)
{
    int gid = blockIdx.x * blockDim.x + threadIdx.x;
    int EE = E + N;
    if (gid >= EE * heads) return;
    int idx = gid / heads, hd = gid - idx * heads;
    int dst = (idx < E) ? ei[E + idx] : idx - E;
    float e = __expf(eb[gid] - m[dst * heads + hd]);
    eb[gid] = e;
    atomicAdd(&s[dst * heads + hd], e);
}

template<int C, int VEC>
__global__ __launch_bounds__(256) void gat_accum_csr(
    const int* __restrict__ off, const int* __restrict__ eidx,
    const int* __restrict__ ei, int E,
    const float* __restrict__ eb, const float* __restrict__ s,
    const u16* __restrict__ feat, const float* __restrict__ bias,
    float* __restrict__ outf, u16* __restrict__ outb,
    int N, int heads, int HC, int nchunk)
{
    int gt = blockIdx.x * blockDim.x + threadIdx.x;
    int w = gt >> 6, lane = gt & 63;
    int dst = w / nchunk, chunk = w - dst * nchunk;
    if (dst >= N) return;
    int c0 = chunk * 64 * VEC + lane * VEC;
    if (c0 >= HC) return;
    int hh[VEC]; float sinv[VEC], acc[VEC];
#pragma unroll
    for (int v = 0; v < VEC; ++v) {
        int c = c0 + v;
        hh[v] = c / C;
        sinv[v] = __fdividef(1.f, s[dst * heads + hh[v]]);
        acc[v] = 0.f;
    }
    int e0 = off[dst], e1 = off[dst + 1];
    for (int p = e0; p < e1; ++p) {
        int j = eidx[p];
        int src = (j < E) ? ei[j] : (j - E);
        const u16* frp = feat + (size_t)src * HC + c0;
        float fv[VEC];
        if (VEC == 4) {
            uint2 pk = *(const uint2*)frp;
            fv[0] = bf2f((u16)(pk.x & 0xffff)); fv[1] = bf2f((u16)(pk.x >> 16));
            fv[2] = bf2f((u16)(pk.y & 0xffff)); fv[3] = bf2f((u16)(pk.y >> 16));
        } else {
            u32 pk = *(const u32*)frp;
            fv[0] = bf2f((u16)(pk & 0xffff)); fv[1] = bf2f((u16)(pk >> 16));
        }
#pragma unroll
        for (int v = 0; v < VEC; ++v)
            acc[v] += fv[v] * eb[(size_t)j * heads + hh[v]] * sinv[v];
    }
#pragma unroll
    for (int v = 0; v < VEC; ++v) {
        int c = c0 + v;
        float o = fmaxf(acc[v] + bias[c], 0.f);
        if (outf) outf[(size_t)dst * HC + c] = o;
        if (outb) outb[(size_t)dst * HC + c] = f2bf(o);
    }
}

__global__ void scatter_mean_accum(const float* __restrict__ x, const int* __restrict__ idx,
                                   float* __restrict__ ssum, float* __restrict__ cnt)
{
    int t = blockIdx.x * blockDim.x + threadIdx.x;
    if (t >= NTREE * HD) return;
    int n = t / HD, c = t - n * HD;
    int b = idx[n];
    atomicAdd(&ssum[b * HD + c], x[t]);
    if (c == 0) atomicAdd(&cnt[b], 1.f);
}

__global__ void fc_out(const float* __restrict__ ssum, const float* __restrict__ cnt,
                       const float* __restrict__ W, const float* __restrict__ b,
                       float* __restrict__ out)
{
    int t = threadIdx.x;                 // 512 threads
    int bb = t >> 2, j = t & 3;
    float inv = __fdividef(1.f, fmaxf(cnt[bb], 1.f));
    float acc = b[j];
    for (int k = 0; k < HD; ++k) acc += ssum[bb * HD + k] * inv * W[j * HD + k];
    out[t] = acc;
}

// ---------------------------------------------------------------------------
// Host launcher
// ---------------------------------------------------------------------------
extern "C" void kernel_launch(void* const* d_in, const int* in_sizes, int n_in,
                              void* d_out, int out_size, void* d_ws, size_t ws_size,
                              hipStream_t stream)
{
    const float* user_feats = (const float*)d_in[1];
    const int*   gnf        = (const int*)d_in[2];
    const int*   gei        = (const int*)d_in[3];
    const int*   tnf        = (const int*)d_in[4];
    const int*   tei        = (const int*)d_in[5];
    const int*   indices    = (const int*)d_in[6];
    const float* h0g        = (const float*)d_in[7];
    const float* h0t        = (const float*)d_in[8];
    const float* temb       = (const float*)d_in[9];
    const float* gW[2][4] = {{(const float*)d_in[10], (const float*)d_in[11], (const float*)d_in[12], (const float*)d_in[13]},
                             {(const float*)d_in[14], (const float*)d_in[15], (const float*)d_in[16], (const float*)d_in[17]}};
    const float* tW[2][4] = {{(const float*)d_in[18], (const float*)d_in[19], (const float*)d_in[20], (const float*)d_in[21]},
                             {(const float*)d_in[22], (const float*)d_in[23], (const float*)d_in[24], (const float*)d_in[25]}};
    const float* uW1 = (const float*)d_in[26]; const float* ub1 = (const float*)d_in[27];
    const float* uW2 = (const float*)d_in[28]; const float* ub2 = (const float*)d_in[29];
    const float* gc1W = (const float*)d_in[30]; const float* gc1as = (const float*)d_in[31];
    const float* gc1ad = (const float*)d_in[32]; const float* gc1b = (const float*)d_in[33];
    const float* gc2W = (const float*)d_in[34]; const float* gc2as = (const float*)d_in[35];
    const float* gc2ad = (const float*)d_in[36]; const float* gc2b = (const float*)d_in[37];
    const float* tc1W = (const float*)d_in[38]; const float* tc1as = (const float*)d_in[39];
    const float* tc1ad = (const float*)d_in[40]; const float* tc1b = (const float*)d_in[41];
    const float* tc2W = (const float*)d_in[42]; const float* tc2as = (const float*)d_in[43];
    const float* tc2ad = (const float*)d_in[44]; const float* tc2b = (const float*)d_in[45];
    const float* fcW = (const float*)d_in[46]; const float* fcb = (const float*)d_in[47];
    float* out = (float*)d_out;

    char* ws = (char*)d_ws;
    const size_t NEED = 226500000;
    if (ws_size < NEED) return;

    // ---- workspace layout (decimal byte offsets, overlays noted) ----
    float* XGF    = (float*)(ws + 0);            // 12 MB [NG][100] fp32
    u16*   TEMB_B = (u16*)(ws + 12000000);       // 12.8 MB [VOC][128]
    u16*   ETAB_G = (u16*)(ws + 25000000);       // 44.8 MB [VOC][448] interleaved
    u16*   ETAB_T = (u16*)(ws + 70000000);       // 44.8 MB -> 114.8
    u16*   GH1B   = (u16*)(ws + 115000000);      // 2.56 MB [NTG][128]
    u16*   TH1B   = (u16*)(ws + 117600000);      // 7.68 MB [NTREE][128]
    float* UE     = (float*)(ws + 125300000);    // 8 MB
    float* HID    = (float*)(ws + 133400000);    // 8 MB
    u16*   WARENA = (u16*)(ws + 141500000);      // 1.11 MB weight arena
    int*   GOFF   = (int*)(ws + 142700000);
    int*   GCUR   = (int*)(ws + 142900000);
    int*   GCNT   = (int*)(ws + 143100000);      // NG ints
    int*   TCNT   = (int*)(ws + 143220000);      // NTREE ints (adjacent: 1 memset)
    int*   GEIDX  = (int*)(ws + 143400000);      // 0.92 MB
    int*   TOFF   = (int*)(ws + 144400000);
    int*   TCUR   = (int*)(ws + 144600000);
    int*   TEIDX  = (int*)(ws + 144800000);      // 0.36 MB
    float* ESB    = (float*)(ws + 145300000);
    float* EDB    = (float*)(ws + 146300000);
    float* MB     = (float*)(ws + 147300000);
    float* SB     = (float*)(ws + 148300000);
    float* EBB    = (float*)(ws + 149300000);    // 7.36 MB
    float* SSUM   = (float*)(ws + 156700000);
    float* SCNT   = (float*)(ws + 156800000);
    u16*   XG_B   = (u16*)(ws + 157000000);      // 7.68 MB [NG][128]
    u16*   GFEAT1 = (u16*)(ws + 165000000);      // 30.72 MB [NG][512] -> 195.72
    // overlays (regions dead by the time they're written):
    u16*   GOUT1B = (u16*)(ws + 25000000);       // 30.72 MB (over ETAB_G, dead after GRU)
    u16*   GFEAT2 = (u16*)(ws + 56000000);       // 6 MB [NG][100]
    u16*   TFEAT1 = (u16*)(ws + 25000000);       // 48 MB [NTREE][800] (after graph GATs)
    u16*   TOUT1B = (u16*)(ws + 74000000);       // 48 MB (over ETAB_T/GH1B/TH1B-tail, dead)
    u16*   TFEAT2 = (u16*)(ws + 123000000);      // 6 MB (over TH1B-tail/UE, dead)
    float* XOUT2  = (float*)(ws + 157000000);    // 12 MB (over XG_B/GFEAT1-head, dead)

    // weight arena slots (u16 element offsets)
    u16* gWHH0  = WARENA + 0;        // 6 x [336][128]
    u16* gWIH1  = WARENA + 43008;
    u16* gWHH1  = WARENA + 86016;
    u16* tWHH0  = WARENA + 129024;
    u16* tWIH1  = WARENA + 172032;
    u16* tWHH1  = WARENA + 215040;
    u16* W_IH0A = WARENA + 258048;   // [448][128] interleaved-row Etab weights
    u16* W_IH0B = WARENA + 315392;
    u16* W_G1   = WARENA + 372736;   // up to [800][128]
    u16* W_G2   = WARENA + 475136;   // up to [100][800] -> end 555136 u16 (1.11 MB)

    auto cvt = [&](const float* src, u16* dst, int M, int Mp, int K, int ldk,
                   const float* app = nullptr, int appone = 0) {
        convert_pad2<<<((size_t)Mp * ldk + 255) / 256, 256, 0, stream>>>(
            src, dst, M, Mp, K, ldk, app, appone);
    };
    auto mfma = [&](const u16* A, int lda, const u16* W, int ldw,
                    float* Cf, u16* Cb, int ldc, int M, int N, int Kt) {
        dim3 grid((M + 63) / 64, (N + 63) / 64, 1);
        gemm_mfma<<<grid, 256, 0, stream>>>(A, W, Cf, Cb, M, N, Kt, lda, ldw, ldc);
    };
    auto gat_pre = [&](const u16* feat, int N, int heads, int C,
                       const float* asrc, const float* adst, const int* ei, int E) {
        gat_es_ed<<<(N * heads + 255) / 256, 256, 0, stream>>>(
            feat, asrc, adst, ESB, EDB, MB, SB, N, heads, C);
        int EE = E + N;
        gat_edge_logit<<<(EE * heads + 255) / 256, 256, 0, stream>>>(ei, E, N, heads, ESB, EDB, EBB, MB);
        gat_edge_expsum<<<(EE * heads + 255) / 256, 256, 0, stream>>>(ei, E, N, heads, EBB, MB, SB);
    };

    // ---- 1. user embed (fp32) ----
    {
        dim3 g1((NU + 63) / 64, (HD + 63) / 64, 1);
        gemm_nt<<<g1, 256, 0, stream>>>(user_feats, uW1, ub1, HID, NU, HD, 9, 1);
        gemm_nt<<<g1, 256, 0, stream>>>(HID, uW2, ub2, UE, NU, HD, HD, 0);
    }

    // ---- 2. converts (scaled) + fused Etab build ----
    cvt(temb, TEMB_B, VOC, VOC, HD, 128, nullptr, 1);           // col100 = 1
    {
        CvtgBatch B;
        B.src[0] = gW[0][1]; B.bias[0] = gW[0][3]; B.dst[0] = gWHH0;
        B.src[1] = gW[1][0]; B.bias[1] = gW[1][2]; B.dst[1] = gWIH1;
        B.src[2] = gW[1][1]; B.bias[2] = gW[1][3]; B.dst[2] = gWHH1;
        B.src[3] = tW[0][1]; B.bias[3] = tW[0][3]; B.dst[3] = tWHH0;
        B.src[4] = tW[1][0]; B.bias[4] = tW[1][2]; B.dst[4] = tWIH1;
        B.src[5] = tW[1][1]; B.bias[5] = tW[1][3]; B.dst[5] = tWHH1;
        convert_gru_w6<<<6 * CVTG_BLOCKS_PER_MAT, 256, 0, stream>>>(B);
    }
    convert_ih0<<<(2 * 448 * 128 + 255) / 256, 256, 0, stream>>>(
        gW[0][0], gW[0][2], W_IH0A, tW[0][0], tW[0][2], W_IH0B);
    {
        dim3 ge((VOC + 63) / 64, 7, 2);
        gemm_etab<<<ge, 256, 0, stream>>>(TEMB_B, W_IH0A, W_IH0B, ETAB_G, ETAB_T);
    }

    // ---- CSR (both graphs, fused phases) ----
    hipMemsetAsync(GCNT, 0, 143400000 - 143100000, stream);   // GCNT + TCNT
    {
        int tot = (EG + NG) + (ET + NTREE);
        csr_count2<<<(tot + 255) / 256, 256, 0, stream>>>(gei, tei, GCNT, TCNT);
        csr_scan2<<<2, 256, 0, stream>>>(GCNT, GOFF, GCUR, TCNT, TOFF, TCUR);
        csr_scatter2<<<(tot + 255) / 256, 256, 0, stream>>>(gei, tei, GCUR, TCUR, GEIDX, TEIDX);
    }

    // ---- 3. combined GRU (both branches, one launch) ----
    {
        GruProb Pg = { ETAB_G, gnf, h0g, gWHH0, gWIH1, gWHH1, GH1B, NTG };
        GruProb Pt = { ETAB_T, tnf, h0t, tWHH0, tWIH1, tWHH1, TH1B, NTREE };
        int gblk = (NTG + 31) / 32;      // 313
        int tblk = (NTREE + 31) / 32;    // 938
        gru_fused10<<<gblk + tblk, 448, 0, stream>>>(Pg, Pt, gblk);
    }

    // ---- 4. graph GAT chain ----
    build_xg_bf<<<(NG * 128 + 255) / 256, 256, 0, stream>>>(GH1B, UE, XG_B);
    cvt(gc1W, W_G1, 512, 512, HD, 128);
    cvt(gc2W, W_G2, 100, 100, 512, 512);
    {   // graph GAT1: 8 heads x 64
        mfma(XG_B, 128, W_G1, 128, nullptr, GFEAT1, 512, NG, 512, 4);
        gat_pre(GFEAT1, NG, 8, 64, gc1as, gc1ad, gei, EG);
        int waves = NG * 2;
        gat_accum_csr<64, 4><<<(waves + 3) / 4, 256, 0, stream>>>(
            GOFF, GEIDX, gei, EG, EBB, SB, GFEAT1, gc1b, nullptr, GOUT1B, NG, 8, 512, 2);
    }
    {   // graph GAT2: 1 head x 100
        mfma(GOUT1B, 512, W_G2, 512, nullptr, GFEAT2, 100, NG, 100, 16);
        gat_pre(GFEAT2, NG, 1, 100, gc2as, gc2ad, gei, EG);
        int waves = NG;
        gat_accum_csr<100, 2><<<(waves + 3) / 4, 256, 0, stream>>>(
            GOFF, GEIDX, gei, EG, EBB, SB, GFEAT2, gc2b, XGF, nullptr, NG, 1, 100, 1);
    }

    // ---- 5. tree GAT chain ----
    set_roots<<<(NB * HD + 255) / 256, 256, 0, stream>>>(XGF, TH1B);
    cvt(tc1W, W_G1, 800, 800, HD, 128);
    cvt(tc2W, W_G2, 100, 100, 800, 800);
    {   // tree GAT1: 8 heads x 100
        mfma(TH1B, 128, W_G1, 128, nullptr, TFEAT1, 800, NTREE, 800, 4);
        gat_pre(TFEAT1, NTREE, 8, 100, tc1as, tc1ad, tei, ET);
        int waves = NTREE * 4;
        gat_accum_csr<100, 4><<<(waves + 3) / 4, 256, 0, stream>>>(
            TOFF, TEIDX, tei, ET, EBB, SB, TFEAT1, tc1b, nullptr, TOUT1B, NTREE, 8, 800, 4);
    }
    {   // tree GAT2: 1 head x 100
        mfma(TOUT1B, 800, W_G2, 800, nullptr, TFEAT2, 100, NTREE, 100, 25);
        gat_pre(TFEAT2, NTREE, 1, 100, tc2as, tc2ad, tei, ET);
        int waves = NTREE;
        gat_accum_csr<100, 2><<<(waves + 3) / 4, 256, 0, stream>>>(
            TOFF, TEIDX, tei, ET, EBB, SB, TFEAT2, tc2b, XOUT2, nullptr, NTREE, 1, 100, 1);
    }

    // ---- 6. scatter_mean + classifier ----
    hipMemsetAsync(SSUM, 0, (size_t)NB * HD * 4, stream);
    hipMemsetAsync(SCNT, 0, (size_t)NB * 4, stream);
    scatter_mean_accum<<<(NTREE * HD + 255) / 256, 256, 0, stream>>>(XOUT2, indices, SSUM, SCNT);
    fc_out<<<1, 512, 0, stream>>>(SSUM, SCNT, fcW, fcb, out);
}